// Round 7
// baseline (493.626 us; speedup 1.0000x reference)
//
#include <hip/hip_runtime.h>
#include <cstdint>

#define N_NODES 100000
#define EP_N 400000
#define EN_N 400000
#define NODE_BLOCKS ((N_NODES + 63) / 64)
#define SCHUNK 512
#define SBLK ((N_NODES + SCHUNK - 1) / SCHUNK)

#define BSTR 264   // base LDS row: [gP(64) | X(64) | gN(64) | X(64)] + 8 pad (ushorts)
#define DSTR 392   // deep LDS row: [posIn(192) | negIn(192)] + 8 pad (ushorts)

// ws layout (in 4-byte units)
#define ACC_OFF 0
#define I_CNTP 16
#define I_CNTN (I_CNTP + N_NODES)
#define I_CURP (I_CNTN + N_NODES)
#define I_CURN (I_CURP + N_NODES)
#define I_OFFP (I_CURN + N_NODES)
#define I_OFFN (I_OFFP + N_NODES + 1)
#define I_CSRP (I_OFFN + N_NODES + 1)
#define I_CSRN (I_CSRP + EP_N)
#define I_PART (I_CSRN + EN_N)
#define I_EIDX (((I_PART + 2 * SBLK) + 3) & ~3)       // int4 per edge
#define F_XB (((I_EIDX + 4 * (EP_N + EN_N)) + 15) & ~15)
#define F_HB (F_XB + 32 * N_NODES)                // hboth: N*64 u32
#define F_PN (F_HB + 64 * N_NODES)                // pn: N*8 floats
#define F_ZB (F_PN + 8 * N_NODES)                 // zb: N*64 ushort
#define F_WT (((F_ZB + 32 * N_NODES) + 15) & ~15) // wt: 28672 ushorts

typedef __attribute__((ext_vector_type(8))) short sh8;
typedef __attribute__((ext_vector_type(4))) float f32x4;

__device__ inline float bf2f(unsigned short u) {
    return __uint_as_float((unsigned)u << 16);
}
__device__ inline unsigned short f2bf(float v) {
    unsigned u = __float_as_uint(v);
    return (unsigned short)((u + 0x7FFFu + ((u >> 16) & 1u)) >> 16);
}
__device__ inline float lo_bf(unsigned u) { return __uint_as_float(u << 16); }
__device__ inline float hi_bf(unsigned u) { return __uint_as_float(u & 0xFFFF0000u); }

__global__ void x_to_bf(const float* __restrict__ X, unsigned short* __restrict__ xb) {
    int i = blockIdx.x * 256 + threadIdx.x;
    if (i < N_NODES * 16) {
        float4 v = ((const float4*)X)[i];
        ushort4 o;
        o.x = f2bf(v.x); o.y = f2bf(v.y); o.z = f2bf(v.z); o.w = f2bf(v.w);
        ((ushort4*)xb)[i] = o;
    }
}

// transpose + bf16-ify the 4 weight matrices: Wt[n][k] = W[k][n]
__global__ void wprep(const float* __restrict__ W0p, const float* __restrict__ W0n,
                      const float* __restrict__ W1p, const float* __restrict__ W1n,
                      unsigned short* __restrict__ wt) {
    int i = blockIdx.x * 256 + threadIdx.x;
    if (i < 8192) {
        int n = i >> 7, k = i & 127;
        wt[i] = f2bf(W0p[k * 64 + n]);
    } else if (i < 16384) {
        int j = i - 8192; int n = j >> 7, k = j & 127;
        wt[i] = f2bf(W0n[k * 64 + n]);
    } else if (i < 22528) {
        int j = i - 16384; int n = j / 192, k = j - n * 192;
        wt[i] = f2bf(W1p[k * 32 + n]);
    } else if (i < 28672) {
        int j = i - 22528; int n = j / 192, k = j - n * 192;
        wt[i] = f2bf(W1n[k * 32 + n]);
    }
}

__global__ void count_kernel(const int* __restrict__ pe, const int* __restrict__ ne,
                             int* cp, int* cn) {
    int i = blockIdx.x * 256 + threadIdx.x;
    if (i < EP_N) {
        atomicAdd(&cp[pe[i]], 1);
    } else if (i < EP_N + EN_N) {
        atomicAdd(&cn[ne[i - EP_N]], 1);
    }
}

__global__ __launch_bounds__(512) void scan_p1(const int* __restrict__ cntP,
                                               const int* __restrict__ cntN,
                                               int* part) {
    int l = blockIdx.x < SBLK ? 0 : 1;
    int blk = blockIdx.x - l * SBLK;
    const int* cnt = l == 0 ? cntP : cntN;
    int idx = blk * SCHUNK + threadIdx.x;
    int v = idx < N_NODES ? cnt[idx] : 0;
    __shared__ int tmp[512];
    tmp[threadIdx.x] = v;
    __syncthreads();
    for (int d = 256; d > 0; d >>= 1) {
        if (threadIdx.x < d) tmp[threadIdx.x] += tmp[threadIdx.x + d];
        __syncthreads();
    }
    if (threadIdx.x == 0) part[l * SBLK + blk] = tmp[0];
}

__global__ __launch_bounds__(512) void scan_p2(int* part) {
    int t = threadIdx.x;
    int l = t >> 8, idx = t & 255;
    int v = idx < SBLK ? part[l * SBLK + idx] : 0;
    __shared__ int tmp[512];
    int sb = l << 8;
    tmp[sb + idx] = v;
    __syncthreads();
    for (int d = 1; d < 256; d <<= 1) {
        int x = (idx >= d) ? tmp[sb + idx - d] : 0;
        __syncthreads();
        tmp[sb + idx] += x;
        __syncthreads();
    }
    if (idx < SBLK) part[l * SBLK + idx] = tmp[sb + idx] - v;
}

__global__ __launch_bounds__(512) void scan_p3(const int* __restrict__ cntP,
                                               const int* __restrict__ cntN,
                                               const int* __restrict__ part,
                                               int* offP, int* offN) {
    int l = blockIdx.x < SBLK ? 0 : 1;
    int blk = blockIdx.x - l * SBLK;
    const int* cnt = l == 0 ? cntP : cntN;
    int* off = l == 0 ? offP : offN;
    int base = part[l * SBLK + blk];
    int t = threadIdx.x;
    int gidx = blk * SCHUNK + t;
    int c = gidx < N_NODES ? cnt[gidx] : 0;
    __shared__ int tmp[512];
    tmp[t] = c;
    __syncthreads();
    for (int d = 1; d < 512; d <<= 1) {
        int x = (t >= d) ? tmp[t - d] : 0;
        __syncthreads();
        tmp[t] += x;
        __syncthreads();
    }
    int incl = tmp[t];
    if (gidx < N_NODES) off[gidx] = base + incl - c;
    if (gidx == N_NODES - 1) off[N_NODES] = base + incl;
}

// CSR fill + packed per-edge {i,j,k,t} table
__global__ void fill_kernel(const int* __restrict__ pe, const int* __restrict__ ne,
                            const int* __restrict__ offP, const int* __restrict__ offN,
                            const int* __restrict__ ps, const int* __restrict__ ns,
                            const int* __restrict__ tgt,
                            int* curP, int* curN, int* csrP, int* csrN,
                            int4* __restrict__ eidx) {
    int e = blockIdx.x * 256 + threadIdx.x;
    if (e < EP_N) {
        int row = pe[e], col = pe[EP_N + e];
        int slot = atomicAdd(&curP[row], 1);
        csrP[offP[row] + slot] = col;
        int4 q = {row, col, ps[e], tgt[e]};
        eidx[e] = q;
    } else if (e < EP_N + EN_N) {
        int e2 = e - EP_N;
        int row = ne[e2], col = ne[EN_N + e2];
        int slot = atomicAdd(&curN[row], 1);
        csrN[offN[row] + slot] = col;
        int4 q = {row, col, ns[e2], tgt[e]};
        eidx[e] = q;
    }
}

// joint P/N gather-mean over bf16 rows: 8 loads in flight
__device__ inline void gather_mean2b(const unsigned short* __restrict__ src,
                                     const int* __restrict__ csrA, int stA, int enA,
                                     const int* __restrict__ csrB, int stB, int enB,
                                     int lane, float& mA, float& mB) {
    int dA = enA - stA, dB = enB - stB;
    int n = dA > dB ? dA : dB;
    float a0 = 0.f, a1 = 0.f, a2 = 0.f, a3 = 0.f;
    float b0 = 0.f, b1 = 0.f, b2 = 0.f, b3 = 0.f;
    int ea = dA ? enA - 1 : 0, eb = dB ? enB - 1 : 0;
    for (int p = 0; p < n; p += 4) {
        int ia0 = dA ? csrA[min(stA + p, ea)] : 0;
        int ia1 = dA ? csrA[min(stA + p + 1, ea)] : 0;
        int ia2 = dA ? csrA[min(stA + p + 2, ea)] : 0;
        int ia3 = dA ? csrA[min(stA + p + 3, ea)] : 0;
        int ib0 = dB ? csrB[min(stB + p, eb)] : 0;
        int ib1 = dB ? csrB[min(stB + p + 1, eb)] : 0;
        int ib2 = dB ? csrB[min(stB + p + 2, eb)] : 0;
        int ib3 = dB ? csrB[min(stB + p + 3, eb)] : 0;
        float va0 = bf2f(src[ia0 * 64 + lane]);
        float va1 = bf2f(src[ia1 * 64 + lane]);
        float va2 = bf2f(src[ia2 * 64 + lane]);
        float va3 = bf2f(src[ia3 * 64 + lane]);
        float vb0 = bf2f(src[ib0 * 64 + lane]);
        float vb1 = bf2f(src[ib1 * 64 + lane]);
        float vb2 = bf2f(src[ib2 * 64 + lane]);
        float vb3 = bf2f(src[ib3 * 64 + lane]);
        a0 += (p < dA) ? va0 : 0.f;
        a1 += (p + 1 < dA) ? va1 : 0.f;
        a2 += (p + 2 < dA) ? va2 : 0.f;
        a3 += (p + 3 < dA) ? va3 : 0.f;
        b0 += (p < dB) ? vb0 : 0.f;
        b1 += (p + 1 < dB) ? vb1 : 0.f;
        b2 += (p + 2 < dB) ? vb2 : 0.f;
        b3 += (p + 3 < dB) ? vb3 : 0.f;
    }
    mA = ((a0 + a1) + (a2 + a3)) / fmaxf((float)dA, 1.f);
    mB = ((b0 + b1) + (b2 + b3)) / fmaxf((float)dB, 1.f);
}

// joint P/N gather-mean over interleaved (hp,hn) u32 rows -> four means
__device__ inline void gather2x2(const unsigned* __restrict__ hb32,
                                 const int* __restrict__ csrA, int stA, int enA,
                                 const int* __restrict__ csrB, int stB, int enB,
                                 int lane,
                                 float& mAp, float& mAn, float& mBp, float& mBn) {
    int dA = enA - stA, dB = enB - stB;
    int n = dA > dB ? dA : dB;
    float ap0 = 0.f, ap1 = 0.f, ap2 = 0.f, ap3 = 0.f;
    float an0 = 0.f, an1 = 0.f, an2 = 0.f, an3 = 0.f;
    float bp0 = 0.f, bp1 = 0.f, bp2 = 0.f, bp3 = 0.f;
    float bn0 = 0.f, bn1 = 0.f, bn2 = 0.f, bn3 = 0.f;
    int ea = dA ? enA - 1 : 0, eb = dB ? enB - 1 : 0;
    for (int p = 0; p < n; p += 4) {
        int ia0 = dA ? csrA[min(stA + p, ea)] : 0;
        int ia1 = dA ? csrA[min(stA + p + 1, ea)] : 0;
        int ia2 = dA ? csrA[min(stA + p + 2, ea)] : 0;
        int ia3 = dA ? csrA[min(stA + p + 3, ea)] : 0;
        int ib0 = dB ? csrB[min(stB + p, eb)] : 0;
        int ib1 = dB ? csrB[min(stB + p + 1, eb)] : 0;
        int ib2 = dB ? csrB[min(stB + p + 2, eb)] : 0;
        int ib3 = dB ? csrB[min(stB + p + 3, eb)] : 0;
        unsigned va0 = hb32[ia0 * 64 + lane];
        unsigned va1 = hb32[ia1 * 64 + lane];
        unsigned va2 = hb32[ia2 * 64 + lane];
        unsigned va3 = hb32[ia3 * 64 + lane];
        unsigned vb0 = hb32[ib0 * 64 + lane];
        unsigned vb1 = hb32[ib1 * 64 + lane];
        unsigned vb2 = hb32[ib2 * 64 + lane];
        unsigned vb3 = hb32[ib3 * 64 + lane];
        bool ma0 = p < dA, ma1 = p + 1 < dA, ma2 = p + 2 < dA, ma3 = p + 3 < dA;
        bool mb0 = p < dB, mb1 = p + 1 < dB, mb2 = p + 2 < dB, mb3 = p + 3 < dB;
        ap0 += ma0 ? lo_bf(va0) : 0.f;  an0 += ma0 ? hi_bf(va0) : 0.f;
        ap1 += ma1 ? lo_bf(va1) : 0.f;  an1 += ma1 ? hi_bf(va1) : 0.f;
        ap2 += ma2 ? lo_bf(va2) : 0.f;  an2 += ma2 ? hi_bf(va2) : 0.f;
        ap3 += ma3 ? lo_bf(va3) : 0.f;  an3 += ma3 ? hi_bf(va3) : 0.f;
        bp0 += mb0 ? lo_bf(vb0) : 0.f;  bn0 += mb0 ? hi_bf(vb0) : 0.f;
        bp1 += mb1 ? lo_bf(vb1) : 0.f;  bn1 += mb1 ? hi_bf(vb1) : 0.f;
        bp2 += mb2 ? lo_bf(vb2) : 0.f;  bn2 += mb2 ? hi_bf(vb2) : 0.f;
        bp3 += mb3 ? lo_bf(vb3) : 0.f;  bn3 += mb3 ? hi_bf(vb3) : 0.f;
    }
    float rA = 1.f / fmaxf((float)dA, 1.f), rB = 1.f / fmaxf((float)dB, 1.f);
    mAp = ((ap0 + ap1) + (ap2 + ap3)) * rA;
    mAn = ((an0 + an1) + (an2 + an3)) * rA;
    mBp = ((bp0 + bp1) + (bp2 + bp3)) * rB;
    mBn = ((bn0 + bn1) + (bn2 + bn3)) * rB;
}

// both base layers: gather (bf16) -> MFMA GEMM -> tanh -> interleaved bf16 h
__global__ __launch_bounds__(512) void base_both(
    const unsigned short* __restrict__ xb,
    const int* __restrict__ offP, const int* __restrict__ csrP,
    const int* __restrict__ offN, const int* __restrict__ csrN,
    const unsigned short* __restrict__ wt0,   // [Wt0p(64x128) | Wt0n(64x128)]
    const float* __restrict__ bp0, const float* __restrict__ bn0,
    unsigned short* __restrict__ hboth) {
    __shared__ unsigned short lds[64 * BSTR];
    int tid = threadIdx.x, lane = tid & 63, w = tid >> 6;
    int base = blockIdx.x * 64;
    for (int r = w * 8; r < w * 8 + 8; ++r) {
        int node = base + r;
        float gP = 0.f, gN = 0.f;
        unsigned short sx = 0;
        if (node < N_NODES) {
            gather_mean2b(xb, csrP, offP[node], offP[node + 1],
                          csrN, offN[node], offN[node + 1], lane, gP, gN);
            sx = xb[node * 64 + lane];
        }
        unsigned short* rp = &lds[r * BSTR];
        rp[lane] = f2bf(gP);
        rp[64 + lane] = sx;
        rp[128 + lane] = f2bf(gN);
        rp[192 + lane] = sx;
    }
    __syncthreads();
    int wu = __builtin_amdgcn_readfirstlane(w);
    int mt = wu >> 1, half = wu & 1;
    int l15 = lane & 15, kq = lane >> 4;
    const unsigned short* wbase = wt0 + half * 8192;
    f32x4 acc[4];
#pragma unroll
    for (int nt = 0; nt < 4; ++nt) acc[nt] = (f32x4){0.f, 0.f, 0.f, 0.f};
    const unsigned short* arow = &lds[(mt * 16 + l15) * BSTR + half * 128 + kq * 8];
#pragma unroll
    for (int ks = 0; ks < 4; ++ks) {
        sh8 a = *(const sh8*)(arow + ks * 32);
#pragma unroll
        for (int nt = 0; nt < 4; ++nt) {
            sh8 bf = *(const sh8*)(wbase + (nt * 16 + l15) * 128 + ks * 32 + kq * 8);
            acc[nt] = __builtin_amdgcn_mfma_f32_16x16x32_bf16(a, bf, acc[nt], 0, 0, 0);
        }
    }
    __syncthreads();
    float* ht = (float*)lds;  // [64][130]
    const float* bias = half ? bn0 : bp0;
#pragma unroll
    for (int nt = 0; nt < 4; ++nt) {
        int col = nt * 16 + l15;
        float bb = bias[col];
#pragma unroll
        for (int r = 0; r < 4; ++r) {
            int row = mt * 16 + kq * 4 + r;
            ht[row * 130 + half * 64 + col] = tanhf(acc[nt][r] + bb);
        }
    }
    __syncthreads();
    unsigned* hb32 = (unsigned*)hboth;
    for (int i = tid; i < 64 * 64; i += 512) {
        int rr = i >> 6, c = i & 63;
        int node = base + rr;
        if (node < N_NODES) {
            unsigned lo = f2bf(ht[rr * 130 + c]);
            unsigned hi = f2bf(ht[rr * 130 + 64 + c]);
            hb32[node * 64 + c] = lo | (hi << 16);
        }
    }
}

// both deep layers: gather -> MFMA GEMM -> tanh -> z/zb/pn epilogue
__global__ __launch_bounds__(512) void deep_both(
    const unsigned short* __restrict__ hb,
    const int* __restrict__ offP, const int* __restrict__ csrP,
    const int* __restrict__ offN, const int* __restrict__ csrN,
    const unsigned short* __restrict__ wt1,   // [Wt1p(32x192) | Wt1n(32x192)]
    const float* __restrict__ bp1, const float* __restrict__ bn1,
    const float* __restrict__ Wreg, float* __restrict__ z,
    unsigned short* __restrict__ zbuf, float* __restrict__ pn) {
    __shared__ unsigned short lds[64 * DSTR];
    int tid = threadIdx.x, lane = tid & 63, w = tid >> 6;
    int base = blockIdx.x * 64;
    const unsigned* hb32 = (const unsigned*)hb;
    for (int r = w * 8; r < w * 8 + 8; ++r) {
        int node = base + r;
        float gPp = 0.f, gPn = 0.f, gNp = 0.f, gNn = 0.f, sp = 0.f, sn = 0.f;
        if (node < N_NODES) {
            gather2x2(hb32, csrP, offP[node], offP[node + 1],
                      csrN, offN[node], offN[node + 1], lane, gPp, gPn, gNp, gNn);
            unsigned self = hb32[node * 64 + lane];
            sp = lo_bf(self);
            sn = hi_bf(self);
        }
        unsigned short* rp = &lds[r * DSTR];
        rp[lane] = f2bf(gPp);        // posIn[0:64]   = gm(h_pos, csrP)
        rp[64 + lane] = f2bf(gNn);   // posIn[64:128] = gm(h_neg, csrN)
        rp[128 + lane] = f2bf(sp);   // posIn[128:192]= h_pos self
        rp[192 + lane] = f2bf(gPn);  // negIn[0:64]   = gm(h_neg, csrP)
        rp[256 + lane] = f2bf(gNp);  // negIn[64:128] = gm(h_pos, csrN)
        rp[320 + lane] = f2bf(sn);   // negIn[128:192]= h_neg self
    }
    __syncthreads();
    int wu = __builtin_amdgcn_readfirstlane(w);
    int mt = wu >> 1, half = wu & 1;
    int l15 = lane & 15, kq = lane >> 4;
    const unsigned short* wbase = wt1 + half * 6144;
    f32x4 acc[2];
    acc[0] = (f32x4){0.f, 0.f, 0.f, 0.f};
    acc[1] = (f32x4){0.f, 0.f, 0.f, 0.f};
    const unsigned short* arow = &lds[(mt * 16 + l15) * DSTR + half * 192 + kq * 8];
#pragma unroll
    for (int ks = 0; ks < 6; ++ks) {
        sh8 a = *(const sh8*)(arow + ks * 32);
#pragma unroll
        for (int nt = 0; nt < 2; ++nt) {
            sh8 bf = *(const sh8*)(wbase + (nt * 16 + l15) * 192 + ks * 32 + kq * 8);
            acc[nt] = __builtin_amdgcn_mfma_f32_16x16x32_bf16(a, bf, acc[nt], 0, 0, 0);
        }
    }
    __syncthreads();
    float* ot = (float*)lds;  // [64][65]
    const float* bias = half ? bn1 : bp1;
#pragma unroll
    for (int nt = 0; nt < 2; ++nt) {
        int col = nt * 16 + l15;
        float bb = bias[col];
#pragma unroll
        for (int r = 0; r < 4; ++r) {
            int row = mt * 16 + kq * 4 + r;
            ot[row * 65 + half * 32 + col] = tanhf(acc[nt][r] + bb);
        }
    }
    __syncthreads();
    for (int r = w * 8; r < w * 8 + 8; ++r) {
        int node = base + r;
        if (node >= N_NODES) break;
        float v = ot[r * 65 + lane];
        z[node * 64 + lane] = v;
        unsigned short rb = f2bf(v);
        zbuf[node * 64 + lane] = rb;
        float vb = bf2f(rb);
        float u0 = vb * Wreg[lane * 2 + 0];
        float u1 = vb * Wreg[lane * 2 + 1];
        float v0 = vb * Wreg[128 + lane * 2 + 0];
        float v1 = vb * Wreg[128 + lane * 2 + 1];
        float s = vb * vb;
#pragma unroll
        for (int off = 32; off; off >>= 1) {
            u0 += __shfl_xor(u0, off);
            u1 += __shfl_xor(u1, off);
            v0 += __shfl_xor(v0, off);
            v1 += __shfl_xor(v1, off);
            s += __shfl_xor(s, off);
        }
        if (lane == 0) {
            float4 st = {u0, u1, v0, v1};
            *(float4*)(pn + node * 8) = st;
            pn[node * 8 + 4] = s;
        }
    }
}

// 8 edges per wave (8-lane groups): uint4 row loads + packed eidx
__global__ __launch_bounds__(256) void loss3_kernel(
    const unsigned short* __restrict__ zb, const float* __restrict__ pn,
    const int4* __restrict__ eidx, float* acc) {
    int tid = threadIdx.x;
    int lane = tid & 63;
    int g = lane >> 3, sub = lane & 7;
    int wid = (blockIdx.x * 256 + tid) >> 6;
    int nw = (gridDim.x * 256) >> 6;
    float s_p = 0.f, s_n = 0.f, s_r = 0.f;
    const float q = 0.125f;
    for (int eb = wid * 8; eb < EP_N + EN_N; eb += nw * 8) {
        int e = eb + g;
        bool valid = e < EP_N + EN_N;
        bool isp = e < EP_N;
        int4 quad = eidx[valid ? e : 0];
        int i = valid ? quad.x : 0;
        int j = valid ? quad.y : 0;
        int k = valid ? quad.z : 0;
        int t = quad.w;
        const uint4 zi4 = *(const uint4*)(zb + ((long long)i << 6) + (sub << 3));
        const uint4 zj4 = *(const uint4*)(zb + ((long long)j << 6) + (sub << 3));
        const uint4 zk4 = *(const uint4*)(zb + ((long long)k << 6) + (sub << 3));
        float d1 = 0.f, d2 = 0.f;
        d1 = fmaf(lo_bf(zi4.x), lo_bf(zj4.x), d1);
        d1 = fmaf(hi_bf(zi4.x), hi_bf(zj4.x), d1);
        d1 = fmaf(lo_bf(zi4.y), lo_bf(zj4.y), d1);
        d1 = fmaf(hi_bf(zi4.y), hi_bf(zj4.y), d1);
        d1 = fmaf(lo_bf(zi4.z), lo_bf(zj4.z), d1);
        d1 = fmaf(hi_bf(zi4.z), hi_bf(zj4.z), d1);
        d1 = fmaf(lo_bf(zi4.w), lo_bf(zj4.w), d1);
        d1 = fmaf(hi_bf(zi4.w), hi_bf(zj4.w), d1);
        d2 = fmaf(lo_bf(zj4.x), lo_bf(zk4.x), d2);
        d2 = fmaf(hi_bf(zj4.x), hi_bf(zk4.x), d2);
        d2 = fmaf(lo_bf(zj4.y), lo_bf(zk4.y), d2);
        d2 = fmaf(hi_bf(zj4.y), hi_bf(zk4.y), d2);
        d2 = fmaf(lo_bf(zj4.z), lo_bf(zk4.z), d2);
        d2 = fmaf(hi_bf(zj4.z), hi_bf(zk4.z), d2);
        d2 = fmaf(lo_bf(zj4.w), lo_bf(zk4.w), d2);
        d2 = fmaf(hi_bf(zj4.w), hi_bf(zk4.w), d2);
#pragma unroll
        for (int off = 1; off < 8; off <<= 1) {
            d1 += __shfl_xor(d1, off);
            d2 += __shfl_xor(d2, off);
        }
        if (valid) {
            const float* pni = pn + ((long long)i << 3);
            const float* pnj = pn + ((long long)j << 3);
            float u0 = pni[0], u1 = pni[1], si = pni[4];
            float v0 = pnj[2], v1 = pnj[3], sj = pnj[4];
            float sk = pn[((long long)k << 3) + 4];
            float nij = si + sj - 2.f * d1;
            float nik = sj + sk - 2.f * d2;
            float tri = fmaxf(nij - nik, 0.f);
            float l0 = u0 + v0, l1 = u1 + v1;
            float m = fmaxf(l0, l1);
            float lse = m + logf(expf(l0 - m) + expf(l1 - m));
            float r = lse - (t ? l1 : l0);
            s_r += r * q;
            if (isp) s_p += tri * q; else s_n += tri * q;
        }
    }
#pragma unroll
    for (int off = 32; off; off >>= 1) {
        s_p += __shfl_xor(s_p, off);
        s_n += __shfl_xor(s_n, off);
        s_r += __shfl_xor(s_r, off);
    }
    __shared__ float red[3][4];
    int w = tid >> 6;
    if (lane == 0) {
        red[0][w] = s_p; red[1][w] = s_n; red[2][w] = s_r;
    }
    __syncthreads();
    if (tid == 0) {
        atomicAdd(&acc[0], red[0][0] + red[0][1] + red[0][2] + red[0][3]);
        atomicAdd(&acc[1], red[1][0] + red[1][1] + red[1][2] + red[1][3]);
        atomicAdd(&acc[2], red[2][0] + red[2][1] + red[2][2] + red[2][3]);
    }
}

__global__ void finalize_kernel(const float* __restrict__ acc, float* out) {
    out[0] = acc[2] / (float)(EP_N + EN_N) +
             1.0f * (acc[0] / (float)EP_N + acc[1] / (float)EN_N);
}

extern "C" void kernel_launch(void* const* d_in, const int* in_sizes, int n_in,
                              void* d_out, int out_size, void* d_ws, size_t ws_size,
                              hipStream_t stream) {
    const float* X = (const float*)d_in[0];
    const float* W_pos0 = (const float*)d_in[1];
    const float* b_pos0 = (const float*)d_in[2];
    const float* W_neg0 = (const float*)d_in[3];
    const float* b_neg0 = (const float*)d_in[4];
    const float* W_pos1 = (const float*)d_in[5];
    const float* b_pos1 = (const float*)d_in[6];
    const float* W_neg1 = (const float*)d_in[7];
    const float* b_neg1 = (const float*)d_in[8];
    const float* W_reg = (const float*)d_in[9];
    const int* pe = (const int*)d_in[10];
    const int* ne = (const int*)d_in[11];
    const int* target = (const int*)d_in[12];
    const int* ps = (const int*)d_in[13];
    const int* ns = (const int*)d_in[14];
    float* out = (float*)d_out;
    float* ws = (float*)d_ws;
    int* wsi = (int*)d_ws;

    float* acc = ws + ACC_OFF;
    int* cntP = wsi + I_CNTP;
    int* cntN = wsi + I_CNTN;
    int* curP = wsi + I_CURP;
    int* curN = wsi + I_CURN;
    int* offP = wsi + I_OFFP;
    int* offN = wsi + I_OFFN;
    int* csrP = wsi + I_CSRP;
    int* csrN = wsi + I_CSRN;
    int* part = wsi + I_PART;
    int4* eidx = (int4*)(wsi + I_EIDX);
    unsigned short* xb = (unsigned short*)(ws + F_XB);
    unsigned short* hboth = (unsigned short*)(ws + F_HB);
    float* pn = ws + F_PN;
    unsigned short* zb = (unsigned short*)(ws + F_ZB);
    unsigned short* wt = (unsigned short*)(ws + F_WT);
    float* z = out + 1;

    hipMemsetAsync(ws, 0, (size_t)(16 + 4 * N_NODES) * sizeof(float), stream);

    x_to_bf<<<(N_NODES * 16 + 255) / 256, 256, 0, stream>>>(X, xb);
    wprep<<<112, 256, 0, stream>>>(W_pos0, W_neg0, W_pos1, W_neg1, wt);
    count_kernel<<<(EP_N + EN_N + 255) / 256, 256, 0, stream>>>(pe, ne, cntP, cntN);
    scan_p1<<<2 * SBLK, 512, 0, stream>>>(cntP, cntN, part);
    scan_p2<<<1, 512, 0, stream>>>(part);
    scan_p3<<<2 * SBLK, 512, 0, stream>>>(cntP, cntN, part, offP, offN);
    fill_kernel<<<(EP_N + EN_N + 255) / 256, 256, 0, stream>>>(
        pe, ne, offP, offN, ps, ns, target, curP, curN, csrP, csrN, eidx);

    base_both<<<NODE_BLOCKS, 512, 0, stream>>>(xb, offP, csrP, offN, csrN,
                                               wt, b_pos0, b_neg0, hboth);
    deep_both<<<NODE_BLOCKS, 512, 0, stream>>>(hboth, offP, csrP, offN, csrN,
                                               wt + 16384, b_pos1, b_neg1,
                                               W_reg, z, zb, pn);

    loss3_kernel<<<2048, 256, 0, stream>>>(zb, pn, eidx, acc);
    finalize_kernel<<<1, 1, 0, stream>>>(acc, out);
}

// Round 8
// 426.171 us; speedup vs baseline: 1.1583x; 1.1583x over previous
//
#include <hip/hip_runtime.h>
#include <cstdint>

#define N_NODES 100000
#define EP_N 400000
#define EN_N 400000
#define NODE_BLOCKS ((N_NODES + 63) / 64)
#define SCHUNK 512
#define SBLK ((N_NODES + SCHUNK - 1) / SCHUNK)

#define BSTR 264   // base LDS row: [gP(64) | X(64) | gN(64) | X(64)] + 8 pad (ushorts)
#define DSTR 392   // deep LDS row: [posIn(192) | negIn(192)] + 8 pad (ushorts)

// ws layout (in 4-byte units)
#define ACC_OFF 0
#define I_CNTP 16
#define I_CNTN (I_CNTP + N_NODES)
#define I_CURP (I_CNTN + N_NODES)
#define I_CURN (I_CURP + N_NODES)
#define I_OFFP (I_CURN + N_NODES)
#define I_OFFN (I_OFFP + N_NODES + 1)
#define I_CSRP (I_OFFN + N_NODES + 1)
#define I_CSRN (I_CSRP + EP_N)
#define I_PART (I_CSRN + EN_N)
#define F_XB (((I_PART + 2 * SBLK) + 15) & ~15)   // xb: N*64 ushort
#define F_HB (F_XB + 32 * N_NODES)                // hboth: N*64 u32
#define F_PN (F_HB + 64 * N_NODES)                // pn: N*8 floats
#define F_ZQ (F_PN + 8 * N_NODES)                 // zq: N*64 bytes = N*16 dwords
#define F_WT (((F_ZQ + 16 * N_NODES) + 15) & ~15) // wt: 28672 ushorts

typedef __attribute__((ext_vector_type(8))) short sh8;
typedef __attribute__((ext_vector_type(4))) float f32x4;

__device__ inline float bf2f(unsigned short u) {
    return __uint_as_float((unsigned)u << 16);
}
__device__ inline unsigned short f2bf(float v) {
    unsigned u = __float_as_uint(v);
    return (unsigned short)((u + 0x7FFFu + ((u >> 16) & 1u)) >> 16);
}
__device__ inline float lo_bf(unsigned u) { return __uint_as_float(u << 16); }
__device__ inline float hi_bf(unsigned u) { return __uint_as_float(u & 0xFFFF0000u); }

__global__ void x_to_bf(const float* __restrict__ X, unsigned short* __restrict__ xb) {
    int i = blockIdx.x * 256 + threadIdx.x;
    if (i < N_NODES * 16) {
        float4 v = ((const float4*)X)[i];
        ushort4 o;
        o.x = f2bf(v.x); o.y = f2bf(v.y); o.z = f2bf(v.z); o.w = f2bf(v.w);
        ((ushort4*)xb)[i] = o;
    }
}

// transpose + bf16-ify the 4 weight matrices: Wt[n][k] = W[k][n]
__global__ void wprep(const float* __restrict__ W0p, const float* __restrict__ W0n,
                      const float* __restrict__ W1p, const float* __restrict__ W1n,
                      unsigned short* __restrict__ wt) {
    int i = blockIdx.x * 256 + threadIdx.x;
    if (i < 8192) {
        int n = i >> 7, k = i & 127;
        wt[i] = f2bf(W0p[k * 64 + n]);
    } else if (i < 16384) {
        int j = i - 8192; int n = j >> 7, k = j & 127;
        wt[i] = f2bf(W0n[k * 64 + n]);
    } else if (i < 22528) {
        int j = i - 16384; int n = j / 192, k = j - n * 192;
        wt[i] = f2bf(W1p[k * 32 + n]);
    } else if (i < 28672) {
        int j = i - 22528; int n = j / 192, k = j - n * 192;
        wt[i] = f2bf(W1n[k * 32 + n]);
    }
}

__global__ void count_kernel(const int* __restrict__ pe, const int* __restrict__ ne,
                             int* cp, int* cn) {
    int i = blockIdx.x * 256 + threadIdx.x;
    if (i < EP_N) {
        atomicAdd(&cp[pe[i]], 1);
    } else if (i < EP_N + EN_N) {
        atomicAdd(&cn[ne[i - EP_N]], 1);
    }
}

__global__ __launch_bounds__(512) void scan_p1(const int* __restrict__ cntP,
                                               const int* __restrict__ cntN,
                                               int* part) {
    int l = blockIdx.x < SBLK ? 0 : 1;
    int blk = blockIdx.x - l * SBLK;
    const int* cnt = l == 0 ? cntP : cntN;
    int idx = blk * SCHUNK + threadIdx.x;
    int v = idx < N_NODES ? cnt[idx] : 0;
    __shared__ int tmp[512];
    tmp[threadIdx.x] = v;
    __syncthreads();
    for (int d = 256; d > 0; d >>= 1) {
        if (threadIdx.x < d) tmp[threadIdx.x] += tmp[threadIdx.x + d];
        __syncthreads();
    }
    if (threadIdx.x == 0) part[l * SBLK + blk] = tmp[0];
}

__global__ __launch_bounds__(512) void scan_p2(int* part) {
    int t = threadIdx.x;
    int l = t >> 8, idx = t & 255;
    int v = idx < SBLK ? part[l * SBLK + idx] : 0;
    __shared__ int tmp[512];
    int sb = l << 8;
    tmp[sb + idx] = v;
    __syncthreads();
    for (int d = 1; d < 256; d <<= 1) {
        int x = (idx >= d) ? tmp[sb + idx - d] : 0;
        __syncthreads();
        tmp[sb + idx] += x;
        __syncthreads();
    }
    if (idx < SBLK) part[l * SBLK + idx] = tmp[sb + idx] - v;
}

__global__ __launch_bounds__(512) void scan_p3(const int* __restrict__ cntP,
                                               const int* __restrict__ cntN,
                                               const int* __restrict__ part,
                                               int* offP, int* offN) {
    int l = blockIdx.x < SBLK ? 0 : 1;
    int blk = blockIdx.x - l * SBLK;
    const int* cnt = l == 0 ? cntP : cntN;
    int* off = l == 0 ? offP : offN;
    int base = part[l * SBLK + blk];
    int t = threadIdx.x;
    int gidx = blk * SCHUNK + t;
    int c = gidx < N_NODES ? cnt[gidx] : 0;
    __shared__ int tmp[512];
    tmp[t] = c;
    __syncthreads();
    for (int d = 1; d < 512; d <<= 1) {
        int x = (t >= d) ? tmp[t - d] : 0;
        __syncthreads();
        tmp[t] += x;
        __syncthreads();
    }
    int incl = tmp[t];
    if (gidx < N_NODES) off[gidx] = base + incl - c;
    if (gidx == N_NODES - 1) off[N_NODES] = base + incl;
}

__global__ void fill_kernel(const int* __restrict__ pe, const int* __restrict__ ne,
                            const int* __restrict__ offP, const int* __restrict__ offN,
                            int* curP, int* curN, int* csrP, int* csrN) {
    int e = blockIdx.x * 256 + threadIdx.x;
    if (e < EP_N) {
        int row = pe[e], col = pe[EP_N + e];
        int slot = atomicAdd(&curP[row], 1);
        csrP[offP[row] + slot] = col;
    } else if (e < EP_N + EN_N) {
        int e2 = e - EP_N;
        int row = ne[e2], col = ne[EN_N + e2];
        int slot = atomicAdd(&curN[row], 1);
        csrN[offN[row] + slot] = col;
    }
}

// gather-mean of bf16 rows (2B/lane)
__device__ inline float gather_mean_b(const unsigned short* __restrict__ src,
                                      const int* __restrict__ csr,
                                      int st, int en, int lane) {
    float s0 = 0.f, s1 = 0.f, s2 = 0.f, s3 = 0.f;
    for (int p = st; p < en; p += 4) {
        int c0 = csr[p];
        int c1 = csr[min(p + 1, en - 1)];
        int c2 = csr[min(p + 2, en - 1)];
        int c3 = csr[min(p + 3, en - 1)];
        float v0 = bf2f(src[c0 * 64 + lane]);
        float v1 = bf2f(src[c1 * 64 + lane]);
        float v2 = bf2f(src[c2 * 64 + lane]);
        float v3 = bf2f(src[c3 * 64 + lane]);
        s0 += v0;
        s1 += (p + 1 < en) ? v1 : 0.f;
        s2 += (p + 2 < en) ? v2 : 0.f;
        s3 += (p + 3 < en) ? v3 : 0.f;
    }
    return ((s0 + s1) + (s2 + s3)) / fmaxf((float)(en - st), 1.0f);
}

// gather-mean of interleaved (hp,hn) u32 rows -> two means
__device__ inline void gather2(const unsigned* __restrict__ hb32,
                               const int* __restrict__ csr,
                               int st, int en, int lane, float& mp, float& mn) {
    float p0 = 0.f, p1 = 0.f, p2 = 0.f, p3 = 0.f;
    float n0 = 0.f, n1 = 0.f, n2 = 0.f, n3 = 0.f;
    for (int p = st; p < en; p += 4) {
        int c0 = csr[p];
        int c1 = csr[min(p + 1, en - 1)];
        int c2 = csr[min(p + 2, en - 1)];
        int c3 = csr[min(p + 3, en - 1)];
        unsigned v0 = hb32[c0 * 64 + lane];
        unsigned v1 = hb32[c1 * 64 + lane];
        unsigned v2 = hb32[c2 * 64 + lane];
        unsigned v3 = hb32[c3 * 64 + lane];
        p0 += lo_bf(v0); n0 += hi_bf(v0);
        p1 += (p + 1 < en) ? lo_bf(v1) : 0.f;
        n1 += (p + 1 < en) ? hi_bf(v1) : 0.f;
        p2 += (p + 2 < en) ? lo_bf(v2) : 0.f;
        n2 += (p + 2 < en) ? hi_bf(v2) : 0.f;
        p3 += (p + 3 < en) ? lo_bf(v3) : 0.f;
        n3 += (p + 3 < en) ? hi_bf(v3) : 0.f;
    }
    float d = 1.0f / fmaxf((float)(en - st), 1.0f);
    mp = ((p0 + p1) + (p2 + p3)) * d;
    mn = ((n0 + n1) + (n2 + n3)) * d;
}

// both base layers: gather (bf16) -> MFMA GEMM -> tanh -> interleaved bf16 h
__global__ __launch_bounds__(512) void base_both(
    const unsigned short* __restrict__ xb,
    const int* __restrict__ offP, const int* __restrict__ csrP,
    const int* __restrict__ offN, const int* __restrict__ csrN,
    const unsigned short* __restrict__ wt0,   // [Wt0p(64x128) | Wt0n(64x128)]
    const float* __restrict__ bp0, const float* __restrict__ bn0,
    unsigned short* __restrict__ hboth) {
    __shared__ unsigned short lds[64 * BSTR];
    int tid = threadIdx.x, lane = tid & 63, w = tid >> 6;
    int base = blockIdx.x * 64;
    for (int r = w * 8; r < w * 8 + 8; ++r) {
        int node = base + r;
        float gP = 0.f, gN = 0.f;
        unsigned short sx = 0;
        if (node < N_NODES) {
            gP = gather_mean_b(xb, csrP, offP[node], offP[node + 1], lane);
            gN = gather_mean_b(xb, csrN, offN[node], offN[node + 1], lane);
            sx = xb[node * 64 + lane];
        }
        unsigned short* rp = &lds[r * BSTR];
        rp[lane] = f2bf(gP);
        rp[64 + lane] = sx;
        rp[128 + lane] = f2bf(gN);
        rp[192 + lane] = sx;
    }
    __syncthreads();
    int wu = __builtin_amdgcn_readfirstlane(w);
    int mt = wu >> 1, half = wu & 1;
    int l15 = lane & 15, kq = lane >> 4;
    const unsigned short* wbase = wt0 + half * 8192;
    f32x4 acc[4];
#pragma unroll
    for (int nt = 0; nt < 4; ++nt) acc[nt] = (f32x4){0.f, 0.f, 0.f, 0.f};
    const unsigned short* arow = &lds[(mt * 16 + l15) * BSTR + half * 128 + kq * 8];
#pragma unroll
    for (int ks = 0; ks < 4; ++ks) {
        sh8 a = *(const sh8*)(arow + ks * 32);
#pragma unroll
        for (int nt = 0; nt < 4; ++nt) {
            sh8 bf = *(const sh8*)(wbase + (nt * 16 + l15) * 128 + ks * 32 + kq * 8);
            acc[nt] = __builtin_amdgcn_mfma_f32_16x16x32_bf16(a, bf, acc[nt], 0, 0, 0);
        }
    }
    __syncthreads();
    float* ht = (float*)lds;  // [64][130]
    const float* bias = half ? bn0 : bp0;
#pragma unroll
    for (int nt = 0; nt < 4; ++nt) {
        int col = nt * 16 + l15;
        float bb = bias[col];
#pragma unroll
        for (int r = 0; r < 4; ++r) {
            int row = mt * 16 + kq * 4 + r;
            ht[row * 130 + half * 64 + col] = tanhf(acc[nt][r] + bb);
        }
    }
    __syncthreads();
    unsigned* hb32 = (unsigned*)hboth;
    for (int i = tid; i < 64 * 64; i += 512) {
        int rr = i >> 6, c = i & 63;
        int node = base + rr;
        if (node < N_NODES) {
            unsigned lo = f2bf(ht[rr * 130 + c]);
            unsigned hi = f2bf(ht[rr * 130 + 64 + c]);
            hb32[node * 64 + c] = lo | (hi << 16);
        }
    }
}

// both deep layers: gather -> MFMA GEMM -> tanh -> z/zq/pn epilogue (fp8-consistent)
__global__ __launch_bounds__(512) void deep_both(
    const unsigned short* __restrict__ hb,
    const int* __restrict__ offP, const int* __restrict__ csrP,
    const int* __restrict__ offN, const int* __restrict__ csrN,
    const unsigned short* __restrict__ wt1,   // [Wt1p(32x192) | Wt1n(32x192)]
    const float* __restrict__ bp1, const float* __restrict__ bn1,
    const float* __restrict__ Wreg, float* __restrict__ z,
    unsigned char* __restrict__ zq, float* __restrict__ pn) {
    __shared__ unsigned short lds[64 * DSTR];
    int tid = threadIdx.x, lane = tid & 63, w = tid >> 6;
    int base = blockIdx.x * 64;
    const unsigned* hb32 = (const unsigned*)hb;
    for (int r = w * 8; r < w * 8 + 8; ++r) {
        int node = base + r;
        float gPp = 0.f, gPn = 0.f, gNp = 0.f, gNn = 0.f, sp = 0.f, sn = 0.f;
        if (node < N_NODES) {
            gather2(hb32, csrP, offP[node], offP[node + 1], lane, gPp, gPn);
            gather2(hb32, csrN, offN[node], offN[node + 1], lane, gNp, gNn);
            unsigned self = hb32[node * 64 + lane];
            sp = lo_bf(self);
            sn = hi_bf(self);
        }
        unsigned short* rp = &lds[r * DSTR];
        rp[lane] = f2bf(gPp);        // posIn[0:64]   = gm(h_pos, csrP)
        rp[64 + lane] = f2bf(gNn);   // posIn[64:128] = gm(h_neg, csrN)
        rp[128 + lane] = f2bf(sp);   // posIn[128:192]= h_pos self
        rp[192 + lane] = f2bf(gPn);  // negIn[0:64]   = gm(h_neg, csrP)
        rp[256 + lane] = f2bf(gNp);  // negIn[64:128] = gm(h_pos, csrN)
        rp[320 + lane] = f2bf(sn);   // negIn[128:192]= h_neg self
    }
    __syncthreads();
    int wu = __builtin_amdgcn_readfirstlane(w);
    int mt = wu >> 1, half = wu & 1;
    int l15 = lane & 15, kq = lane >> 4;
    const unsigned short* wbase = wt1 + half * 6144;
    f32x4 acc[2];
    acc[0] = (f32x4){0.f, 0.f, 0.f, 0.f};
    acc[1] = (f32x4){0.f, 0.f, 0.f, 0.f};
    const unsigned short* arow = &lds[(mt * 16 + l15) * DSTR + half * 192 + kq * 8];
#pragma unroll
    for (int ks = 0; ks < 6; ++ks) {
        sh8 a = *(const sh8*)(arow + ks * 32);
#pragma unroll
        for (int nt = 0; nt < 2; ++nt) {
            sh8 bf = *(const sh8*)(wbase + (nt * 16 + l15) * 192 + ks * 32 + kq * 8);
            acc[nt] = __builtin_amdgcn_mfma_f32_16x16x32_bf16(a, bf, acc[nt], 0, 0, 0);
        }
    }
    __syncthreads();
    float* ot = (float*)lds;  // [64][65]
    const float* bias = half ? bn1 : bp1;
#pragma unroll
    for (int nt = 0; nt < 2; ++nt) {
        int col = nt * 16 + l15;
        float bb = bias[col];
#pragma unroll
        for (int r = 0; r < 4; ++r) {
            int row = mt * 16 + kq * 4 + r;
            ot[row * 65 + half * 32 + col] = tanhf(acc[nt][r] + bb);
        }
    }
    __syncthreads();
    // epilogue: z write + fp8 copy + per-node loss projections from fp8 values
    for (int r = w * 8; r < w * 8 + 8; ++r) {
        int node = base + r;
        if (node >= N_NODES) break;
        float v = ot[r * 65 + lane];
        z[node * 64 + lane] = v;
        int pq = __builtin_amdgcn_cvt_pk_fp8_f32(v, v, 0, false);
        zq[node * 64 + lane] = (unsigned char)(pq & 0xFF);
        float vq = __builtin_amdgcn_cvt_f32_fp8(pq, 0);
        float u0 = vq * Wreg[lane * 2 + 0];
        float u1 = vq * Wreg[lane * 2 + 1];
        float v0 = vq * Wreg[128 + lane * 2 + 0];
        float v1 = vq * Wreg[128 + lane * 2 + 1];
        float s = vq * vq;
#pragma unroll
        for (int off = 32; off; off >>= 1) {
            u0 += __shfl_xor(u0, off);
            u1 += __shfl_xor(u1, off);
            v0 += __shfl_xor(v0, off);
            v1 += __shfl_xor(v1, off);
            s += __shfl_xor(s, off);
        }
        if (lane == 0) {
            float4 st = {u0, u1, v0, v1};
            *(float4*)(pn + node * 8) = st;
            pn[node * 8 + 4] = s;
        }
    }
}

// 4 edges per wave (16-lane groups): fp8 rows, cross-dots + precomputed node scalars
__global__ __launch_bounds__(256) void loss2_kernel(
    const unsigned char* __restrict__ zq, const float* __restrict__ pn,
    const int* __restrict__ pe, const int* __restrict__ ne,
    const int* __restrict__ ps, const int* __restrict__ ns,
    const int* __restrict__ tgt, float* acc) {
    int tid = threadIdx.x;
    int lane = tid & 63;
    int g = lane >> 4, sub = lane & 15;
    int wid = (blockIdx.x * 256 + tid) >> 6;
    int nw = (gridDim.x * 256) >> 6;
    float s_p = 0.f, s_n = 0.f, s_r = 0.f;
    const float q = 0.0625f;
    for (int eb = wid * 4; eb < EP_N + EN_N; eb += nw * 4) {
        int e = eb + g;
        bool valid = e < EP_N + EN_N;
        bool isp = e < EP_N;
        int i = 0, j = 0, k = 0, t = 0;
        if (valid) {
            if (isp) {
                i = pe[e]; j = pe[EP_N + e]; k = ps[e];
            } else {
                int e2 = e - EP_N;
                i = ne[e2]; j = ne[EN_N + e2]; k = ns[e2];
            }
            t = tgt[e];
        }
        unsigned zi4 = *(const unsigned*)(zq + ((long long)i << 6) + (sub << 2));
        unsigned zj4 = *(const unsigned*)(zq + ((long long)j << 6) + (sub << 2));
        unsigned zk4 = *(const unsigned*)(zq + ((long long)k << 6) + (sub << 2));
        float i0 = __builtin_amdgcn_cvt_f32_fp8(zi4, 0);
        float i1 = __builtin_amdgcn_cvt_f32_fp8(zi4, 1);
        float i2 = __builtin_amdgcn_cvt_f32_fp8(zi4, 2);
        float i3 = __builtin_amdgcn_cvt_f32_fp8(zi4, 3);
        float j0 = __builtin_amdgcn_cvt_f32_fp8(zj4, 0);
        float j1 = __builtin_amdgcn_cvt_f32_fp8(zj4, 1);
        float j2 = __builtin_amdgcn_cvt_f32_fp8(zj4, 2);
        float j3 = __builtin_amdgcn_cvt_f32_fp8(zj4, 3);
        float k0 = __builtin_amdgcn_cvt_f32_fp8(zk4, 0);
        float k1 = __builtin_amdgcn_cvt_f32_fp8(zk4, 1);
        float k2 = __builtin_amdgcn_cvt_f32_fp8(zk4, 2);
        float k3 = __builtin_amdgcn_cvt_f32_fp8(zk4, 3);
        float d1 = fmaf(i0, j0, fmaf(i1, j1, fmaf(i2, j2, i3 * j3)));
        float d2 = fmaf(j0, k0, fmaf(j1, k1, fmaf(j2, k2, j3 * k3)));
#pragma unroll
        for (int off = 1; off < 16; off <<= 1) {
            d1 += __shfl_xor(d1, off);
            d2 += __shfl_xor(d2, off);
        }
        if (valid) {
            const float* pni = pn + ((long long)i << 3);
            const float* pnj = pn + ((long long)j << 3);
            float u0 = pni[0], u1 = pni[1], si = pni[4];
            float v0 = pnj[2], v1 = pnj[3], sj = pnj[4];
            float sk = pn[((long long)k << 3) + 4];
            float nij = si + sj - 2.f * d1;
            float nik = sj + sk - 2.f * d2;
            float tri = fmaxf(nij - nik, 0.f);
            float l0 = u0 + v0, l1 = u1 + v1;
            float m = fmaxf(l0, l1);
            float lse = m + logf(expf(l0 - m) + expf(l1 - m));
            float r = lse - (t ? l1 : l0);
            s_r += r * q;
            if (isp) s_p += tri * q; else s_n += tri * q;
        }
    }
#pragma unroll
    for (int off = 32; off; off >>= 1) {
        s_p += __shfl_xor(s_p, off);
        s_n += __shfl_xor(s_n, off);
        s_r += __shfl_xor(s_r, off);
    }
    __shared__ float red[3][4];
    int w = tid >> 6;
    if (lane == 0) {
        red[0][w] = s_p; red[1][w] = s_n; red[2][w] = s_r;
    }
    __syncthreads();
    if (tid == 0) {
        atomicAdd(&acc[0], red[0][0] + red[0][1] + red[0][2] + red[0][3]);
        atomicAdd(&acc[1], red[1][0] + red[1][1] + red[1][2] + red[1][3]);
        atomicAdd(&acc[2], red[2][0] + red[2][1] + red[2][2] + red[2][3]);
    }
}

__global__ void finalize_kernel(const float* __restrict__ acc, float* out) {
    out[0] = acc[2] / (float)(EP_N + EN_N) +
             1.0f * (acc[0] / (float)EP_N + acc[1] / (float)EN_N);
}

extern "C" void kernel_launch(void* const* d_in, const int* in_sizes, int n_in,
                              void* d_out, int out_size, void* d_ws, size_t ws_size,
                              hipStream_t stream) {
    const float* X = (const float*)d_in[0];
    const float* W_pos0 = (const float*)d_in[1];
    const float* b_pos0 = (const float*)d_in[2];
    const float* W_neg0 = (const float*)d_in[3];
    const float* b_neg0 = (const float*)d_in[4];
    const float* W_pos1 = (const float*)d_in[5];
    const float* b_pos1 = (const float*)d_in[6];
    const float* W_neg1 = (const float*)d_in[7];
    const float* b_neg1 = (const float*)d_in[8];
    const float* W_reg = (const float*)d_in[9];
    const int* pe = (const int*)d_in[10];
    const int* ne = (const int*)d_in[11];
    const int* target = (const int*)d_in[12];
    const int* ps = (const int*)d_in[13];
    const int* ns = (const int*)d_in[14];
    float* out = (float*)d_out;
    float* ws = (float*)d_ws;
    int* wsi = (int*)d_ws;

    float* acc = ws + ACC_OFF;
    int* cntP = wsi + I_CNTP;
    int* cntN = wsi + I_CNTN;
    int* curP = wsi + I_CURP;
    int* curN = wsi + I_CURN;
    int* offP = wsi + I_OFFP;
    int* offN = wsi + I_OFFN;
    int* csrP = wsi + I_CSRP;
    int* csrN = wsi + I_CSRN;
    int* part = wsi + I_PART;
    unsigned short* xb = (unsigned short*)(ws + F_XB);
    unsigned short* hboth = (unsigned short*)(ws + F_HB);
    float* pn = ws + F_PN;
    unsigned char* zq = (unsigned char*)(ws + F_ZQ);
    unsigned short* wt = (unsigned short*)(ws + F_WT);
    float* z = out + 1;

    hipMemsetAsync(ws, 0, (size_t)(16 + 4 * N_NODES) * sizeof(float), stream);

    x_to_bf<<<(N_NODES * 16 + 255) / 256, 256, 0, stream>>>(X, xb);
    wprep<<<112, 256, 0, stream>>>(W_pos0, W_neg0, W_pos1, W_neg1, wt);
    count_kernel<<<(EP_N + EN_N + 255) / 256, 256, 0, stream>>>(pe, ne, cntP, cntN);
    scan_p1<<<2 * SBLK, 512, 0, stream>>>(cntP, cntN, part);
    scan_p2<<<1, 512, 0, stream>>>(part);
    scan_p3<<<2 * SBLK, 512, 0, stream>>>(cntP, cntN, part, offP, offN);
    fill_kernel<<<(EP_N + EN_N + 255) / 256, 256, 0, stream>>>(pe, ne, offP, offN,
                                                               curP, curN, csrP, csrN);

    base_both<<<NODE_BLOCKS, 512, 0, stream>>>(xb, offP, csrP, offN, csrN,
                                               wt, b_pos0, b_neg0, hboth);
    deep_both<<<NODE_BLOCKS, 512, 0, stream>>>(hboth, offP, csrP, offN, csrN,
                                               wt + 16384, b_pos1, b_neg1,
                                               W_reg, z, zq, pn);

    loss2_kernel<<<2048, 256, 0, stream>>>(zq, pn, pe, ne, ps, ns, target, acc);
    finalize_kernel<<<1, 1, 0, stream>>>(acc, out);
}

// Round 9
// 418.937 us; speedup vs baseline: 1.1783x; 1.0173x over previous
//
#include <hip/hip_runtime.h>
#include <cstdint>

#define N_NODES 100000
#define EP_N 400000
#define EN_N 400000
#define NODE_BLOCKS ((N_NODES + 63) / 64)
#define SCHUNK 512
#define SBLK ((N_NODES + SCHUNK - 1) / SCHUNK)

#define BSTR 264   // base LDS row: [gP(64) | X(64) | gN(64) | X(64)] + 8 pad (ushorts)
#define DSTR 392   // deep LDS row: [posIn(192) | negIn(192)] + 8 pad (ushorts)

// prep_kernel block ranges
#define XB_BLKS ((((N_NODES + 1) * 16) + 255) / 256)
#define WP_BLKS 112
#define CNT_BLKS (((EP_N + EN_N) + 255) / 256)

// ws layout (in 4-byte units)
#define ACC_OFF 0
#define I_CNTP 16
#define I_CNTN (I_CNTP + N_NODES)
#define I_CURP (I_CNTN + N_NODES)
#define I_CURN (I_CURP + N_NODES)
#define I_OFFP (I_CURN + N_NODES)
#define I_OFFN (I_OFFP + N_NODES + 1)
#define I_CSRP (((I_OFFN + N_NODES + 1) + 3) & ~3)
#define CSR_SZ (EP_N + 4 * N_NODES)
#define I_CSRN (I_CSRP + CSR_SZ)
#define I_PART (I_CSRN + CSR_SZ)
#define F_XB (((I_PART + 2 * SBLK) + 15) & ~15)   // xb: (N+1)*64 ushort
#define F_HB (F_XB + 32 * (N_NODES + 1))          // hboth: (N+1)*64 u32
#define F_PN (F_HB + 64 * (N_NODES + 1))          // pn: N*8 floats
#define F_ZQ (F_PN + 8 * N_NODES)                 // zq: N*64 bytes
#define F_WT (((F_ZQ + 16 * N_NODES) + 15) & ~15) // wt: 28672 ushorts

typedef __attribute__((ext_vector_type(8))) short sh8;
typedef __attribute__((ext_vector_type(4))) float f32x4;

__device__ inline float bf2f(unsigned short u) {
    return __uint_as_float((unsigned)u << 16);
}
__device__ inline unsigned short f2bf(float v) {
    unsigned u = __float_as_uint(v);
    return (unsigned short)((u + 0x7FFFu + ((u >> 16) & 1u)) >> 16);
}
__device__ inline float lo_bf(unsigned u) { return __uint_as_float(u << 16); }
__device__ inline float hi_bf(unsigned u) { return __uint_as_float(u & 0xFFFF0000u); }

// fused: X->bf16 (incl. zero sentinel row) | weight transpose->bf16 | degree count
__global__ void prep_kernel(const float* __restrict__ X, unsigned short* __restrict__ xb,
                            const float* __restrict__ W0p, const float* __restrict__ W0n,
                            const float* __restrict__ W1p, const float* __restrict__ W1n,
                            unsigned short* __restrict__ wt,
                            const int* __restrict__ pe, const int* __restrict__ ne,
                            int* cp, int* cn) {
    int b = blockIdx.x;
    if (b < XB_BLKS) {
        int i = b * 256 + threadIdx.x;
        if (i < (N_NODES + 1) * 16) {
            ushort4 o = {0, 0, 0, 0};
            if (i < N_NODES * 16) {
                float4 v = ((const float4*)X)[i];
                o.x = f2bf(v.x); o.y = f2bf(v.y); o.z = f2bf(v.z); o.w = f2bf(v.w);
            }
            ((ushort4*)xb)[i] = o;
        }
    } else if (b < XB_BLKS + WP_BLKS) {
        int i = (b - XB_BLKS) * 256 + threadIdx.x;
        if (i < 8192) {
            int n = i >> 7, k = i & 127;
            wt[i] = f2bf(W0p[k * 64 + n]);
        } else if (i < 16384) {
            int j = i - 8192; int n = j >> 7, k = j & 127;
            wt[i] = f2bf(W0n[k * 64 + n]);
        } else if (i < 22528) {
            int j = i - 16384; int n = j / 192, k = j - n * 192;
            wt[i] = f2bf(W1p[k * 32 + n]);
        } else if (i < 28672) {
            int j = i - 22528; int n = j / 192, k = j - n * 192;
            wt[i] = f2bf(W1n[k * 32 + n]);
        }
    } else {
        int i = (b - XB_BLKS - WP_BLKS) * 256 + threadIdx.x;
        if (i < EP_N) {
            atomicAdd(&cp[pe[i]], 1);
        } else if (i < EP_N + EN_N) {
            atomicAdd(&cn[ne[i - EP_N]], 1);
        }
    }
}

__global__ __launch_bounds__(512) void scan_p1(const int* __restrict__ cntP,
                                               const int* __restrict__ cntN,
                                               int* part) {
    int l = blockIdx.x < SBLK ? 0 : 1;
    int blk = blockIdx.x - l * SBLK;
    const int* cnt = l == 0 ? cntP : cntN;
    int idx = blk * SCHUNK + threadIdx.x;
    int v = idx < N_NODES ? (cnt[idx] + 3) & ~3 : 0;   // padded counts
    __shared__ int tmp[512];
    tmp[threadIdx.x] = v;
    __syncthreads();
    for (int d = 256; d > 0; d >>= 1) {
        if (threadIdx.x < d) tmp[threadIdx.x] += tmp[threadIdx.x + d];
        __syncthreads();
    }
    if (threadIdx.x == 0) part[l * SBLK + blk] = tmp[0];
}

__global__ __launch_bounds__(512) void scan_p2(int* part) {
    int t = threadIdx.x;
    int l = t >> 8, idx = t & 255;
    int v = idx < SBLK ? part[l * SBLK + idx] : 0;
    __shared__ int tmp[512];
    int sb = l << 8;
    tmp[sb + idx] = v;
    __syncthreads();
    for (int d = 1; d < 256; d <<= 1) {
        int x = (idx >= d) ? tmp[sb + idx - d] : 0;
        __syncthreads();
        tmp[sb + idx] += x;
        __syncthreads();
    }
    if (idx < SBLK) part[l * SBLK + idx] = tmp[sb + idx] - v;
}

// padded offsets + sentinel pad fill
__global__ __launch_bounds__(512) void scan_p3(const int* __restrict__ cntP,
                                               const int* __restrict__ cntN,
                                               const int* __restrict__ part,
                                               int* offP, int* offN,
                                               int* csrP, int* csrN) {
    int l = blockIdx.x < SBLK ? 0 : 1;
    int blk = blockIdx.x - l * SBLK;
    const int* cnt = l == 0 ? cntP : cntN;
    int* off = l == 0 ? offP : offN;
    int* csr = l == 0 ? csrP : csrN;
    int base = part[l * SBLK + blk];
    int t = threadIdx.x;
    int gidx = blk * SCHUNK + t;
    int c = gidx < N_NODES ? cnt[gidx] : 0;
    int cpad = (c + 3) & ~3;
    __shared__ int tmp[512];
    tmp[t] = cpad;
    __syncthreads();
    for (int d = 1; d < 512; d <<= 1) {
        int x = (t >= d) ? tmp[t - d] : 0;
        __syncthreads();
        tmp[t] += x;
        __syncthreads();
    }
    int incl = tmp[t];
    if (gidx < N_NODES) {
        int o = base + incl - cpad;
        off[gidx] = o;
        for (int p = c; p < cpad; ++p) csr[o + p] = N_NODES;  // sentinel pads
    }
    if (gidx == N_NODES - 1) off[N_NODES] = base + incl;
}

__global__ void fill_kernel(const int* __restrict__ pe, const int* __restrict__ ne,
                            const int* __restrict__ offP, const int* __restrict__ offN,
                            int* curP, int* curN, int* csrP, int* csrN) {
    int e = blockIdx.x * 256 + threadIdx.x;
    if (e < EP_N) {
        int row = pe[e], col = pe[EP_N + e];
        int slot = atomicAdd(&curP[row], 1);
        csrP[offP[row] + slot] = col;
    } else if (e < EP_N + EN_N) {
        int e2 = e - EP_N;
        int row = ne[e2], col = ne[EN_N + e2];
        int slot = atomicAdd(&curN[row], 1);
        csrN[offN[row] + slot] = col;
    }
}

// unmasked padded gather-mean (bf16 rows); st/en 4-aligned, cnt = true degree
__device__ inline float gather_mean_b(const unsigned short* __restrict__ src,
                                      const int* __restrict__ csr,
                                      int st, int en, int cnt, int lane) {
    float s0 = 0.f, s1 = 0.f, s2 = 0.f, s3 = 0.f;
    for (int p = st; p < en; p += 4) {
        int4 c4 = *(const int4*)(csr + p);
        s0 += bf2f(src[c4.x * 64 + lane]);
        s1 += bf2f(src[c4.y * 64 + lane]);
        s2 += bf2f(src[c4.z * 64 + lane]);
        s3 += bf2f(src[c4.w * 64 + lane]);
    }
    return ((s0 + s1) + (s2 + s3)) / fmaxf((float)cnt, 1.0f);
}

// unmasked padded gather-mean of interleaved (hp,hn) u32 rows -> two means
__device__ inline void gather2(const unsigned* __restrict__ hb32,
                               const int* __restrict__ csr,
                               int st, int en, int cnt, int lane,
                               float& mp, float& mn) {
    float p0 = 0.f, p1 = 0.f, p2 = 0.f, p3 = 0.f;
    float n0 = 0.f, n1 = 0.f, n2 = 0.f, n3 = 0.f;
    for (int p = st; p < en; p += 4) {
        int4 c4 = *(const int4*)(csr + p);
        unsigned v0 = hb32[c4.x * 64 + lane];
        unsigned v1 = hb32[c4.y * 64 + lane];
        unsigned v2 = hb32[c4.z * 64 + lane];
        unsigned v3 = hb32[c4.w * 64 + lane];
        p0 += lo_bf(v0); n0 += hi_bf(v0);
        p1 += lo_bf(v1); n1 += hi_bf(v1);
        p2 += lo_bf(v2); n2 += hi_bf(v2);
        p3 += lo_bf(v3); n3 += hi_bf(v3);
    }
    float d = 1.0f / fmaxf((float)cnt, 1.0f);
    mp = ((p0 + p1) + (p2 + p3)) * d;
    mn = ((n0 + n1) + (n2 + n3)) * d;
}

// both base layers: gather (bf16) -> MFMA GEMM -> tanh -> interleaved bf16 h
__global__ __launch_bounds__(512) void base_both(
    const unsigned short* __restrict__ xb,
    const int* __restrict__ offP, const int* __restrict__ csrP,
    const int* __restrict__ offN, const int* __restrict__ csrN,
    const int* __restrict__ cntP, const int* __restrict__ cntN,
    const unsigned short* __restrict__ wt0,
    const float* __restrict__ bp0, const float* __restrict__ bn0,
    unsigned short* __restrict__ hboth) {
    __shared__ unsigned short lds[64 * BSTR];
    int tid = threadIdx.x, lane = tid & 63, w = tid >> 6;
    int base = blockIdx.x * 64;
    // zero sentinel row of hboth (once, before deep_both runs)
    if (blockIdx.x == 0 && tid < 64) ((unsigned*)hboth)[N_NODES * 64 + tid] = 0u;
    for (int r = w * 8; r < w * 8 + 8; ++r) {
        int node = base + r;
        float gP = 0.f, gN = 0.f;
        unsigned short sx = 0;
        if (node < N_NODES) {
            gP = gather_mean_b(xb, csrP, offP[node], offP[node + 1], cntP[node], lane);
            gN = gather_mean_b(xb, csrN, offN[node], offN[node + 1], cntN[node], lane);
            sx = xb[node * 64 + lane];
        }
        unsigned short* rp = &lds[r * BSTR];
        rp[lane] = f2bf(gP);
        rp[64 + lane] = sx;
        rp[128 + lane] = f2bf(gN);
        rp[192 + lane] = sx;
    }
    __syncthreads();
    int wu = __builtin_amdgcn_readfirstlane(w);
    int mt = wu >> 1, half = wu & 1;
    int l15 = lane & 15, kq = lane >> 4;
    const unsigned short* wbase = wt0 + half * 8192;
    f32x4 acc[4];
#pragma unroll
    for (int nt = 0; nt < 4; ++nt) acc[nt] = (f32x4){0.f, 0.f, 0.f, 0.f};
    const unsigned short* arow = &lds[(mt * 16 + l15) * BSTR + half * 128 + kq * 8];
#pragma unroll
    for (int ks = 0; ks < 4; ++ks) {
        sh8 a = *(const sh8*)(arow + ks * 32);
#pragma unroll
        for (int nt = 0; nt < 4; ++nt) {
            sh8 bf = *(const sh8*)(wbase + (nt * 16 + l15) * 128 + ks * 32 + kq * 8);
            acc[nt] = __builtin_amdgcn_mfma_f32_16x16x32_bf16(a, bf, acc[nt], 0, 0, 0);
        }
    }
    __syncthreads();
    float* ht = (float*)lds;  // [64][130]
    const float* bias = half ? bn0 : bp0;
#pragma unroll
    for (int nt = 0; nt < 4; ++nt) {
        int col = nt * 16 + l15;
        float bb = bias[col];
#pragma unroll
        for (int r = 0; r < 4; ++r) {
            int row = mt * 16 + kq * 4 + r;
            ht[row * 130 + half * 64 + col] = tanhf(acc[nt][r] + bb);
        }
    }
    __syncthreads();
    unsigned* hb32 = (unsigned*)hboth;
    for (int i = tid; i < 64 * 64; i += 512) {
        int rr = i >> 6, c = i & 63;
        int node = base + rr;
        if (node < N_NODES) {
            unsigned lo = f2bf(ht[rr * 130 + c]);
            unsigned hi = f2bf(ht[rr * 130 + 64 + c]);
            hb32[node * 64 + c] = lo | (hi << 16);
        }
    }
}

// both deep layers: gather -> MFMA GEMM -> tanh -> z/zq/pn epilogue (fp8-consistent)
__global__ __launch_bounds__(512) void deep_both(
    const unsigned short* __restrict__ hb,
    const int* __restrict__ offP, const int* __restrict__ csrP,
    const int* __restrict__ offN, const int* __restrict__ csrN,
    const int* __restrict__ cntP, const int* __restrict__ cntN,
    const unsigned short* __restrict__ wt1,
    const float* __restrict__ bp1, const float* __restrict__ bn1,
    const float* __restrict__ Wreg, float* __restrict__ z,
    unsigned char* __restrict__ zq, float* __restrict__ pn) {
    __shared__ unsigned short lds[64 * DSTR];
    int tid = threadIdx.x, lane = tid & 63, w = tid >> 6;
    int base = blockIdx.x * 64;
    const unsigned* hb32 = (const unsigned*)hb;
    for (int r = w * 8; r < w * 8 + 8; ++r) {
        int node = base + r;
        float gPp = 0.f, gPn = 0.f, gNp = 0.f, gNn = 0.f, sp = 0.f, sn = 0.f;
        if (node < N_NODES) {
            gather2(hb32, csrP, offP[node], offP[node + 1], cntP[node], lane, gPp, gPn);
            gather2(hb32, csrN, offN[node], offN[node + 1], cntN[node], lane, gNp, gNn);
            unsigned self = hb32[node * 64 + lane];
            sp = lo_bf(self);
            sn = hi_bf(self);
        }
        unsigned short* rp = &lds[r * DSTR];
        rp[lane] = f2bf(gPp);        // posIn[0:64]   = gm(h_pos, csrP)
        rp[64 + lane] = f2bf(gNn);   // posIn[64:128] = gm(h_neg, csrN)
        rp[128 + lane] = f2bf(sp);   // posIn[128:192]= h_pos self
        rp[192 + lane] = f2bf(gPn);  // negIn[0:64]   = gm(h_neg, csrP)
        rp[256 + lane] = f2bf(gNp);  // negIn[64:128] = gm(h_pos, csrN)
        rp[320 + lane] = f2bf(sn);   // negIn[128:192]= h_neg self
    }
    __syncthreads();
    int wu = __builtin_amdgcn_readfirstlane(w);
    int mt = wu >> 1, half = wu & 1;
    int l15 = lane & 15, kq = lane >> 4;
    const unsigned short* wbase = wt1 + half * 6144;
    f32x4 acc[2];
    acc[0] = (f32x4){0.f, 0.f, 0.f, 0.f};
    acc[1] = (f32x4){0.f, 0.f, 0.f, 0.f};
    const unsigned short* arow = &lds[(mt * 16 + l15) * DSTR + half * 192 + kq * 8];
#pragma unroll
    for (int ks = 0; ks < 6; ++ks) {
        sh8 a = *(const sh8*)(arow + ks * 32);
#pragma unroll
        for (int nt = 0; nt < 2; ++nt) {
            sh8 bf = *(const sh8*)(wbase + (nt * 16 + l15) * 192 + ks * 32 + kq * 8);
            acc[nt] = __builtin_amdgcn_mfma_f32_16x16x32_bf16(a, bf, acc[nt], 0, 0, 0);
        }
    }
    __syncthreads();
    float* ot = (float*)lds;  // [64][65]
    const float* bias = half ? bn1 : bp1;
#pragma unroll
    for (int nt = 0; nt < 2; ++nt) {
        int col = nt * 16 + l15;
        float bb = bias[col];
#pragma unroll
        for (int r = 0; r < 4; ++r) {
            int row = mt * 16 + kq * 4 + r;
            ot[row * 65 + half * 32 + col] = tanhf(acc[nt][r] + bb);
        }
    }
    __syncthreads();
    for (int r = w * 8; r < w * 8 + 8; ++r) {
        int node = base + r;
        if (node >= N_NODES) break;
        float v = ot[r * 65 + lane];
        z[node * 64 + lane] = v;
        int pq = __builtin_amdgcn_cvt_pk_fp8_f32(v, v, 0, false);
        zq[node * 64 + lane] = (unsigned char)(pq & 0xFF);
        float vq = __builtin_amdgcn_cvt_f32_fp8(pq, 0);
        float u0 = vq * Wreg[lane * 2 + 0];
        float u1 = vq * Wreg[lane * 2 + 1];
        float v0 = vq * Wreg[128 + lane * 2 + 0];
        float v1 = vq * Wreg[128 + lane * 2 + 1];
        float s = vq * vq;
#pragma unroll
        for (int off = 32; off; off >>= 1) {
            u0 += __shfl_xor(u0, off);
            u1 += __shfl_xor(u1, off);
            v0 += __shfl_xor(v0, off);
            v1 += __shfl_xor(v1, off);
            s += __shfl_xor(s, off);
        }
        if (lane == 0) {
            float4 st = {u0, u1, v0, v1};
            *(float4*)(pn + node * 8) = st;
            pn[node * 8 + 4] = s;
        }
    }
}

// 4 edges per wave (16-lane groups): fp8 rows, cross-dots + precomputed node scalars
__global__ __launch_bounds__(256) void loss2_kernel(
    const unsigned char* __restrict__ zq, const float* __restrict__ pn,
    const int* __restrict__ pe, const int* __restrict__ ne,
    const int* __restrict__ ps, const int* __restrict__ ns,
    const int* __restrict__ tgt, float* acc) {
    int tid = threadIdx.x;
    int lane = tid & 63;
    int g = lane >> 4, sub = lane & 15;
    int wid = (blockIdx.x * 256 + tid) >> 6;
    int nw = (gridDim.x * 256) >> 6;
    float s_p = 0.f, s_n = 0.f, s_r = 0.f;
    const float q = 0.0625f;
    for (int eb = wid * 4; eb < EP_N + EN_N; eb += nw * 4) {
        int e = eb + g;
        bool valid = e < EP_N + EN_N;
        bool isp = e < EP_N;
        int i = 0, j = 0, k = 0, t = 0;
        if (valid) {
            if (isp) {
                i = pe[e]; j = pe[EP_N + e]; k = ps[e];
            } else {
                int e2 = e - EP_N;
                i = ne[e2]; j = ne[EN_N + e2]; k = ns[e2];
            }
            t = tgt[e];
        }
        unsigned zi4 = *(const unsigned*)(zq + ((long long)i << 6) + (sub << 2));
        unsigned zj4 = *(const unsigned*)(zq + ((long long)j << 6) + (sub << 2));
        unsigned zk4 = *(const unsigned*)(zq + ((long long)k << 6) + (sub << 2));
        float i0 = __builtin_amdgcn_cvt_f32_fp8(zi4, 0);
        float i1 = __builtin_amdgcn_cvt_f32_fp8(zi4, 1);
        float i2 = __builtin_amdgcn_cvt_f32_fp8(zi4, 2);
        float i3 = __builtin_amdgcn_cvt_f32_fp8(zi4, 3);
        float j0 = __builtin_amdgcn_cvt_f32_fp8(zj4, 0);
        float j1 = __builtin_amdgcn_cvt_f32_fp8(zj4, 1);
        float j2 = __builtin_amdgcn_cvt_f32_fp8(zj4, 2);
        float j3 = __builtin_amdgcn_cvt_f32_fp8(zj4, 3);
        float k0 = __builtin_amdgcn_cvt_f32_fp8(zk4, 0);
        float k1 = __builtin_amdgcn_cvt_f32_fp8(zk4, 1);
        float k2 = __builtin_amdgcn_cvt_f32_fp8(zk4, 2);
        float k3 = __builtin_amdgcn_cvt_f32_fp8(zk4, 3);
        float d1 = fmaf(i0, j0, fmaf(i1, j1, fmaf(i2, j2, i3 * j3)));
        float d2 = fmaf(j0, k0, fmaf(j1, k1, fmaf(j2, k2, j3 * k3)));
#pragma unroll
        for (int off = 1; off < 16; off <<= 1) {
            d1 += __shfl_xor(d1, off);
            d2 += __shfl_xor(d2, off);
        }
        if (valid) {
            const float* pni = pn + ((long long)i << 3);
            const float* pnj = pn + ((long long)j << 3);
            float u0 = pni[0], u1 = pni[1], si = pni[4];
            float v0 = pnj[2], v1 = pnj[3], sj = pnj[4];
            float sk = pn[((long long)k << 3) + 4];
            float nij = si + sj - 2.f * d1;
            float nik = sj + sk - 2.f * d2;
            float tri = fmaxf(nij - nik, 0.f);
            float l0 = u0 + v0, l1 = u1 + v1;
            float m = fmaxf(l0, l1);
            float lse = m + logf(expf(l0 - m) + expf(l1 - m));
            float r = lse - (t ? l1 : l0);
            s_r += r * q;
            if (isp) s_p += tri * q; else s_n += tri * q;
        }
    }
#pragma unroll
    for (int off = 32; off; off >>= 1) {
        s_p += __shfl_xor(s_p, off);
        s_n += __shfl_xor(s_n, off);
        s_r += __shfl_xor(s_r, off);
    }
    __shared__ float red[3][4];
    int w = tid >> 6;
    if (lane == 0) {
        red[0][w] = s_p; red[1][w] = s_n; red[2][w] = s_r;
    }
    __syncthreads();
    if (tid == 0) {
        atomicAdd(&acc[0], red[0][0] + red[0][1] + red[0][2] + red[0][3]);
        atomicAdd(&acc[1], red[1][0] + red[1][1] + red[1][2] + red[1][3]);
        atomicAdd(&acc[2], red[2][0] + red[2][1] + red[2][2] + red[2][3]);
    }
}

__global__ void finalize_kernel(const float* __restrict__ acc, float* out) {
    out[0] = acc[2] / (float)(EP_N + EN_N) +
             1.0f * (acc[0] / (float)EP_N + acc[1] / (float)EN_N);
}

extern "C" void kernel_launch(void* const* d_in, const int* in_sizes, int n_in,
                              void* d_out, int out_size, void* d_ws, size_t ws_size,
                              hipStream_t stream) {
    const float* X = (const float*)d_in[0];
    const float* W_pos0 = (const float*)d_in[1];
    const float* b_pos0 = (const float*)d_in[2];
    const float* W_neg0 = (const float*)d_in[3];
    const float* b_neg0 = (const float*)d_in[4];
    const float* W_pos1 = (const float*)d_in[5];
    const float* b_pos1 = (const float*)d_in[6];
    const float* W_neg1 = (const float*)d_in[7];
    const float* b_neg1 = (const float*)d_in[8];
    const float* W_reg = (const float*)d_in[9];
    const int* pe = (const int*)d_in[10];
    const int* ne = (const int*)d_in[11];
    const int* target = (const int*)d_in[12];
    const int* ps = (const int*)d_in[13];
    const int* ns = (const int*)d_in[14];
    float* out = (float*)d_out;
    float* ws = (float*)d_ws;
    int* wsi = (int*)d_ws;

    float* acc = ws + ACC_OFF;
    int* cntP = wsi + I_CNTP;
    int* cntN = wsi + I_CNTN;
    int* curP = wsi + I_CURP;
    int* curN = wsi + I_CURN;
    int* offP = wsi + I_OFFP;
    int* offN = wsi + I_OFFN;
    int* csrP = wsi + I_CSRP;
    int* csrN = wsi + I_CSRN;
    int* part = wsi + I_PART;
    unsigned short* xb = (unsigned short*)(ws + F_XB);
    unsigned short* hboth = (unsigned short*)(ws + F_HB);
    float* pn = ws + F_PN;
    unsigned char* zq = (unsigned char*)(ws + F_ZQ);
    unsigned short* wt = (unsigned short*)(ws + F_WT);
    float* z = out + 1;

    hipMemsetAsync(ws, 0, (size_t)(16 + 4 * N_NODES) * sizeof(float), stream);

    prep_kernel<<<XB_BLKS + WP_BLKS + CNT_BLKS, 256, 0, stream>>>(
        X, xb, W_pos0, W_neg0, W_pos1, W_neg1, wt, pe, ne, cntP, cntN);
    scan_p1<<<2 * SBLK, 512, 0, stream>>>(cntP, cntN, part);
    scan_p2<<<1, 512, 0, stream>>>(part);
    scan_p3<<<2 * SBLK, 512, 0, stream>>>(cntP, cntN, part, offP, offN, csrP, csrN);
    fill_kernel<<<(EP_N + EN_N + 255) / 256, 256, 0, stream>>>(pe, ne, offP, offN,
                                                               curP, curN, csrP, csrN);

    base_both<<<NODE_BLOCKS, 512, 0, stream>>>(xb, offP, csrP, offN, csrN, cntP, cntN,
                                               wt, b_pos0, b_neg0, hboth);
    deep_both<<<NODE_BLOCKS, 512, 0, stream>>>(hboth, offP, csrP, offN, csrN, cntP, cntN,
                                               wt + 16384, b_pos1, b_neg1,
                                               W_reg, z, zq, pn);

    loss2_kernel<<<2048, 256, 0, stream>>>(zq, pn, pe, ne, ps, ns, target, acc);
    finalize_kernel<<<1, 1, 0, stream>>>(acc, out);
}

// Round 10
// 410.353 us; speedup vs baseline: 1.2029x; 1.0209x over previous
//
#include <hip/hip_runtime.h>
#include <cstdint>

#define N_NODES 100000
#define EP_N 400000
#define EN_N 400000
#define NODE_BLOCKS ((N_NODES + 63) / 64)
#define SCHUNK 512
#define SBLK ((N_NODES + SCHUNK - 1) / SCHUNK)

#define BSTR 264   // base LDS row: [gP(64) | X(64) | gN(64) | X(64)] + 8 pad (ushorts)
#define DSTR 392   // deep LDS row: [posIn(192) | negIn(192)] + 8 pad (ushorts)

// prep_kernel block ranges
#define XB_BLKS ((((N_NODES + 1) * 16) + 255) / 256)
#define WP_BLKS 112
#define CNT_BLKS (((EP_N + EN_N) + 255) / 256)

// ws layout (in 4-byte units)
#define ACC_OFF 0
#define I_CNTP 16
#define I_CNTN (I_CNTP + N_NODES)
#define I_CURP (I_CNTN + N_NODES)
#define I_CURN (I_CURP + N_NODES)
#define I_OFFP (I_CURN + N_NODES)
#define I_OFFN (I_OFFP + N_NODES + 1)
#define I_CSRP (((I_OFFN + N_NODES + 1) + 3) & ~3)
#define CSR_SZ (EP_N + 4 * N_NODES)
#define I_CSRN (I_CSRP + CSR_SZ)
#define I_PART (I_CSRN + CSR_SZ)
#define F_XB (((I_PART + 2 * SBLK) + 15) & ~15)   // xb: (N+1)*64 ushort
#define F_HB (F_XB + 32 * (N_NODES + 1))          // hboth: (N+1)*64 u32
#define F_PN (F_HB + 64 * (N_NODES + 1))          // pn: N*8 floats
#define F_ZQ (F_PN + 8 * N_NODES)                 // zq: N*64 bytes
#define F_WT (((F_ZQ + 16 * N_NODES) + 15) & ~15) // wt: 28672 ushorts

typedef __attribute__((ext_vector_type(8))) short sh8;
typedef __attribute__((ext_vector_type(4))) float f32x4;

__device__ inline float bf2f(unsigned short u) {
    return __uint_as_float((unsigned)u << 16);
}
__device__ inline unsigned short f2bf(float v) {
    unsigned u = __float_as_uint(v);
    return (unsigned short)((u + 0x7FFFu + ((u >> 16) & 1u)) >> 16);
}
__device__ inline float lo_bf(unsigned u) { return __uint_as_float(u << 16); }
__device__ inline float hi_bf(unsigned u) { return __uint_as_float(u & 0xFFFF0000u); }

// fused: X->bf16 (incl. zero sentinel row) | weight transpose->bf16 | degree count
__global__ void prep_kernel(const float* __restrict__ X, unsigned short* __restrict__ xb,
                            const float* __restrict__ W0p, const float* __restrict__ W0n,
                            const float* __restrict__ W1p, const float* __restrict__ W1n,
                            unsigned short* __restrict__ wt,
                            const int* __restrict__ pe, const int* __restrict__ ne,
                            int* cp, int* cn) {
    int b = blockIdx.x;
    if (b < XB_BLKS) {
        int i = b * 256 + threadIdx.x;
        if (i < (N_NODES + 1) * 16) {
            ushort4 o = {0, 0, 0, 0};
            if (i < N_NODES * 16) {
                float4 v = ((const float4*)X)[i];
                o.x = f2bf(v.x); o.y = f2bf(v.y); o.z = f2bf(v.z); o.w = f2bf(v.w);
            }
            ((ushort4*)xb)[i] = o;
        }
    } else if (b < XB_BLKS + WP_BLKS) {
        int i = (b - XB_BLKS) * 256 + threadIdx.x;
        if (i < 8192) {
            int n = i >> 7, k = i & 127;
            wt[i] = f2bf(W0p[k * 64 + n]);
        } else if (i < 16384) {
            int j = i - 8192; int n = j >> 7, k = j & 127;
            wt[i] = f2bf(W0n[k * 64 + n]);
        } else if (i < 22528) {
            int j = i - 16384; int n = j / 192, k = j - n * 192;
            wt[i] = f2bf(W1p[k * 32 + n]);
        } else if (i < 28672) {
            int j = i - 22528; int n = j / 192, k = j - n * 192;
            wt[i] = f2bf(W1n[k * 32 + n]);
        }
    } else {
        int i = (b - XB_BLKS - WP_BLKS) * 256 + threadIdx.x;
        if (i < EP_N) {
            atomicAdd(&cp[pe[i]], 1);
        } else if (i < EP_N + EN_N) {
            atomicAdd(&cn[ne[i - EP_N]], 1);
        }
    }
}

__global__ __launch_bounds__(512) void scan_p1(const int* __restrict__ cntP,
                                               const int* __restrict__ cntN,
                                               int* part) {
    int l = blockIdx.x < SBLK ? 0 : 1;
    int blk = blockIdx.x - l * SBLK;
    const int* cnt = l == 0 ? cntP : cntN;
    int idx = blk * SCHUNK + threadIdx.x;
    int v = idx < N_NODES ? (cnt[idx] + 3) & ~3 : 0;   // padded counts
    __shared__ int tmp[512];
    tmp[threadIdx.x] = v;
    __syncthreads();
    for (int d = 256; d > 0; d >>= 1) {
        if (threadIdx.x < d) tmp[threadIdx.x] += tmp[threadIdx.x + d];
        __syncthreads();
    }
    if (threadIdx.x == 0) part[l * SBLK + blk] = tmp[0];
}

__global__ __launch_bounds__(512) void scan_p2(int* part) {
    int t = threadIdx.x;
    int l = t >> 8, idx = t & 255;
    int v = idx < SBLK ? part[l * SBLK + idx] : 0;
    __shared__ int tmp[512];
    int sb = l << 8;
    tmp[sb + idx] = v;
    __syncthreads();
    for (int d = 1; d < 256; d <<= 1) {
        int x = (idx >= d) ? tmp[sb + idx - d] : 0;
        __syncthreads();
        tmp[sb + idx] += x;
        __syncthreads();
    }
    if (idx < SBLK) part[l * SBLK + idx] = tmp[sb + idx] - v;
}

// padded offsets + sentinel pad fill
__global__ __launch_bounds__(512) void scan_p3(const int* __restrict__ cntP,
                                               const int* __restrict__ cntN,
                                               const int* __restrict__ part,
                                               int* offP, int* offN,
                                               int* csrP, int* csrN) {
    int l = blockIdx.x < SBLK ? 0 : 1;
    int blk = blockIdx.x - l * SBLK;
    const int* cnt = l == 0 ? cntP : cntN;
    int* off = l == 0 ? offP : offN;
    int* csr = l == 0 ? csrP : csrN;
    int base = part[l * SBLK + blk];
    int t = threadIdx.x;
    int gidx = blk * SCHUNK + t;
    int c = gidx < N_NODES ? cnt[gidx] : 0;
    int cpad = (c + 3) & ~3;
    __shared__ int tmp[512];
    tmp[t] = cpad;
    __syncthreads();
    for (int d = 1; d < 512; d <<= 1) {
        int x = (t >= d) ? tmp[t - d] : 0;
        __syncthreads();
        tmp[t] += x;
        __syncthreads();
    }
    int incl = tmp[t];
    if (gidx < N_NODES) {
        int o = base + incl - cpad;
        off[gidx] = o;
        for (int p = c; p < cpad; ++p) csr[o + p] = N_NODES;  // sentinel pads
    }
    if (gidx == N_NODES - 1) off[N_NODES] = base + incl;
}

__global__ void fill_kernel(const int* __restrict__ pe, const int* __restrict__ ne,
                            const int* __restrict__ offP, const int* __restrict__ offN,
                            int* curP, int* curN, int* csrP, int* csrN) {
    int e = blockIdx.x * 256 + threadIdx.x;
    if (e < EP_N) {
        int row = pe[e], col = pe[EP_N + e];
        int slot = atomicAdd(&curP[row], 1);
        csrP[offP[row] + slot] = col;
    } else if (e < EP_N + EN_N) {
        int e2 = e - EP_N;
        int row = ne[e2], col = ne[EN_N + e2];
        int slot = atomicAdd(&curN[row], 1);
        csrN[offN[row] + slot] = col;
    }
}

// unmasked padded gather-mean (bf16 rows); st/en 4-aligned, cnt = true degree
__device__ inline float gather_mean_b(const unsigned short* __restrict__ src,
                                      const int* __restrict__ csr,
                                      int st, int en, int cnt, int lane) {
    float s0 = 0.f, s1 = 0.f, s2 = 0.f, s3 = 0.f;
    for (int p = st; p < en; p += 4) {
        int4 c4 = *(const int4*)(csr + p);
        s0 += bf2f(src[c4.x * 64 + lane]);
        s1 += bf2f(src[c4.y * 64 + lane]);
        s2 += bf2f(src[c4.z * 64 + lane]);
        s3 += bf2f(src[c4.w * 64 + lane]);
    }
    return ((s0 + s1) + (s2 + s3)) / fmaxf((float)cnt, 1.0f);
}

// unmasked padded gather-mean of interleaved (hp,hn) u32 rows -> two means
__device__ inline void gather2(const unsigned* __restrict__ hb32,
                               const int* __restrict__ csr,
                               int st, int en, int cnt, int lane,
                               float& mp, float& mn) {
    float p0 = 0.f, p1 = 0.f, p2 = 0.f, p3 = 0.f;
    float n0 = 0.f, n1 = 0.f, n2 = 0.f, n3 = 0.f;
    for (int p = st; p < en; p += 4) {
        int4 c4 = *(const int4*)(csr + p);
        unsigned v0 = hb32[c4.x * 64 + lane];
        unsigned v1 = hb32[c4.y * 64 + lane];
        unsigned v2 = hb32[c4.z * 64 + lane];
        unsigned v3 = hb32[c4.w * 64 + lane];
        p0 += lo_bf(v0); n0 += hi_bf(v0);
        p1 += lo_bf(v1); n1 += hi_bf(v1);
        p2 += lo_bf(v2); n2 += hi_bf(v2);
        p3 += lo_bf(v3); n3 += hi_bf(v3);
    }
    float d = 1.0f / fmaxf((float)cnt, 1.0f);
    mp = ((p0 + p1) + (p2 + p3)) * d;
    mn = ((n0 + n1) + (n2 + n3)) * d;
}

// both base layers: gather (bf16) -> MFMA GEMM -> tanh -> interleaved bf16 h
__global__ __launch_bounds__(512) void base_both(
    const unsigned short* __restrict__ xb,
    const int* __restrict__ offP, const int* __restrict__ csrP,
    const int* __restrict__ offN, const int* __restrict__ csrN,
    const int* __restrict__ cntP, const int* __restrict__ cntN,
    const unsigned short* __restrict__ wt0,
    const float* __restrict__ bp0, const float* __restrict__ bn0,
    unsigned short* __restrict__ hboth) {
    __shared__ unsigned short lds[64 * BSTR];
    int tid = threadIdx.x, lane = tid & 63, w = tid >> 6;
    int base = blockIdx.x * 64;
    // zero sentinel row of hboth (once, before deep_both runs)
    if (blockIdx.x == 0 && tid < 64) ((unsigned*)hboth)[N_NODES * 64 + tid] = 0u;
    for (int r = w * 8; r < w * 8 + 8; ++r) {
        int node = base + r;
        float gP = 0.f, gN = 0.f;
        unsigned short sx = 0;
        if (node < N_NODES) {
            gP = gather_mean_b(xb, csrP, offP[node], offP[node + 1], cntP[node], lane);
            gN = gather_mean_b(xb, csrN, offN[node], offN[node + 1], cntN[node], lane);
            sx = xb[node * 64 + lane];
        }
        unsigned short* rp = &lds[r * BSTR];
        rp[lane] = f2bf(gP);
        rp[64 + lane] = sx;
        rp[128 + lane] = f2bf(gN);
        rp[192 + lane] = sx;
    }
    __syncthreads();
    int wu = __builtin_amdgcn_readfirstlane(w);
    int mt = wu >> 1, half = wu & 1;
    int l15 = lane & 15, kq = lane >> 4;
    const unsigned short* wbase = wt0 + half * 8192;
    f32x4 acc[4];
#pragma unroll
    for (int nt = 0; nt < 4; ++nt) acc[nt] = (f32x4){0.f, 0.f, 0.f, 0.f};
    const unsigned short* arow = &lds[(mt * 16 + l15) * BSTR + half * 128 + kq * 8];
#pragma unroll
    for (int ks = 0; ks < 4; ++ks) {
        sh8 a = *(const sh8*)(arow + ks * 32);
#pragma unroll
        for (int nt = 0; nt < 4; ++nt) {
            sh8 bf = *(const sh8*)(wbase + (nt * 16 + l15) * 128 + ks * 32 + kq * 8);
            acc[nt] = __builtin_amdgcn_mfma_f32_16x16x32_bf16(a, bf, acc[nt], 0, 0, 0);
        }
    }
    __syncthreads();
    float* ht = (float*)lds;  // [64][130]
    const float* bias = half ? bn0 : bp0;
#pragma unroll
    for (int nt = 0; nt < 4; ++nt) {
        int col = nt * 16 + l15;
        float bb = bias[col];
#pragma unroll
        for (int r = 0; r < 4; ++r) {
            int row = mt * 16 + kq * 4 + r;
            ht[row * 130 + half * 64 + col] = tanhf(acc[nt][r] + bb);
        }
    }
    __syncthreads();
    unsigned* hb32 = (unsigned*)hboth;
    for (int i = tid; i < 64 * 64; i += 512) {
        int rr = i >> 6, c = i & 63;
        int node = base + rr;
        if (node < N_NODES) {
            unsigned lo = f2bf(ht[rr * 130 + c]);
            unsigned hi = f2bf(ht[rr * 130 + 64 + c]);
            hb32[node * 64 + c] = lo | (hi << 16);
        }
    }
}

// both deep layers: gather -> MFMA GEMM -> tanh -> z/zq/pn epilogue (fp8-consistent)
__global__ __launch_bounds__(512) void deep_both(
    const unsigned short* __restrict__ hb,
    const int* __restrict__ offP, const int* __restrict__ csrP,
    const int* __restrict__ offN, const int* __restrict__ csrN,
    const int* __restrict__ cntP, const int* __restrict__ cntN,
    const unsigned short* __restrict__ wt1,
    const float* __restrict__ bp1, const float* __restrict__ bn1,
    const float* __restrict__ Wreg, float* __restrict__ z,
    unsigned char* __restrict__ zq, float* __restrict__ pn) {
    __shared__ unsigned short lds[64 * DSTR];
    int tid = threadIdx.x, lane = tid & 63, w = tid >> 6;
    int base = blockIdx.x * 64;
    const unsigned* hb32 = (const unsigned*)hb;
    for (int r = w * 8; r < w * 8 + 8; ++r) {
        int node = base + r;
        float gPp = 0.f, gPn = 0.f, gNp = 0.f, gNn = 0.f, sp = 0.f, sn = 0.f;
        if (node < N_NODES) {
            gather2(hb32, csrP, offP[node], offP[node + 1], cntP[node], lane, gPp, gPn);
            gather2(hb32, csrN, offN[node], offN[node + 1], cntN[node], lane, gNp, gNn);
            unsigned self = hb32[node * 64 + lane];
            sp = lo_bf(self);
            sn = hi_bf(self);
        }
        unsigned short* rp = &lds[r * DSTR];
        rp[lane] = f2bf(gPp);        // posIn[0:64]   = gm(h_pos, csrP)
        rp[64 + lane] = f2bf(gNn);   // posIn[64:128] = gm(h_neg, csrN)
        rp[128 + lane] = f2bf(sp);   // posIn[128:192]= h_pos self
        rp[192 + lane] = f2bf(gPn);  // negIn[0:64]   = gm(h_neg, csrP)
        rp[256 + lane] = f2bf(gNp);  // negIn[64:128] = gm(h_pos, csrN)
        rp[320 + lane] = f2bf(sn);   // negIn[128:192]= h_neg self
    }
    __syncthreads();
    int wu = __builtin_amdgcn_readfirstlane(w);
    int mt = wu >> 1, half = wu & 1;
    int l15 = lane & 15, kq = lane >> 4;
    const unsigned short* wbase = wt1 + half * 6144;
    f32x4 acc[2];
    acc[0] = (f32x4){0.f, 0.f, 0.f, 0.f};
    acc[1] = (f32x4){0.f, 0.f, 0.f, 0.f};
    const unsigned short* arow = &lds[(mt * 16 + l15) * DSTR + half * 192 + kq * 8];
#pragma unroll
    for (int ks = 0; ks < 6; ++ks) {
        sh8 a = *(const sh8*)(arow + ks * 32);
#pragma unroll
        for (int nt = 0; nt < 2; ++nt) {
            sh8 bf = *(const sh8*)(wbase + (nt * 16 + l15) * 192 + ks * 32 + kq * 8);
            acc[nt] = __builtin_amdgcn_mfma_f32_16x16x32_bf16(a, bf, acc[nt], 0, 0, 0);
        }
    }
    __syncthreads();
    float* ot = (float*)lds;  // [64][65]
    const float* bias = half ? bn1 : bp1;
#pragma unroll
    for (int nt = 0; nt < 2; ++nt) {
        int col = nt * 16 + l15;
        float bb = bias[col];
#pragma unroll
        for (int r = 0; r < 4; ++r) {
            int row = mt * 16 + kq * 4 + r;
            ot[row * 65 + half * 32 + col] = tanhf(acc[nt][r] + bb);
        }
    }
    __syncthreads();
    for (int r = w * 8; r < w * 8 + 8; ++r) {
        int node = base + r;
        if (node >= N_NODES) break;
        float v = ot[r * 65 + lane];
        z[node * 64 + lane] = v;
        int pq = __builtin_amdgcn_cvt_pk_fp8_f32(v, v, 0, false);
        zq[node * 64 + lane] = (unsigned char)(pq & 0xFF);
        float vq = __builtin_amdgcn_cvt_f32_fp8(pq, 0);
        float u0 = vq * Wreg[lane * 2 + 0];
        float u1 = vq * Wreg[lane * 2 + 1];
        float v0 = vq * Wreg[128 + lane * 2 + 0];
        float v1 = vq * Wreg[128 + lane * 2 + 1];
        float s = vq * vq;
#pragma unroll
        for (int off = 32; off; off >>= 1) {
            u0 += __shfl_xor(u0, off);
            u1 += __shfl_xor(u1, off);
            v0 += __shfl_xor(v0, off);
            v1 += __shfl_xor(v1, off);
            s += __shfl_xor(s, off);
        }
        if (lane == 0) {
            float4 st = {u0, u1, v0, v1};
            *(float4*)(pn + node * 8) = st;
            pn[node * 8 + 4] = s;
        }
    }
}

// 16-lane groups, TWO independent edge-quads per iteration (8 edges/wave/iter):
// all loads issued up-front to double memory-level parallelism
__global__ __launch_bounds__(256) void loss4_kernel(
    const unsigned char* __restrict__ zq, const float* __restrict__ pn,
    const int* __restrict__ pe, const int* __restrict__ ne,
    const int* __restrict__ ps, const int* __restrict__ ns,
    const int* __restrict__ tgt, float* acc) {
    int tid = threadIdx.x;
    int lane = tid & 63;
    int g = lane >> 4, sub = lane & 15;
    int wid = (blockIdx.x * 256 + tid) >> 6;
    int nw = (gridDim.x * 256) >> 6;
    float s_p = 0.f, s_n = 0.f, s_r = 0.f;
    const float q = 0.0625f;
    for (int eb = wid * 8; eb < EP_N + EN_N; eb += nw * 8) {
        int eA = eb + g, eB = eb + 4 + g;
        bool vA = eA < EP_N + EN_N, vB = eB < EP_N + EN_N;
        bool pA = eA < EP_N, pB = eB < EP_N;
        int iA = 0, jA = 0, kA = 0, tA = 0, iB = 0, jB = 0, kB = 0, tB = 0;
        if (vA) {
            if (pA) { iA = pe[eA]; jA = pe[EP_N + eA]; kA = ps[eA]; }
            else { int e2 = eA - EP_N; iA = ne[e2]; jA = ne[EN_N + e2]; kA = ns[e2]; }
            tA = tgt[eA];
        }
        if (vB) {
            if (pB) { iB = pe[eB]; jB = pe[EP_N + eB]; kB = ps[eB]; }
            else { int e2 = eB - EP_N; iB = ne[e2]; jB = ne[EN_N + e2]; kB = ns[e2]; }
            tB = tgt[eB];
        }
        // issue all row loads (6 independent)
        unsigned ziA = *(const unsigned*)(zq + ((long long)iA << 6) + (sub << 2));
        unsigned zjA = *(const unsigned*)(zq + ((long long)jA << 6) + (sub << 2));
        unsigned zkA = *(const unsigned*)(zq + ((long long)kA << 6) + (sub << 2));
        unsigned ziB = *(const unsigned*)(zq + ((long long)iB << 6) + (sub << 2));
        unsigned zjB = *(const unsigned*)(zq + ((long long)jB << 6) + (sub << 2));
        unsigned zkB = *(const unsigned*)(zq + ((long long)kB << 6) + (sub << 2));
        // issue pn broadcast loads early (independent of shuffles)
        const float* pniA = pn + ((long long)iA << 3);
        const float* pnjA = pn + ((long long)jA << 3);
        float u0A = pniA[0], u1A = pniA[1], siA = pniA[4];
        float v0A = pnjA[2], v1A = pnjA[3], sjA = pnjA[4];
        float skA = pn[((long long)kA << 3) + 4];
        const float* pniB = pn + ((long long)iB << 3);
        const float* pnjB = pn + ((long long)jB << 3);
        float u0B = pniB[0], u1B = pniB[1], siB = pniB[4];
        float v0B = pnjB[2], v1B = pnjB[3], sjB = pnjB[4];
        float skB = pn[((long long)kB << 3) + 4];
        // dot products
        float d1A, d2A, d1B, d2B;
        {
            float i0 = __builtin_amdgcn_cvt_f32_fp8(ziA, 0), i1 = __builtin_amdgcn_cvt_f32_fp8(ziA, 1);
            float i2 = __builtin_amdgcn_cvt_f32_fp8(ziA, 2), i3 = __builtin_amdgcn_cvt_f32_fp8(ziA, 3);
            float j0 = __builtin_amdgcn_cvt_f32_fp8(zjA, 0), j1 = __builtin_amdgcn_cvt_f32_fp8(zjA, 1);
            float j2 = __builtin_amdgcn_cvt_f32_fp8(zjA, 2), j3 = __builtin_amdgcn_cvt_f32_fp8(zjA, 3);
            float k0 = __builtin_amdgcn_cvt_f32_fp8(zkA, 0), k1 = __builtin_amdgcn_cvt_f32_fp8(zkA, 1);
            float k2 = __builtin_amdgcn_cvt_f32_fp8(zkA, 2), k3 = __builtin_amdgcn_cvt_f32_fp8(zkA, 3);
            d1A = fmaf(i0, j0, fmaf(i1, j1, fmaf(i2, j2, i3 * j3)));
            d2A = fmaf(j0, k0, fmaf(j1, k1, fmaf(j2, k2, j3 * k3)));
        }
        {
            float i0 = __builtin_amdgcn_cvt_f32_fp8(ziB, 0), i1 = __builtin_amdgcn_cvt_f32_fp8(ziB, 1);
            float i2 = __builtin_amdgcn_cvt_f32_fp8(ziB, 2), i3 = __builtin_amdgcn_cvt_f32_fp8(ziB, 3);
            float j0 = __builtin_amdgcn_cvt_f32_fp8(zjB, 0), j1 = __builtin_amdgcn_cvt_f32_fp8(zjB, 1);
            float j2 = __builtin_amdgcn_cvt_f32_fp8(zjB, 2), j3 = __builtin_amdgcn_cvt_f32_fp8(zjB, 3);
            float k0 = __builtin_amdgcn_cvt_f32_fp8(zkB, 0), k1 = __builtin_amdgcn_cvt_f32_fp8(zkB, 1);
            float k2 = __builtin_amdgcn_cvt_f32_fp8(zkB, 2), k3 = __builtin_amdgcn_cvt_f32_fp8(zkB, 3);
            d1B = fmaf(i0, j0, fmaf(i1, j1, fmaf(i2, j2, i3 * j3)));
            d2B = fmaf(j0, k0, fmaf(j1, k1, fmaf(j2, k2, j3 * k3)));
        }
        // interleaved butterfly reduces
#pragma unroll
        for (int off = 1; off < 16; off <<= 1) {
            d1A += __shfl_xor(d1A, off);
            d2A += __shfl_xor(d2A, off);
            d1B += __shfl_xor(d1B, off);
            d2B += __shfl_xor(d2B, off);
        }
        if (vA) {
            float nij = siA + sjA - 2.f * d1A;
            float nik = sjA + skA - 2.f * d2A;
            float tri = fmaxf(nij - nik, 0.f);
            float l0 = u0A + v0A, l1 = u1A + v1A;
            float m = fmaxf(l0, l1);
            float lse = m + logf(expf(l0 - m) + expf(l1 - m));
            s_r += (lse - (tA ? l1 : l0)) * q;
            if (pA) s_p += tri * q; else s_n += tri * q;
        }
        if (vB) {
            float nij = siB + sjB - 2.f * d1B;
            float nik = sjB + skB - 2.f * d2B;
            float tri = fmaxf(nij - nik, 0.f);
            float l0 = u0B + v0B, l1 = u1B + v1B;
            float m = fmaxf(l0, l1);
            float lse = m + logf(expf(l0 - m) + expf(l1 - m));
            s_r += (lse - (tB ? l1 : l0)) * q;
            if (pB) s_p += tri * q; else s_n += tri * q;
        }
    }
#pragma unroll
    for (int off = 32; off; off >>= 1) {
        s_p += __shfl_xor(s_p, off);
        s_n += __shfl_xor(s_n, off);
        s_r += __shfl_xor(s_r, off);
    }
    __shared__ float red[3][4];
    int w = tid >> 6;
    if (lane == 0) {
        red[0][w] = s_p; red[1][w] = s_n; red[2][w] = s_r;
    }
    __syncthreads();
    if (tid == 0) {
        atomicAdd(&acc[0], red[0][0] + red[0][1] + red[0][2] + red[0][3]);
        atomicAdd(&acc[1], red[1][0] + red[1][1] + red[1][2] + red[1][3]);
        atomicAdd(&acc[2], red[2][0] + red[2][1] + red[2][2] + red[2][3]);
    }
}

__global__ void finalize_kernel(const float* __restrict__ acc, float* out) {
    out[0] = acc[2] / (float)(EP_N + EN_N) +
             1.0f * (acc[0] / (float)EP_N + acc[1] / (float)EN_N);
}

extern "C" void kernel_launch(void* const* d_in, const int* in_sizes, int n_in,
                              void* d_out, int out_size, void* d_ws, size_t ws_size,
                              hipStream_t stream) {
    const float* X = (const float*)d_in[0];
    const float* W_pos0 = (const float*)d_in[1];
    const float* b_pos0 = (const float*)d_in[2];
    const float* W_neg0 = (const float*)d_in[3];
    const float* b_neg0 = (const float*)d_in[4];
    const float* W_pos1 = (const float*)d_in[5];
    const float* b_pos1 = (const float*)d_in[6];
    const float* W_neg1 = (const float*)d_in[7];
    const float* b_neg1 = (const float*)d_in[8];
    const float* W_reg = (const float*)d_in[9];
    const int* pe = (const int*)d_in[10];
    const int* ne = (const int*)d_in[11];
    const int* target = (const int*)d_in[12];
    const int* ps = (const int*)d_in[13];
    const int* ns = (const int*)d_in[14];
    float* out = (float*)d_out;
    float* ws = (float*)d_ws;
    int* wsi = (int*)d_ws;

    float* acc = ws + ACC_OFF;
    int* cntP = wsi + I_CNTP;
    int* cntN = wsi + I_CNTN;
    int* curP = wsi + I_CURP;
    int* curN = wsi + I_CURN;
    int* offP = wsi + I_OFFP;
    int* offN = wsi + I_OFFN;
    int* csrP = wsi + I_CSRP;
    int* csrN = wsi + I_CSRN;
    int* part = wsi + I_PART;
    unsigned short* xb = (unsigned short*)(ws + F_XB);
    unsigned short* hboth = (unsigned short*)(ws + F_HB);
    float* pn = ws + F_PN;
    unsigned char* zq = (unsigned char*)(ws + F_ZQ);
    unsigned short* wt = (unsigned short*)(ws + F_WT);
    float* z = out + 1;

    hipMemsetAsync(ws, 0, (size_t)(16 + 4 * N_NODES) * sizeof(float), stream);

    prep_kernel<<<XB_BLKS + WP_BLKS + CNT_BLKS, 256, 0, stream>>>(
        X, xb, W_pos0, W_neg0, W_pos1, W_neg1, wt, pe, ne, cntP, cntN);
    scan_p1<<<2 * SBLK, 512, 0, stream>>>(cntP, cntN, part);
    scan_p2<<<1, 512, 0, stream>>>(part);
    scan_p3<<<2 * SBLK, 512, 0, stream>>>(cntP, cntN, part, offP, offN, csrP, csrN);
    fill_kernel<<<(EP_N + EN_N + 255) / 256, 256, 0, stream>>>(pe, ne, offP, offN,
                                                               curP, curN, csrP, csrN);

    base_both<<<NODE_BLOCKS, 512, 0, stream>>>(xb, offP, csrP, offN, csrN, cntP, cntN,
                                               wt, b_pos0, b_neg0, hboth);
    deep_both<<<NODE_BLOCKS, 512, 0, stream>>>(hboth, offP, csrP, offN, csrN, cntP, cntN,
                                               wt + 16384, b_pos1, b_neg1,
                                               W_reg, z, zq, pn);

    loss4_kernel<<<2048, 256, 0, stream>>>(zq, pn, pe, ne, ps, ns, target, acc);
    finalize_kernel<<<1, 1, 0, stream>>>(acc, out);
}

// Round 11
// 379.895 us; speedup vs baseline: 1.2994x; 1.0802x over previous
//
#include <hip/hip_runtime.h>
#include <cstdint>

#define N_NODES 100000
#define EP_N 400000
#define EN_N 400000
#define NODE_BLOCKS ((N_NODES + 63) / 64)
#define SCHUNK 512
#define SBLK ((N_NODES + SCHUNK - 1) / SCHUNK)

#define BSTR 264   // base LDS row: [gP(64) | X(64) | gN(64) | X(64)] + 8 pad (ushorts)
#define DSTR 392   // deep LDS row: [posIn(192) | negIn(192)] + 8 pad (ushorts)

// prep_kernel block ranges
#define XB_BLKS ((((N_NODES + 1) * 16) + 255) / 256)
#define WP_BLKS 112
#define CNT_BLKS (((EP_N + EN_N) + 255) / 256)
#define EI_BLKS CNT_BLKS

// ws layout (in 4-byte units)
#define ACC_OFF 0
#define I_CNTP 16
#define I_CNTN (I_CNTP + N_NODES)
#define I_CURP (I_CNTN + N_NODES)
#define I_CURN (I_CURP + N_NODES)
#define I_OFFP (I_CURN + N_NODES)
#define I_OFFN (I_OFFP + N_NODES + 1)
#define I_CSRP (((I_OFFN + N_NODES + 1) + 3) & ~3)
#define CSR_SZ (EP_N + 4 * N_NODES)
#define I_CSRN (I_CSRP + CSR_SZ)
#define I_PART (I_CSRN + CSR_SZ)
#define I_EIDX (((I_PART + 2 * SBLK) + 3) & ~3)      // int4 per edge
#define F_XB (((I_EIDX + 4 * (EP_N + EN_N)) + 15) & ~15)
#define F_HB (F_XB + 32 * (N_NODES + 1))          // hboth: (N+1)*64 u32
#define F_PNU (F_HB + 64 * (N_NODES + 1))         // pnu: N float4
#define F_PNV (F_PNU + 4 * N_NODES)               // pnv: N float4
#define F_ZQ (F_PNV + 4 * N_NODES)                // zq: N*64 bytes
#define F_WT (((F_ZQ + 16 * N_NODES) + 15) & ~15) // wt: 28672 ushorts

typedef __attribute__((ext_vector_type(8))) short sh8;
typedef __attribute__((ext_vector_type(4))) float f32x4;

__device__ inline float bf2f(unsigned short u) {
    return __uint_as_float((unsigned)u << 16);
}
__device__ inline unsigned short f2bf(float v) {
    unsigned u = __float_as_uint(v);
    return (unsigned short)((u + 0x7FFFu + ((u >> 16) & 1u)) >> 16);
}
__device__ inline float lo_bf(unsigned u) { return __uint_as_float(u << 16); }
__device__ inline float hi_bf(unsigned u) { return __uint_as_float(u & 0xFFFF0000u); }

// fused: X->bf16 (+sentinel) | weight transpose->bf16 | degree count | eidx pack
__global__ void prep_kernel(const float* __restrict__ X, unsigned short* __restrict__ xb,
                            const float* __restrict__ W0p, const float* __restrict__ W0n,
                            const float* __restrict__ W1p, const float* __restrict__ W1n,
                            unsigned short* __restrict__ wt,
                            const int* __restrict__ pe, const int* __restrict__ ne,
                            const int* __restrict__ ps, const int* __restrict__ ns,
                            const int* __restrict__ tgt,
                            int* cp, int* cn, int4* __restrict__ eidx) {
    int b = blockIdx.x;
    if (b < XB_BLKS) {
        int i = b * 256 + threadIdx.x;
        if (i < (N_NODES + 1) * 16) {
            ushort4 o = {0, 0, 0, 0};
            if (i < N_NODES * 16) {
                float4 v = ((const float4*)X)[i];
                o.x = f2bf(v.x); o.y = f2bf(v.y); o.z = f2bf(v.z); o.w = f2bf(v.w);
            }
            ((ushort4*)xb)[i] = o;
        }
    } else if (b < XB_BLKS + WP_BLKS) {
        int i = (b - XB_BLKS) * 256 + threadIdx.x;
        if (i < 8192) {
            int n = i >> 7, k = i & 127;
            wt[i] = f2bf(W0p[k * 64 + n]);
        } else if (i < 16384) {
            int j = i - 8192; int n = j >> 7, k = j & 127;
            wt[i] = f2bf(W0n[k * 64 + n]);
        } else if (i < 22528) {
            int j = i - 16384; int n = j / 192, k = j - n * 192;
            wt[i] = f2bf(W1p[k * 32 + n]);
        } else if (i < 28672) {
            int j = i - 22528; int n = j / 192, k = j - n * 192;
            wt[i] = f2bf(W1n[k * 32 + n]);
        }
    } else if (b < XB_BLKS + WP_BLKS + CNT_BLKS) {
        int i = (b - XB_BLKS - WP_BLKS) * 256 + threadIdx.x;
        if (i < EP_N) {
            atomicAdd(&cp[pe[i]], 1);
        } else if (i < EP_N + EN_N) {
            atomicAdd(&cn[ne[i - EP_N]], 1);
        }
    } else {
        int e = (b - XB_BLKS - WP_BLKS - CNT_BLKS) * 256 + threadIdx.x;
        if (e < EP_N) {
            int4 q = {pe[e], pe[EP_N + e], ps[e], tgt[e]};
            eidx[e] = q;
        } else if (e < EP_N + EN_N) {
            int e2 = e - EP_N;
            int4 q = {ne[e2], ne[EN_N + e2], ns[e2], tgt[e]};
            eidx[e] = q;
        }
    }
}

__global__ __launch_bounds__(512) void scan_p1(const int* __restrict__ cntP,
                                               const int* __restrict__ cntN,
                                               int* part) {
    int l = blockIdx.x < SBLK ? 0 : 1;
    int blk = blockIdx.x - l * SBLK;
    const int* cnt = l == 0 ? cntP : cntN;
    int idx = blk * SCHUNK + threadIdx.x;
    int v = idx < N_NODES ? (cnt[idx] + 3) & ~3 : 0;   // padded counts
    __shared__ int tmp[512];
    tmp[threadIdx.x] = v;
    __syncthreads();
    for (int d = 256; d > 0; d >>= 1) {
        if (threadIdx.x < d) tmp[threadIdx.x] += tmp[threadIdx.x + d];
        __syncthreads();
    }
    if (threadIdx.x == 0) part[l * SBLK + blk] = tmp[0];
}

__global__ __launch_bounds__(512) void scan_p2(int* part) {
    int t = threadIdx.x;
    int l = t >> 8, idx = t & 255;
    int v = idx < SBLK ? part[l * SBLK + idx] : 0;
    __shared__ int tmp[512];
    int sb = l << 8;
    tmp[sb + idx] = v;
    __syncthreads();
    for (int d = 1; d < 256; d <<= 1) {
        int x = (idx >= d) ? tmp[sb + idx - d] : 0;
        __syncthreads();
        tmp[sb + idx] += x;
        __syncthreads();
    }
    if (idx < SBLK) part[l * SBLK + idx] = tmp[sb + idx] - v;
}

// padded offsets + sentinel pad fill
__global__ __launch_bounds__(512) void scan_p3(const int* __restrict__ cntP,
                                               const int* __restrict__ cntN,
                                               const int* __restrict__ part,
                                               int* offP, int* offN,
                                               int* csrP, int* csrN) {
    int l = blockIdx.x < SBLK ? 0 : 1;
    int blk = blockIdx.x - l * SBLK;
    const int* cnt = l == 0 ? cntP : cntN;
    int* off = l == 0 ? offP : offN;
    int* csr = l == 0 ? csrP : csrN;
    int base = part[l * SBLK + blk];
    int t = threadIdx.x;
    int gidx = blk * SCHUNK + t;
    int c = gidx < N_NODES ? cnt[gidx] : 0;
    int cpad = (c + 3) & ~3;
    __shared__ int tmp[512];
    tmp[t] = cpad;
    __syncthreads();
    for (int d = 1; d < 512; d <<= 1) {
        int x = (t >= d) ? tmp[t - d] : 0;
        __syncthreads();
        tmp[t] += x;
        __syncthreads();
    }
    int incl = tmp[t];
    if (gidx < N_NODES) {
        int o = base + incl - cpad;
        off[gidx] = o;
        for (int p = c; p < cpad; ++p) csr[o + p] = N_NODES;  // sentinel pads
    }
    if (gidx == N_NODES - 1) off[N_NODES] = base + incl;
}

__global__ void fill_kernel(const int* __restrict__ pe, const int* __restrict__ ne,
                            const int* __restrict__ offP, const int* __restrict__ offN,
                            int* curP, int* curN, int* csrP, int* csrN) {
    int e = blockIdx.x * 256 + threadIdx.x;
    if (e < EP_N) {
        int row = pe[e], col = pe[EP_N + e];
        int slot = atomicAdd(&curP[row], 1);
        csrP[offP[row] + slot] = col;
    } else if (e < EP_N + EN_N) {
        int e2 = e - EP_N;
        int row = ne[e2], col = ne[EN_N + e2];
        int slot = atomicAdd(&curN[row], 1);
        csrN[offN[row] + slot] = col;
    }
}

// joint P/N gather-mean over bf16 rows, 8 loads in flight in main loop
__device__ inline void gmb2(const unsigned short* __restrict__ src,
                            const int* __restrict__ csrP, int pP, int enP, int cP,
                            const int* __restrict__ csrN, int pN, int enN, int cN,
                            int lane, float& mP, float& mN) {
    float a0 = 0.f, a1 = 0.f, a2 = 0.f, a3 = 0.f;
    float b0 = 0.f, b1 = 0.f, b2 = 0.f, b3 = 0.f;
    while (pP < enP && pN < enN) {
        int4 ca = *(const int4*)(csrP + pP);
        int4 cb = *(const int4*)(csrN + pN);
        a0 += bf2f(src[ca.x * 64 + lane]);
        a1 += bf2f(src[ca.y * 64 + lane]);
        a2 += bf2f(src[ca.z * 64 + lane]);
        a3 += bf2f(src[ca.w * 64 + lane]);
        b0 += bf2f(src[cb.x * 64 + lane]);
        b1 += bf2f(src[cb.y * 64 + lane]);
        b2 += bf2f(src[cb.z * 64 + lane]);
        b3 += bf2f(src[cb.w * 64 + lane]);
        pP += 4; pN += 4;
    }
    for (; pP < enP; pP += 4) {
        int4 ca = *(const int4*)(csrP + pP);
        a0 += bf2f(src[ca.x * 64 + lane]);
        a1 += bf2f(src[ca.y * 64 + lane]);
        a2 += bf2f(src[ca.z * 64 + lane]);
        a3 += bf2f(src[ca.w * 64 + lane]);
    }
    for (; pN < enN; pN += 4) {
        int4 cb = *(const int4*)(csrN + pN);
        b0 += bf2f(src[cb.x * 64 + lane]);
        b1 += bf2f(src[cb.y * 64 + lane]);
        b2 += bf2f(src[cb.z * 64 + lane]);
        b3 += bf2f(src[cb.w * 64 + lane]);
    }
    mP = ((a0 + a1) + (a2 + a3)) / fmaxf((float)cP, 1.f);
    mN = ((b0 + b1) + (b2 + b3)) / fmaxf((float)cN, 1.f);
}

// joint P/N gather-mean of interleaved (hp,hn) u32 rows -> four means
__device__ inline void gd2(const unsigned* __restrict__ hb32,
                           const int* __restrict__ csrP, int pP, int enP, int cP,
                           const int* __restrict__ csrN, int pN, int enN, int cN,
                           int lane,
                           float& gPp, float& gPn, float& gNp, float& gNn) {
    float ap0 = 0.f, ap1 = 0.f, ap2 = 0.f, ap3 = 0.f;
    float an0 = 0.f, an1 = 0.f, an2 = 0.f, an3 = 0.f;
    float bp0 = 0.f, bp1 = 0.f, bp2 = 0.f, bp3 = 0.f;
    float bn0 = 0.f, bn1 = 0.f, bn2 = 0.f, bn3 = 0.f;
    while (pP < enP && pN < enN) {
        int4 ca = *(const int4*)(csrP + pP);
        int4 cb = *(const int4*)(csrN + pN);
        unsigned va0 = hb32[ca.x * 64 + lane];
        unsigned va1 = hb32[ca.y * 64 + lane];
        unsigned va2 = hb32[ca.z * 64 + lane];
        unsigned va3 = hb32[ca.w * 64 + lane];
        unsigned vb0 = hb32[cb.x * 64 + lane];
        unsigned vb1 = hb32[cb.y * 64 + lane];
        unsigned vb2 = hb32[cb.z * 64 + lane];
        unsigned vb3 = hb32[cb.w * 64 + lane];
        ap0 += lo_bf(va0); an0 += hi_bf(va0);
        ap1 += lo_bf(va1); an1 += hi_bf(va1);
        ap2 += lo_bf(va2); an2 += hi_bf(va2);
        ap3 += lo_bf(va3); an3 += hi_bf(va3);
        bp0 += lo_bf(vb0); bn0 += hi_bf(vb0);
        bp1 += lo_bf(vb1); bn1 += hi_bf(vb1);
        bp2 += lo_bf(vb2); bn2 += hi_bf(vb2);
        bp3 += lo_bf(vb3); bn3 += hi_bf(vb3);
        pP += 4; pN += 4;
    }
    for (; pP < enP; pP += 4) {
        int4 ca = *(const int4*)(csrP + pP);
        unsigned va0 = hb32[ca.x * 64 + lane];
        unsigned va1 = hb32[ca.y * 64 + lane];
        unsigned va2 = hb32[ca.z * 64 + lane];
        unsigned va3 = hb32[ca.w * 64 + lane];
        ap0 += lo_bf(va0); an0 += hi_bf(va0);
        ap1 += lo_bf(va1); an1 += hi_bf(va1);
        ap2 += lo_bf(va2); an2 += hi_bf(va2);
        ap3 += lo_bf(va3); an3 += hi_bf(va3);
    }
    for (; pN < enN; pN += 4) {
        int4 cb = *(const int4*)(csrN + pN);
        unsigned vb0 = hb32[cb.x * 64 + lane];
        unsigned vb1 = hb32[cb.y * 64 + lane];
        unsigned vb2 = hb32[cb.z * 64 + lane];
        unsigned vb3 = hb32[cb.w * 64 + lane];
        bp0 += lo_bf(vb0); bn0 += hi_bf(vb0);
        bp1 += lo_bf(vb1); bn1 += hi_bf(vb1);
        bp2 += lo_bf(vb2); bn2 += hi_bf(vb2);
        bp3 += lo_bf(vb3); bn3 += hi_bf(vb3);
    }
    float rP = 1.f / fmaxf((float)cP, 1.f), rN = 1.f / fmaxf((float)cN, 1.f);
    gPp = ((ap0 + ap1) + (ap2 + ap3)) * rP;
    gPn = ((an0 + an1) + (an2 + an3)) * rP;
    gNp = ((bp0 + bp1) + (bp2 + bp3)) * rN;
    gNn = ((bn0 + bn1) + (bn2 + bn3)) * rN;
}

// both base layers: gather (bf16) -> MFMA GEMM -> tanh -> interleaved bf16 h
__global__ __launch_bounds__(512) void base_both(
    const unsigned short* __restrict__ xb,
    const int* __restrict__ offP, const int* __restrict__ csrP,
    const int* __restrict__ offN, const int* __restrict__ csrN,
    const int* __restrict__ cntP, const int* __restrict__ cntN,
    const unsigned short* __restrict__ wt0,
    const float* __restrict__ bp0, const float* __restrict__ bn0,
    unsigned short* __restrict__ hboth) {
    __shared__ unsigned short lds[64 * BSTR];
    int tid = threadIdx.x, lane = tid & 63, w = tid >> 6;
    int base = blockIdx.x * 64;
    // zero sentinel row of hboth (once, before deep_both runs)
    if (blockIdx.x == 0 && tid < 64) ((unsigned*)hboth)[N_NODES * 64 + tid] = 0u;
    for (int r = w * 8; r < w * 8 + 8; ++r) {
        int node = base + r;
        float gP = 0.f, gN = 0.f;
        unsigned short sx = 0;
        if (node < N_NODES) {
            gmb2(xb, csrP, offP[node], offP[node + 1], cntP[node],
                 csrN, offN[node], offN[node + 1], cntN[node], lane, gP, gN);
            sx = xb[node * 64 + lane];
        }
        unsigned short* rp = &lds[r * BSTR];
        rp[lane] = f2bf(gP);
        rp[64 + lane] = sx;
        rp[128 + lane] = f2bf(gN);
        rp[192 + lane] = sx;
    }
    __syncthreads();
    int wu = __builtin_amdgcn_readfirstlane(w);
    int mt = wu >> 1, half = wu & 1;
    int l15 = lane & 15, kq = lane >> 4;
    const unsigned short* wbase = wt0 + half * 8192;
    f32x4 acc[4];
#pragma unroll
    for (int nt = 0; nt < 4; ++nt) acc[nt] = (f32x4){0.f, 0.f, 0.f, 0.f};
    const unsigned short* arow = &lds[(mt * 16 + l15) * BSTR + half * 128 + kq * 8];
#pragma unroll
    for (int ks = 0; ks < 4; ++ks) {
        sh8 a = *(const sh8*)(arow + ks * 32);
#pragma unroll
        for (int nt = 0; nt < 4; ++nt) {
            sh8 bf = *(const sh8*)(wbase + (nt * 16 + l15) * 128 + ks * 32 + kq * 8);
            acc[nt] = __builtin_amdgcn_mfma_f32_16x16x32_bf16(a, bf, acc[nt], 0, 0, 0);
        }
    }
    __syncthreads();
    float* ht = (float*)lds;  // [64][130]
    const float* bias = half ? bn0 : bp0;
#pragma unroll
    for (int nt = 0; nt < 4; ++nt) {
        int col = nt * 16 + l15;
        float bb = bias[col];
#pragma unroll
        for (int r = 0; r < 4; ++r) {
            int row = mt * 16 + kq * 4 + r;
            ht[row * 130 + half * 64 + col] = tanhf(acc[nt][r] + bb);
        }
    }
    __syncthreads();
    unsigned* hb32 = (unsigned*)hboth;
    for (int i = tid; i < 64 * 64; i += 512) {
        int rr = i >> 6, c = i & 63;
        int node = base + rr;
        if (node < N_NODES) {
            unsigned lo = f2bf(ht[rr * 130 + c]);
            unsigned hi = f2bf(ht[rr * 130 + 64 + c]);
            hb32[node * 64 + c] = lo | (hi << 16);
        }
    }
}

// both deep layers: gather -> MFMA GEMM -> tanh -> z/zq/pnu/pnv epilogue
__global__ __launch_bounds__(512) void deep_both(
    const unsigned short* __restrict__ hb,
    const int* __restrict__ offP, const int* __restrict__ csrP,
    const int* __restrict__ offN, const int* __restrict__ csrN,
    const int* __restrict__ cntP, const int* __restrict__ cntN,
    const unsigned short* __restrict__ wt1,
    const float* __restrict__ bp1, const float* __restrict__ bn1,
    const float* __restrict__ Wreg, float* __restrict__ z,
    unsigned char* __restrict__ zq, float4* __restrict__ pnu,
    float4* __restrict__ pnv) {
    __shared__ unsigned short lds[64 * DSTR];
    int tid = threadIdx.x, lane = tid & 63, w = tid >> 6;
    int base = blockIdx.x * 64;
    const unsigned* hb32 = (const unsigned*)hb;
    for (int r = w * 8; r < w * 8 + 8; ++r) {
        int node = base + r;
        float gPp = 0.f, gPn = 0.f, gNp = 0.f, gNn = 0.f, sp = 0.f, sn = 0.f;
        if (node < N_NODES) {
            gd2(hb32, csrP, offP[node], offP[node + 1], cntP[node],
                csrN, offN[node], offN[node + 1], cntN[node], lane,
                gPp, gPn, gNp, gNn);
            unsigned self = hb32[node * 64 + lane];
            sp = lo_bf(self);
            sn = hi_bf(self);
        }
        unsigned short* rp = &lds[r * DSTR];
        rp[lane] = f2bf(gPp);        // posIn[0:64]   = gm(h_pos, csrP)
        rp[64 + lane] = f2bf(gNn);   // posIn[64:128] = gm(h_neg, csrN)
        rp[128 + lane] = f2bf(sp);   // posIn[128:192]= h_pos self
        rp[192 + lane] = f2bf(gPn);  // negIn[0:64]   = gm(h_neg, csrP)
        rp[256 + lane] = f2bf(gNp);  // negIn[64:128] = gm(h_pos, csrN)
        rp[320 + lane] = f2bf(sn);   // negIn[128:192]= h_neg self
    }
    __syncthreads();
    int wu = __builtin_amdgcn_readfirstlane(w);
    int mt = wu >> 1, half = wu & 1;
    int l15 = lane & 15, kq = lane >> 4;
    const unsigned short* wbase = wt1 + half * 6144;
    f32x4 acc[2];
    acc[0] = (f32x4){0.f, 0.f, 0.f, 0.f};
    acc[1] = (f32x4){0.f, 0.f, 0.f, 0.f};
    const unsigned short* arow = &lds[(mt * 16 + l15) * DSTR + half * 192 + kq * 8];
#pragma unroll
    for (int ks = 0; ks < 6; ++ks) {
        sh8 a = *(const sh8*)(arow + ks * 32);
#pragma unroll
        for (int nt = 0; nt < 2; ++nt) {
            sh8 bf = *(const sh8*)(wbase + (nt * 16 + l15) * 192 + ks * 32 + kq * 8);
            acc[nt] = __builtin_amdgcn_mfma_f32_16x16x32_bf16(a, bf, acc[nt], 0, 0, 0);
        }
    }
    __syncthreads();
    float* ot = (float*)lds;  // [64][65]
    const float* bias = half ? bn1 : bp1;
#pragma unroll
    for (int nt = 0; nt < 2; ++nt) {
        int col = nt * 16 + l15;
        float bb = bias[col];
#pragma unroll
        for (int r = 0; r < 4; ++r) {
            int row = mt * 16 + kq * 4 + r;
            ot[row * 65 + half * 32 + col] = tanhf(acc[nt][r] + bb);
        }
    }
    __syncthreads();
    for (int r = w * 8; r < w * 8 + 8; ++r) {
        int node = base + r;
        if (node >= N_NODES) break;
        float v = ot[r * 65 + lane];
        z[node * 64 + lane] = v;
        int pq = __builtin_amdgcn_cvt_pk_fp8_f32(v, v, 0, false);
        zq[node * 64 + lane] = (unsigned char)(pq & 0xFF);
        float vq = __builtin_amdgcn_cvt_f32_fp8(pq, 0);
        float u0 = vq * Wreg[lane * 2 + 0];
        float u1 = vq * Wreg[lane * 2 + 1];
        float v0 = vq * Wreg[128 + lane * 2 + 0];
        float v1 = vq * Wreg[128 + lane * 2 + 1];
        float s = vq * vq;
#pragma unroll
        for (int off = 32; off; off >>= 1) {
            u0 += __shfl_xor(u0, off);
            u1 += __shfl_xor(u1, off);
            v0 += __shfl_xor(v0, off);
            v1 += __shfl_xor(v1, off);
            s += __shfl_xor(s, off);
        }
        if (lane == 0) {
            float4 su = {u0, u1, s, 0.f};
            float4 sv = {v0, v1, s, 0.f};
            pnu[node] = su;
            pnv[node] = sv;
        }
    }
}

// 16-lane groups, two independent edge-quads per iter; packed eidx + pnu/pnv
__global__ __launch_bounds__(256) void loss5_kernel(
    const unsigned char* __restrict__ zq, const float4* __restrict__ pnu,
    const float4* __restrict__ pnv, const int4* __restrict__ eidx, float* acc) {
    int tid = threadIdx.x;
    int lane = tid & 63;
    int g = lane >> 4, sub = lane & 15;
    int wid = (blockIdx.x * 256 + tid) >> 6;
    int nw = (gridDim.x * 256) >> 6;
    float s_p = 0.f, s_n = 0.f, s_r = 0.f;
    const float q = 0.0625f;
    for (int eb = wid * 8; eb < EP_N + EN_N; eb += nw * 8) {
        int eA = eb + g, eB = eb + 4 + g;
        bool vA = eA < EP_N + EN_N, vB = eB < EP_N + EN_N;
        bool pA = eA < EP_N, pB = eB < EP_N;
        int4 qA = eidx[vA ? eA : 0];
        int4 qB = eidx[vB ? eB : 0];
        // row loads (6 independent)
        unsigned ziA = *(const unsigned*)(zq + ((long long)qA.x << 6) + (sub << 2));
        unsigned zjA = *(const unsigned*)(zq + ((long long)qA.y << 6) + (sub << 2));
        unsigned zkA = *(const unsigned*)(zq + ((long long)qA.z << 6) + (sub << 2));
        unsigned ziB = *(const unsigned*)(zq + ((long long)qB.x << 6) + (sub << 2));
        unsigned zjB = *(const unsigned*)(zq + ((long long)qB.y << 6) + (sub << 2));
        unsigned zkB = *(const unsigned*)(zq + ((long long)qB.z << 6) + (sub << 2));
        // packed node-scalar loads (6 independent)
        float4 uA = pnu[qA.x];
        float4 wA = pnv[qA.y];
        float skA = pnu[qA.z].z;
        float4 uB = pnu[qB.x];
        float4 wB = pnv[qB.y];
        float skB = pnu[qB.z].z;
        float d1A, d2A, d1B, d2B;
        {
            float i0 = __builtin_amdgcn_cvt_f32_fp8(ziA, 0), i1 = __builtin_amdgcn_cvt_f32_fp8(ziA, 1);
            float i2 = __builtin_amdgcn_cvt_f32_fp8(ziA, 2), i3 = __builtin_amdgcn_cvt_f32_fp8(ziA, 3);
            float j0 = __builtin_amdgcn_cvt_f32_fp8(zjA, 0), j1 = __builtin_amdgcn_cvt_f32_fp8(zjA, 1);
            float j2 = __builtin_amdgcn_cvt_f32_fp8(zjA, 2), j3 = __builtin_amdgcn_cvt_f32_fp8(zjA, 3);
            float k0 = __builtin_amdgcn_cvt_f32_fp8(zkA, 0), k1 = __builtin_amdgcn_cvt_f32_fp8(zkA, 1);
            float k2 = __builtin_amdgcn_cvt_f32_fp8(zkA, 2), k3 = __builtin_amdgcn_cvt_f32_fp8(zkA, 3);
            d1A = fmaf(i0, j0, fmaf(i1, j1, fmaf(i2, j2, i3 * j3)));
            d2A = fmaf(j0, k0, fmaf(j1, k1, fmaf(j2, k2, j3 * k3)));
        }
        {
            float i0 = __builtin_amdgcn_cvt_f32_fp8(ziB, 0), i1 = __builtin_amdgcn_cvt_f32_fp8(ziB, 1);
            float i2 = __builtin_amdgcn_cvt_f32_fp8(ziB, 2), i3 = __builtin_amdgcn_cvt_f32_fp8(ziB, 3);
            float j0 = __builtin_amdgcn_cvt_f32_fp8(zjB, 0), j1 = __builtin_amdgcn_cvt_f32_fp8(zjB, 1);
            float j2 = __builtin_amdgcn_cvt_f32_fp8(zjB, 2), j3 = __builtin_amdgcn_cvt_f32_fp8(zjB, 3);
            float k0 = __builtin_amdgcn_cvt_f32_fp8(zkB, 0), k1 = __builtin_amdgcn_cvt_f32_fp8(zkB, 1);
            float k2 = __builtin_amdgcn_cvt_f32_fp8(zkB, 2), k3 = __builtin_amdgcn_cvt_f32_fp8(zkB, 3);
            d1B = fmaf(i0, j0, fmaf(i1, j1, fmaf(i2, j2, i3 * j3)));
            d2B = fmaf(j0, k0, fmaf(j1, k1, fmaf(j2, k2, j3 * k3)));
        }
#pragma unroll
        for (int off = 1; off < 16; off <<= 1) {
            d1A += __shfl_xor(d1A, off);
            d2A += __shfl_xor(d2A, off);
            d1B += __shfl_xor(d1B, off);
            d2B += __shfl_xor(d2B, off);
        }
        if (vA) {
            float nij = uA.z + wA.z - 2.f * d1A;
            float nik = wA.z + skA - 2.f * d2A;
            float tri = fmaxf(nij - nik, 0.f);
            float l0 = uA.x + wA.x, l1 = uA.y + wA.y;
            float m = fmaxf(l0, l1);
            float lse = m + logf(expf(l0 - m) + expf(l1 - m));
            s_r += (lse - (qA.w ? l1 : l0)) * q;
            if (pA) s_p += tri * q; else s_n += tri * q;
        }
        if (vB) {
            float nij = uB.z + wB.z - 2.f * d1B;
            float nik = wB.z + skB - 2.f * d2B;
            float tri = fmaxf(nij - nik, 0.f);
            float l0 = uB.x + wB.x, l1 = uB.y + wB.y;
            float m = fmaxf(l0, l1);
            float lse = m + logf(expf(l0 - m) + expf(l1 - m));
            s_r += (lse - (qB.w ? l1 : l0)) * q;
            if (pB) s_p += tri * q; else s_n += tri * q;
        }
    }
#pragma unroll
    for (int off = 32; off; off >>= 1) {
        s_p += __shfl_xor(s_p, off);
        s_n += __shfl_xor(s_n, off);
        s_r += __shfl_xor(s_r, off);
    }
    __shared__ float red[3][4];
    int w = tid >> 6;
    if (lane == 0) {
        red[0][w] = s_p; red[1][w] = s_n; red[2][w] = s_r;
    }
    __syncthreads();
    if (tid == 0) {
        atomicAdd(&acc[0], red[0][0] + red[0][1] + red[0][2] + red[0][3]);
        atomicAdd(&acc[1], red[1][0] + red[1][1] + red[1][2] + red[1][3]);
        atomicAdd(&acc[2], red[2][0] + red[2][1] + red[2][2] + red[2][3]);
    }
}

__global__ void finalize_kernel(const float* __restrict__ acc, float* out) {
    out[0] = acc[2] / (float)(EP_N + EN_N) +
             1.0f * (acc[0] / (float)EP_N + acc[1] / (float)EN_N);
}

extern "C" void kernel_launch(void* const* d_in, const int* in_sizes, int n_in,
                              void* d_out, int out_size, void* d_ws, size_t ws_size,
                              hipStream_t stream) {
    const float* X = (const float*)d_in[0];
    const float* W_pos0 = (const float*)d_in[1];
    const float* b_pos0 = (const float*)d_in[2];
    const float* W_neg0 = (const float*)d_in[3];
    const float* b_neg0 = (const float*)d_in[4];
    const float* W_pos1 = (const float*)d_in[5];
    const float* b_pos1 = (const float*)d_in[6];
    const float* W_neg1 = (const float*)d_in[7];
    const float* b_neg1 = (const float*)d_in[8];
    const float* W_reg = (const float*)d_in[9];
    const int* pe = (const int*)d_in[10];
    const int* ne = (const int*)d_in[11];
    const int* target = (const int*)d_in[12];
    const int* ps = (const int*)d_in[13];
    const int* ns = (const int*)d_in[14];
    float* out = (float*)d_out;
    float* ws = (float*)d_ws;
    int* wsi = (int*)d_ws;

    float* acc = ws + ACC_OFF;
    int* cntP = wsi + I_CNTP;
    int* cntN = wsi + I_CNTN;
    int* curP = wsi + I_CURP;
    int* curN = wsi + I_CURN;
    int* offP = wsi + I_OFFP;
    int* offN = wsi + I_OFFN;
    int* csrP = wsi + I_CSRP;
    int* csrN = wsi + I_CSRN;
    int* part = wsi + I_PART;
    int4* eidx = (int4*)(wsi + I_EIDX);
    unsigned short* xb = (unsigned short*)(ws + F_XB);
    unsigned short* hboth = (unsigned short*)(ws + F_HB);
    float4* pnu = (float4*)(ws + F_PNU);
    float4* pnv = (float4*)(ws + F_PNV);
    unsigned char* zq = (unsigned char*)(ws + F_ZQ);
    unsigned short* wt = (unsigned short*)(ws + F_WT);
    float* z = out + 1;

    hipMemsetAsync(ws, 0, (size_t)(16 + 4 * N_NODES) * sizeof(float), stream);

    prep_kernel<<<XB_BLKS + WP_BLKS + CNT_BLKS + EI_BLKS, 256, 0, stream>>>(
        X, xb, W_pos0, W_neg0, W_pos1, W_neg1, wt, pe, ne, ps, ns, target,
        cntP, cntN, eidx);
    scan_p1<<<2 * SBLK, 512, 0, stream>>>(cntP, cntN, part);
    scan_p2<<<1, 512, 0, stream>>>(part);
    scan_p3<<<2 * SBLK, 512, 0, stream>>>(cntP, cntN, part, offP, offN, csrP, csrN);
    fill_kernel<<<(EP_N + EN_N + 255) / 256, 256, 0, stream>>>(pe, ne, offP, offN,
                                                               curP, curN, csrP, csrN);

    base_both<<<NODE_BLOCKS, 512, 0, stream>>>(xb, offP, csrP, offN, csrN, cntP, cntN,
                                               wt, b_pos0, b_neg0, hboth);
    deep_both<<<NODE_BLOCKS, 512, 0, stream>>>(hboth, offP, csrP, offN, csrN, cntP, cntN,
                                               wt + 16384, b_pos1, b_neg1,
                                               W_reg, z, zq, pnu, pnv);

    loss5_kernel<<<2048, 256, 0, stream>>>(zq, pnu, pnv, eidx, acc);
    finalize_kernel<<<1, 1, 0, stream>>>(acc, out);
}

// Round 12
// 366.486 us; speedup vs baseline: 1.3469x; 1.0366x over previous
//
#include <hip/hip_runtime.h>
#include <cstdint>

#define N_NODES 100000
#define EP_N 400000
#define EN_N 400000
#define NODE_BLOCKS ((N_NODES + 63) / 64)
#define SCHUNK 512
#define SBLK ((N_NODES + SCHUNK - 1) / SCHUNK)

#define BSTR 264   // base LDS row: [gP(64) | X(64) | gN(64) | X(64)] + 8 pad (ushorts)
#define DSTR 392   // deep LDS row: [posIn(192) | negIn(192)] + 8 pad (ushorts)

// prep_kernel block ranges
#define XB_BLKS ((((N_NODES + 1) * 16) + 255) / 256)
#define WP_BLKS 112
#define CNT_BLKS (((EP_N + EN_N) + 255) / 256)
#define EI_BLKS CNT_BLKS

// ws layout (in 4-byte units)
#define ACC_OFF 0
#define I_CNTP 16
#define I_CNTN (I_CNTP + N_NODES)
#define I_CURP (I_CNTN + N_NODES)
#define I_CURN (I_CURP + N_NODES)
#define I_OFFP (I_CURN + N_NODES)
#define I_OFFN (I_OFFP + N_NODES + 1)
#define I_CSRP (((I_OFFN + N_NODES + 1) + 3) & ~3)
#define CSR_SZ (EP_N + 4 * N_NODES)
#define I_CSRN (I_CSRP + CSR_SZ)
#define I_PART (I_CSRN + CSR_SZ)
#define I_EIDX (((I_PART + 2 * SBLK) + 3) & ~3)      // int4 per edge
#define F_XB (((I_EIDX + 4 * (EP_N + EN_N)) + 15) & ~15)
#define F_HB (F_XB + 32 * (N_NODES + 1))          // hboth: (N+1)*64 u32
#define F_PNU (F_HB + 64 * (N_NODES + 1))         // pnu: N float4
#define F_PNV (F_PNU + 4 * N_NODES)               // pnv: N float4
#define F_ZQ (F_PNV + 4 * N_NODES)                // zq: N*64 bytes
#define F_WT (((F_ZQ + 16 * N_NODES) + 15) & ~15) // wt: 28672 ushorts

typedef __attribute__((ext_vector_type(8))) short sh8;
typedef __attribute__((ext_vector_type(4))) float f32x4;

__device__ inline float bf2f(unsigned short u) {
    return __uint_as_float((unsigned)u << 16);
}
__device__ inline unsigned short f2bf(float v) {
    unsigned u = __float_as_uint(v);
    return (unsigned short)((u + 0x7FFFu + ((u >> 16) & 1u)) >> 16);
}
__device__ inline float lo_bf(unsigned u) { return __uint_as_float(u << 16); }
__device__ inline float hi_bf(unsigned u) { return __uint_as_float(u & 0xFFFF0000u); }

// 4-value fp8 dot of two packed dwords
__device__ inline float dot4f8(unsigned a, unsigned b) {
    float s = __builtin_amdgcn_cvt_f32_fp8(a, 0) * __builtin_amdgcn_cvt_f32_fp8(b, 0);
    s = fmaf(__builtin_amdgcn_cvt_f32_fp8(a, 1), __builtin_amdgcn_cvt_f32_fp8(b, 1), s);
    s = fmaf(__builtin_amdgcn_cvt_f32_fp8(a, 2), __builtin_amdgcn_cvt_f32_fp8(b, 2), s);
    s = fmaf(__builtin_amdgcn_cvt_f32_fp8(a, 3), __builtin_amdgcn_cvt_f32_fp8(b, 3), s);
    return s;
}

// fused: X->bf16 (+sentinel) | weight transpose->bf16 | degree count | eidx pack
__global__ void prep_kernel(const float* __restrict__ X, unsigned short* __restrict__ xb,
                            const float* __restrict__ W0p, const float* __restrict__ W0n,
                            const float* __restrict__ W1p, const float* __restrict__ W1n,
                            unsigned short* __restrict__ wt,
                            const int* __restrict__ pe, const int* __restrict__ ne,
                            const int* __restrict__ ps, const int* __restrict__ ns,
                            const int* __restrict__ tgt,
                            int* cp, int* cn, int4* __restrict__ eidx) {
    int b = blockIdx.x;
    if (b < XB_BLKS) {
        int i = b * 256 + threadIdx.x;
        if (i < (N_NODES + 1) * 16) {
            ushort4 o = {0, 0, 0, 0};
            if (i < N_NODES * 16) {
                float4 v = ((const float4*)X)[i];
                o.x = f2bf(v.x); o.y = f2bf(v.y); o.z = f2bf(v.z); o.w = f2bf(v.w);
            }
            ((ushort4*)xb)[i] = o;
        }
    } else if (b < XB_BLKS + WP_BLKS) {
        int i = (b - XB_BLKS) * 256 + threadIdx.x;
        if (i < 8192) {
            int n = i >> 7, k = i & 127;
            wt[i] = f2bf(W0p[k * 64 + n]);
        } else if (i < 16384) {
            int j = i - 8192; int n = j >> 7, k = j & 127;
            wt[i] = f2bf(W0n[k * 64 + n]);
        } else if (i < 22528) {
            int j = i - 16384; int n = j / 192, k = j - n * 192;
            wt[i] = f2bf(W1p[k * 32 + n]);
        } else if (i < 28672) {
            int j = i - 22528; int n = j / 192, k = j - n * 192;
            wt[i] = f2bf(W1n[k * 32 + n]);
        }
    } else if (b < XB_BLKS + WP_BLKS + CNT_BLKS) {
        int i = (b - XB_BLKS - WP_BLKS) * 256 + threadIdx.x;
        if (i < EP_N) {
            atomicAdd(&cp[pe[i]], 1);
        } else if (i < EP_N + EN_N) {
            atomicAdd(&cn[ne[i - EP_N]], 1);
        }
    } else {
        int e = (b - XB_BLKS - WP_BLKS - CNT_BLKS) * 256 + threadIdx.x;
        if (e < EP_N) {
            int4 q = {pe[e], pe[EP_N + e], ps[e], tgt[e]};
            eidx[e] = q;
        } else if (e < EP_N + EN_N) {
            int e2 = e - EP_N;
            int4 q = {ne[e2], ne[EN_N + e2], ns[e2], tgt[e]};
            eidx[e] = q;
        }
    }
}

__global__ __launch_bounds__(512) void scan_p1(const int* __restrict__ cntP,
                                               const int* __restrict__ cntN,
                                               int* part) {
    int l = blockIdx.x < SBLK ? 0 : 1;
    int blk = blockIdx.x - l * SBLK;
    const int* cnt = l == 0 ? cntP : cntN;
    int idx = blk * SCHUNK + threadIdx.x;
    int v = idx < N_NODES ? (cnt[idx] + 3) & ~3 : 0;   // padded counts
    __shared__ int tmp[512];
    tmp[threadIdx.x] = v;
    __syncthreads();
    for (int d = 256; d > 0; d >>= 1) {
        if (threadIdx.x < d) tmp[threadIdx.x] += tmp[threadIdx.x + d];
        __syncthreads();
    }
    if (threadIdx.x == 0) part[l * SBLK + blk] = tmp[0];
}

__global__ __launch_bounds__(512) void scan_p2(int* part) {
    int t = threadIdx.x;
    int l = t >> 8, idx = t & 255;
    int v = idx < SBLK ? part[l * SBLK + idx] : 0;
    __shared__ int tmp[512];
    int sb = l << 8;
    tmp[sb + idx] = v;
    __syncthreads();
    for (int d = 1; d < 256; d <<= 1) {
        int x = (idx >= d) ? tmp[sb + idx - d] : 0;
        __syncthreads();
        tmp[sb + idx] += x;
        __syncthreads();
    }
    if (idx < SBLK) part[l * SBLK + idx] = tmp[sb + idx] - v;
}

// padded offsets + sentinel pad fill
__global__ __launch_bounds__(512) void scan_p3(const int* __restrict__ cntP,
                                               const int* __restrict__ cntN,
                                               const int* __restrict__ part,
                                               int* offP, int* offN,
                                               int* csrP, int* csrN) {
    int l = blockIdx.x < SBLK ? 0 : 1;
    int blk = blockIdx.x - l * SBLK;
    const int* cnt = l == 0 ? cntP : cntN;
    int* off = l == 0 ? offP : offN;
    int* csr = l == 0 ? csrP : csrN;
    int base = part[l * SBLK + blk];
    int t = threadIdx.x;
    int gidx = blk * SCHUNK + t;
    int c = gidx < N_NODES ? cnt[gidx] : 0;
    int cpad = (c + 3) & ~3;
    __shared__ int tmp[512];
    tmp[t] = cpad;
    __syncthreads();
    for (int d = 1; d < 512; d <<= 1) {
        int x = (t >= d) ? tmp[t - d] : 0;
        __syncthreads();
        tmp[t] += x;
        __syncthreads();
    }
    int incl = tmp[t];
    if (gidx < N_NODES) {
        int o = base + incl - cpad;
        off[gidx] = o;
        for (int p = c; p < cpad; ++p) csr[o + p] = N_NODES;  // sentinel pads
    }
    if (gidx == N_NODES - 1) off[N_NODES] = base + incl;
}

__global__ void fill_kernel(const int* __restrict__ pe, const int* __restrict__ ne,
                            const int* __restrict__ offP, const int* __restrict__ offN,
                            int* curP, int* curN, int* csrP, int* csrN) {
    int e = blockIdx.x * 256 + threadIdx.x;
    if (e < EP_N) {
        int row = pe[e], col = pe[EP_N + e];
        int slot = atomicAdd(&curP[row], 1);
        csrP[offP[row] + slot] = col;
    } else if (e < EP_N + EN_N) {
        int e2 = e - EP_N;
        int row = ne[e2], col = ne[EN_N + e2];
        int slot = atomicAdd(&curN[row], 1);
        csrN[offN[row] + slot] = col;
    }
}

// joint P/N gather-mean over bf16 rows, 8 loads in flight in main loop
__device__ inline void gmb2(const unsigned short* __restrict__ src,
                            const int* __restrict__ csrP, int pP, int enP, int cP,
                            const int* __restrict__ csrN, int pN, int enN, int cN,
                            int lane, float& mP, float& mN) {
    float a0 = 0.f, a1 = 0.f, a2 = 0.f, a3 = 0.f;
    float b0 = 0.f, b1 = 0.f, b2 = 0.f, b3 = 0.f;
    while (pP < enP && pN < enN) {
        int4 ca = *(const int4*)(csrP + pP);
        int4 cb = *(const int4*)(csrN + pN);
        a0 += bf2f(src[ca.x * 64 + lane]);
        a1 += bf2f(src[ca.y * 64 + lane]);
        a2 += bf2f(src[ca.z * 64 + lane]);
        a3 += bf2f(src[ca.w * 64 + lane]);
        b0 += bf2f(src[cb.x * 64 + lane]);
        b1 += bf2f(src[cb.y * 64 + lane]);
        b2 += bf2f(src[cb.z * 64 + lane]);
        b3 += bf2f(src[cb.w * 64 + lane]);
        pP += 4; pN += 4;
    }
    for (; pP < enP; pP += 4) {
        int4 ca = *(const int4*)(csrP + pP);
        a0 += bf2f(src[ca.x * 64 + lane]);
        a1 += bf2f(src[ca.y * 64 + lane]);
        a2 += bf2f(src[ca.z * 64 + lane]);
        a3 += bf2f(src[ca.w * 64 + lane]);
    }
    for (; pN < enN; pN += 4) {
        int4 cb = *(const int4*)(csrN + pN);
        b0 += bf2f(src[cb.x * 64 + lane]);
        b1 += bf2f(src[cb.y * 64 + lane]);
        b2 += bf2f(src[cb.z * 64 + lane]);
        b3 += bf2f(src[cb.w * 64 + lane]);
    }
    mP = ((a0 + a1) + (a2 + a3)) / fmaxf((float)cP, 1.f);
    mN = ((b0 + b1) + (b2 + b3)) / fmaxf((float)cN, 1.f);
}

// joint P/N gather-mean of interleaved (hp,hn) u32 rows -> four means
__device__ inline void gd2(const unsigned* __restrict__ hb32,
                           const int* __restrict__ csrP, int pP, int enP, int cP,
                           const int* __restrict__ csrN, int pN, int enN, int cN,
                           int lane,
                           float& gPp, float& gPn, float& gNp, float& gNn) {
    float ap0 = 0.f, ap1 = 0.f, ap2 = 0.f, ap3 = 0.f;
    float an0 = 0.f, an1 = 0.f, an2 = 0.f, an3 = 0.f;
    float bp0 = 0.f, bp1 = 0.f, bp2 = 0.f, bp3 = 0.f;
    float bn0 = 0.f, bn1 = 0.f, bn2 = 0.f, bn3 = 0.f;
    while (pP < enP && pN < enN) {
        int4 ca = *(const int4*)(csrP + pP);
        int4 cb = *(const int4*)(csrN + pN);
        unsigned va0 = hb32[ca.x * 64 + lane];
        unsigned va1 = hb32[ca.y * 64 + lane];
        unsigned va2 = hb32[ca.z * 64 + lane];
        unsigned va3 = hb32[ca.w * 64 + lane];
        unsigned vb0 = hb32[cb.x * 64 + lane];
        unsigned vb1 = hb32[cb.y * 64 + lane];
        unsigned vb2 = hb32[cb.z * 64 + lane];
        unsigned vb3 = hb32[cb.w * 64 + lane];
        ap0 += lo_bf(va0); an0 += hi_bf(va0);
        ap1 += lo_bf(va1); an1 += hi_bf(va1);
        ap2 += lo_bf(va2); an2 += hi_bf(va2);
        ap3 += lo_bf(va3); an3 += hi_bf(va3);
        bp0 += lo_bf(vb0); bn0 += hi_bf(vb0);
        bp1 += lo_bf(vb1); bn1 += hi_bf(vb1);
        bp2 += lo_bf(vb2); bn2 += hi_bf(vb2);
        bp3 += lo_bf(vb3); bn3 += hi_bf(vb3);
        pP += 4; pN += 4;
    }
    for (; pP < enP; pP += 4) {
        int4 ca = *(const int4*)(csrP + pP);
        unsigned va0 = hb32[ca.x * 64 + lane];
        unsigned va1 = hb32[ca.y * 64 + lane];
        unsigned va2 = hb32[ca.z * 64 + lane];
        unsigned va3 = hb32[ca.w * 64 + lane];
        ap0 += lo_bf(va0); an0 += hi_bf(va0);
        ap1 += lo_bf(va1); an1 += hi_bf(va1);
        ap2 += lo_bf(va2); an2 += hi_bf(va2);
        ap3 += lo_bf(va3); an3 += hi_bf(va3);
    }
    for (; pN < enN; pN += 4) {
        int4 cb = *(const int4*)(csrN + pN);
        unsigned vb0 = hb32[cb.x * 64 + lane];
        unsigned vb1 = hb32[cb.y * 64 + lane];
        unsigned vb2 = hb32[cb.z * 64 + lane];
        unsigned vb3 = hb32[cb.w * 64 + lane];
        bp0 += lo_bf(vb0); bn0 += hi_bf(vb0);
        bp1 += lo_bf(vb1); bn1 += hi_bf(vb1);
        bp2 += lo_bf(vb2); bn2 += hi_bf(vb2);
        bp3 += lo_bf(vb3); bn3 += hi_bf(vb3);
    }
    float rP = 1.f / fmaxf((float)cP, 1.f), rN = 1.f / fmaxf((float)cN, 1.f);
    gPp = ((ap0 + ap1) + (ap2 + ap3)) * rP;
    gPn = ((an0 + an1) + (an2 + an3)) * rP;
    gNp = ((bp0 + bp1) + (bp2 + bp3)) * rN;
    gNn = ((bn0 + bn1) + (bn2 + bn3)) * rN;
}

// both base layers: gather (bf16) -> MFMA GEMM -> tanh -> interleaved bf16 h
__global__ __launch_bounds__(512) void base_both(
    const unsigned short* __restrict__ xb,
    const int* __restrict__ offP, const int* __restrict__ csrP,
    const int* __restrict__ offN, const int* __restrict__ csrN,
    const int* __restrict__ cntP, const int* __restrict__ cntN,
    const unsigned short* __restrict__ wt0,
    const float* __restrict__ bp0, const float* __restrict__ bn0,
    unsigned short* __restrict__ hboth) {
    __shared__ unsigned short lds[64 * BSTR];
    int tid = threadIdx.x, lane = tid & 63, w = tid >> 6;
    int base = blockIdx.x * 64;
    // zero sentinel row of hboth (once, before deep_both runs)
    if (blockIdx.x == 0 && tid < 64) ((unsigned*)hboth)[N_NODES * 64 + tid] = 0u;
    for (int r = w * 8; r < w * 8 + 8; ++r) {
        int node = base + r;
        float gP = 0.f, gN = 0.f;
        unsigned short sx = 0;
        if (node < N_NODES) {
            gmb2(xb, csrP, offP[node], offP[node + 1], cntP[node],
                 csrN, offN[node], offN[node + 1], cntN[node], lane, gP, gN);
            sx = xb[node * 64 + lane];
        }
        unsigned short* rp = &lds[r * BSTR];
        rp[lane] = f2bf(gP);
        rp[64 + lane] = sx;
        rp[128 + lane] = f2bf(gN);
        rp[192 + lane] = sx;
    }
    __syncthreads();
    int wu = __builtin_amdgcn_readfirstlane(w);
    int mt = wu >> 1, half = wu & 1;
    int l15 = lane & 15, kq = lane >> 4;
    const unsigned short* wbase = wt0 + half * 8192;
    f32x4 acc[4];
#pragma unroll
    for (int nt = 0; nt < 4; ++nt) acc[nt] = (f32x4){0.f, 0.f, 0.f, 0.f};
    const unsigned short* arow = &lds[(mt * 16 + l15) * BSTR + half * 128 + kq * 8];
#pragma unroll
    for (int ks = 0; ks < 4; ++ks) {
        sh8 a = *(const sh8*)(arow + ks * 32);
#pragma unroll
        for (int nt = 0; nt < 4; ++nt) {
            sh8 bf = *(const sh8*)(wbase + (nt * 16 + l15) * 128 + ks * 32 + kq * 8);
            acc[nt] = __builtin_amdgcn_mfma_f32_16x16x32_bf16(a, bf, acc[nt], 0, 0, 0);
        }
    }
    __syncthreads();
    float* ht = (float*)lds;  // [64][130]
    const float* bias = half ? bn0 : bp0;
#pragma unroll
    for (int nt = 0; nt < 4; ++nt) {
        int col = nt * 16 + l15;
        float bb = bias[col];
#pragma unroll
        for (int r = 0; r < 4; ++r) {
            int row = mt * 16 + kq * 4 + r;
            ht[row * 130 + half * 64 + col] = tanhf(acc[nt][r] + bb);
        }
    }
    __syncthreads();
    unsigned* hb32 = (unsigned*)hboth;
    for (int i = tid; i < 64 * 64; i += 512) {
        int rr = i >> 6, c = i & 63;
        int node = base + rr;
        if (node < N_NODES) {
            unsigned lo = f2bf(ht[rr * 130 + c]);
            unsigned hi = f2bf(ht[rr * 130 + 64 + c]);
            hb32[node * 64 + c] = lo | (hi << 16);
        }
    }
}

// both deep layers: gather -> MFMA GEMM -> tanh -> z/zq/pnu/pnv epilogue
__global__ __launch_bounds__(512) void deep_both(
    const unsigned short* __restrict__ hb,
    const int* __restrict__ offP, const int* __restrict__ csrP,
    const int* __restrict__ offN, const int* __restrict__ csrN,
    const int* __restrict__ cntP, const int* __restrict__ cntN,
    const unsigned short* __restrict__ wt1,
    const float* __restrict__ bp1, const float* __restrict__ bn1,
    const float* __restrict__ Wreg, float* __restrict__ z,
    unsigned char* __restrict__ zq, float4* __restrict__ pnu,
    float4* __restrict__ pnv) {
    __shared__ unsigned short lds[64 * DSTR];
    int tid = threadIdx.x, lane = tid & 63, w = tid >> 6;
    int base = blockIdx.x * 64;
    const unsigned* hb32 = (const unsigned*)hb;
    for (int r = w * 8; r < w * 8 + 8; ++r) {
        int node = base + r;
        float gPp = 0.f, gPn = 0.f, gNp = 0.f, gNn = 0.f, sp = 0.f, sn = 0.f;
        if (node < N_NODES) {
            gd2(hb32, csrP, offP[node], offP[node + 1], cntP[node],
                csrN, offN[node], offN[node + 1], cntN[node], lane,
                gPp, gPn, gNp, gNn);
            unsigned self = hb32[node * 64 + lane];
            sp = lo_bf(self);
            sn = hi_bf(self);
        }
        unsigned short* rp = &lds[r * DSTR];
        rp[lane] = f2bf(gPp);        // posIn[0:64]   = gm(h_pos, csrP)
        rp[64 + lane] = f2bf(gNn);   // posIn[64:128] = gm(h_neg, csrN)
        rp[128 + lane] = f2bf(sp);   // posIn[128:192]= h_pos self
        rp[192 + lane] = f2bf(gPn);  // negIn[0:64]   = gm(h_neg, csrP)
        rp[256 + lane] = f2bf(gNp);  // negIn[64:128] = gm(h_pos, csrN)
        rp[320 + lane] = f2bf(sn);   // negIn[128:192]= h_neg self
    }
    __syncthreads();
    int wu = __builtin_amdgcn_readfirstlane(w);
    int mt = wu >> 1, half = wu & 1;
    int l15 = lane & 15, kq = lane >> 4;
    const unsigned short* wbase = wt1 + half * 6144;
    f32x4 acc[2];
    acc[0] = (f32x4){0.f, 0.f, 0.f, 0.f};
    acc[1] = (f32x4){0.f, 0.f, 0.f, 0.f};
    const unsigned short* arow = &lds[(mt * 16 + l15) * DSTR + half * 192 + kq * 8];
#pragma unroll
    for (int ks = 0; ks < 6; ++ks) {
        sh8 a = *(const sh8*)(arow + ks * 32);
#pragma unroll
        for (int nt = 0; nt < 2; ++nt) {
            sh8 bf = *(const sh8*)(wbase + (nt * 16 + l15) * 192 + ks * 32 + kq * 8);
            acc[nt] = __builtin_amdgcn_mfma_f32_16x16x32_bf16(a, bf, acc[nt], 0, 0, 0);
        }
    }
    __syncthreads();
    float* ot = (float*)lds;  // [64][65]
    const float* bias = half ? bn1 : bp1;
#pragma unroll
    for (int nt = 0; nt < 2; ++nt) {
        int col = nt * 16 + l15;
        float bb = bias[col];
#pragma unroll
        for (int r = 0; r < 4; ++r) {
            int row = mt * 16 + kq * 4 + r;
            ot[row * 65 + half * 32 + col] = tanhf(acc[nt][r] + bb);
        }
    }
    __syncthreads();
    for (int r = w * 8; r < w * 8 + 8; ++r) {
        int node = base + r;
        if (node >= N_NODES) break;
        float v = ot[r * 65 + lane];
        z[node * 64 + lane] = v;
        int pq = __builtin_amdgcn_cvt_pk_fp8_f32(v, v, 0, false);
        zq[node * 64 + lane] = (unsigned char)(pq & 0xFF);
        float vq = __builtin_amdgcn_cvt_f32_fp8(pq, 0);
        float u0 = vq * Wreg[lane * 2 + 0];
        float u1 = vq * Wreg[lane * 2 + 1];
        float v0 = vq * Wreg[128 + lane * 2 + 0];
        float v1 = vq * Wreg[128 + lane * 2 + 1];
        float s = vq * vq;
#pragma unroll
        for (int off = 32; off; off >>= 1) {
            u0 += __shfl_xor(u0, off);
            u1 += __shfl_xor(u1, off);
            v0 += __shfl_xor(v0, off);
            v1 += __shfl_xor(v1, off);
            s += __shfl_xor(s, off);
        }
        if (lane == 0) {
            float4 su = {u0, u1, s, 0.f};
            float4 sv = {v0, v1, s, 0.f};
            pnu[node] = su;
            pnv[node] = sv;
        }
    }
}

// 4-lane edge groups, 16B/lane rows, two batches of 16 edges per iter
__global__ __launch_bounds__(256) void loss6_kernel(
    const unsigned char* __restrict__ zq, const float4* __restrict__ pnu,
    const float4* __restrict__ pnv, const int4* __restrict__ eidx, float* acc) {
    int tid = threadIdx.x;
    int lane = tid & 63;
    int g = lane >> 2, sub = lane & 3;   // 16 groups of 4 lanes
    int wid = (blockIdx.x * 256 + tid) >> 6;
    int nw = (gridDim.x * 256) >> 6;
    float s_p = 0.f, s_n = 0.f, s_r = 0.f;
    const float q = 0.25f;               // each edge duplicated in 4 lanes
    for (int eb = wid * 32; eb < EP_N + EN_N; eb += nw * 32) {
        int eA = eb + g, eB = eb + 16 + g;
        bool vA = eA < EP_N + EN_N, vB = eB < EP_N + EN_N;
        bool pA = eA < EP_N, pB = eB < EP_N;
        int4 qA = eidx[vA ? eA : 0];
        int4 qB = eidx[vB ? eB : 0];
        // 6 independent 16B row loads (each instruction covers 16 edges)
        uint4 ziA = *(const uint4*)(zq + ((long long)qA.x << 6) + (sub << 4));
        uint4 zjA = *(const uint4*)(zq + ((long long)qA.y << 6) + (sub << 4));
        uint4 zkA = *(const uint4*)(zq + ((long long)qA.z << 6) + (sub << 4));
        uint4 ziB = *(const uint4*)(zq + ((long long)qB.x << 6) + (sub << 4));
        uint4 zjB = *(const uint4*)(zq + ((long long)qB.y << 6) + (sub << 4));
        uint4 zkB = *(const uint4*)(zq + ((long long)qB.z << 6) + (sub << 4));
        // packed node-scalar loads (6 independent)
        float4 uA = pnu[qA.x];
        float4 wA = pnv[qA.y];
        float skA = pnu[qA.z].z;
        float4 uB = pnu[qB.x];
        float4 wB = pnv[qB.y];
        float skB = pnu[qB.z].z;
        // per-lane partial dots over 16 fp8 values
        float d1A = dot4f8(ziA.x, zjA.x) + dot4f8(ziA.y, zjA.y) +
                    dot4f8(ziA.z, zjA.z) + dot4f8(ziA.w, zjA.w);
        float d2A = dot4f8(zjA.x, zkA.x) + dot4f8(zjA.y, zkA.y) +
                    dot4f8(zjA.z, zkA.z) + dot4f8(zjA.w, zkA.w);
        float d1B = dot4f8(ziB.x, zjB.x) + dot4f8(ziB.y, zjB.y) +
                    dot4f8(ziB.z, zjB.z) + dot4f8(ziB.w, zjB.w);
        float d2B = dot4f8(zjB.x, zkB.x) + dot4f8(zjB.y, zkB.y) +
                    dot4f8(zjB.z, zkB.z) + dot4f8(zjB.w, zkB.w);
        // 2-step butterfly within 4-lane groups
#pragma unroll
        for (int off = 1; off < 4; off <<= 1) {
            d1A += __shfl_xor(d1A, off);
            d2A += __shfl_xor(d2A, off);
            d1B += __shfl_xor(d1B, off);
            d2B += __shfl_xor(d2B, off);
        }
        if (vA) {
            float nij = uA.z + wA.z - 2.f * d1A;
            float nik = wA.z + skA - 2.f * d2A;
            float tri = fmaxf(nij - nik, 0.f);
            float l0 = uA.x + wA.x, l1 = uA.y + wA.y;
            float m = fmaxf(l0, l1);
            float lse = m + logf(expf(l0 - m) + expf(l1 - m));
            s_r += (lse - (qA.w ? l1 : l0)) * q;
            if (pA) s_p += tri * q; else s_n += tri * q;
        }
        if (vB) {
            float nij = uB.z + wB.z - 2.f * d1B;
            float nik = wB.z + skB - 2.f * d2B;
            float tri = fmaxf(nij - nik, 0.f);
            float l0 = uB.x + wB.x, l1 = uB.y + wB.y;
            float m = fmaxf(l0, l1);
            float lse = m + logf(expf(l0 - m) + expf(l1 - m));
            s_r += (lse - (qB.w ? l1 : l0)) * q;
            if (pB) s_p += tri * q; else s_n += tri * q;
        }
    }
#pragma unroll
    for (int off = 32; off; off >>= 1) {
        s_p += __shfl_xor(s_p, off);
        s_n += __shfl_xor(s_n, off);
        s_r += __shfl_xor(s_r, off);
    }
    __shared__ float red[3][4];
    int w = tid >> 6;
    if (lane == 0) {
        red[0][w] = s_p; red[1][w] = s_n; red[2][w] = s_r;
    }
    __syncthreads();
    if (tid == 0) {
        atomicAdd(&acc[0], red[0][0] + red[0][1] + red[0][2] + red[0][3]);
        atomicAdd(&acc[1], red[1][0] + red[1][1] + red[1][2] + red[1][3]);
        atomicAdd(&acc[2], red[2][0] + red[2][1] + red[2][2] + red[2][3]);
    }
}

__global__ void finalize_kernel(const float* __restrict__ acc, float* out) {
    out[0] = acc[2] / (float)(EP_N + EN_N) +
             1.0f * (acc[0] / (float)EP_N + acc[1] / (float)EN_N);
}

extern "C" void kernel_launch(void* const* d_in, const int* in_sizes, int n_in,
                              void* d_out, int out_size, void* d_ws, size_t ws_size,
                              hipStream_t stream) {
    const float* X = (const float*)d_in[0];
    const float* W_pos0 = (const float*)d_in[1];
    const float* b_pos0 = (const float*)d_in[2];
    const float* W_neg0 = (const float*)d_in[3];
    const float* b_neg0 = (const float*)d_in[4];
    const float* W_pos1 = (const float*)d_in[5];
    const float* b_pos1 = (const float*)d_in[6];
    const float* W_neg1 = (const float*)d_in[7];
    const float* b_neg1 = (const float*)d_in[8];
    const float* W_reg = (const float*)d_in[9];
    const int* pe = (const int*)d_in[10];
    const int* ne = (const int*)d_in[11];
    const int* target = (const int*)d_in[12];
    const int* ps = (const int*)d_in[13];
    const int* ns = (const int*)d_in[14];
    float* out = (float*)d_out;
    float* ws = (float*)d_ws;
    int* wsi = (int*)d_ws;

    float* acc = ws + ACC_OFF;
    int* cntP = wsi + I_CNTP;
    int* cntN = wsi + I_CNTN;
    int* curP = wsi + I_CURP;
    int* curN = wsi + I_CURN;
    int* offP = wsi + I_OFFP;
    int* offN = wsi + I_OFFN;
    int* csrP = wsi + I_CSRP;
    int* csrN = wsi + I_CSRN;
    int* part = wsi + I_PART;
    int4* eidx = (int4*)(wsi + I_EIDX);
    unsigned short* xb = (unsigned short*)(ws + F_XB);
    unsigned short* hboth = (unsigned short*)(ws + F_HB);
    float4* pnu = (float4*)(ws + F_PNU);
    float4* pnv = (float4*)(ws + F_PNV);
    unsigned char* zq = (unsigned char*)(ws + F_ZQ);
    unsigned short* wt = (unsigned short*)(ws + F_WT);
    float* z = out + 1;

    hipMemsetAsync(ws, 0, (size_t)(16 + 4 * N_NODES) * sizeof(float), stream);

    prep_kernel<<<XB_BLKS + WP_BLKS + CNT_BLKS + EI_BLKS, 256, 0, stream>>>(
        X, xb, W_pos0, W_neg0, W_pos1, W_neg1, wt, pe, ne, ps, ns, target,
        cntP, cntN, eidx);
    scan_p1<<<2 * SBLK, 512, 0, stream>>>(cntP, cntN, part);
    scan_p2<<<1, 512, 0, stream>>>(part);
    scan_p3<<<2 * SBLK, 512, 0, stream>>>(cntP, cntN, part, offP, offN, csrP, csrN);
    fill_kernel<<<(EP_N + EN_N + 255) / 256, 256, 0, stream>>>(pe, ne, offP, offN,
                                                               curP, curN, csrP, csrN);

    base_both<<<NODE_BLOCKS, 512, 0, stream>>>(xb, offP, csrP, offN, csrN, cntP, cntN,
                                               wt, b_pos0, b_neg0, hboth);
    deep_both<<<NODE_BLOCKS, 512, 0, stream>>>(hboth, offP, csrP, offN, csrN, cntP, cntN,
                                               wt + 16384, b_pos1, b_neg1,
                                               W_reg, z, zq, pnu, pnv);

    loss6_kernel<<<2048, 256, 0, stream>>>(zq, pnu, pnv, eidx, acc);
    finalize_kernel<<<1, 1, 0, stream>>>(acc, out);
}

// Round 13
// 353.037 us; speedup vs baseline: 1.3982x; 1.0381x over previous
//
#include <hip/hip_runtime.h>
#include <cstdint>

#define N_NODES 100000
#define EP_N 400000
#define EN_N 400000
#define NODE_BLOCKS ((N_NODES + 63) / 64)
#define DEEP_BLOCKS (N_NODES / 32)   // 3125, exact
#define SCHUNK 512
#define SBLK ((N_NODES + SCHUNK - 1) / SCHUNK)

#define BSTR 264   // base LDS row: [gP(64) | X(64) | gN(64) | X(64)] + 8 pad (ushorts)
#define DSTR 392   // deep LDS row: [posIn(192) | negIn(192)] + 8 pad (ushorts)

// prep_kernel block ranges
#define XB_BLKS ((((N_NODES + 1) * 16) + 255) / 256)
#define WP_BLKS 112
#define CNT_BLKS (((EP_N + EN_N) + 255) / 256)
#define EI_BLKS CNT_BLKS

// ws layout (in 4-byte units)
#define ACC_OFF 0
#define I_CNTP 16
#define I_CNTN (I_CNTP + N_NODES)
#define I_CURP (I_CNTN + N_NODES)
#define I_CURN (I_CURP + N_NODES)
#define I_OFFP (I_CURN + N_NODES)
#define I_OFFN (I_OFFP + N_NODES + 1)
#define I_CSRP (((I_OFFN + N_NODES + 1) + 3) & ~3)
#define CSR_SZ (EP_N + 4 * N_NODES)
#define I_CSRN (I_CSRP + CSR_SZ)
#define I_PART (I_CSRN + CSR_SZ)
#define I_EIDX (((I_PART + 2 * SBLK) + 3) & ~3)      // int4 per edge
#define F_XB (((I_EIDX + 4 * (EP_N + EN_N)) + 15) & ~15)
#define F_HB (F_XB + 32 * (N_NODES + 1))          // hboth: (N+1)*64 u32
#define F_PNU (F_HB + 64 * (N_NODES + 1))         // pnu: N float4
#define F_PNV (F_PNU + 4 * N_NODES)               // pnv: N float4
#define F_ZQ (F_PNV + 4 * N_NODES)                // zq: N*64 bytes
#define F_WT (((F_ZQ + 16 * N_NODES) + 15) & ~15) // wt: 28672 ushorts

typedef __attribute__((ext_vector_type(8))) short sh8;
typedef __attribute__((ext_vector_type(4))) float f32x4;

__device__ inline float bf2f(unsigned short u) {
    return __uint_as_float((unsigned)u << 16);
}
__device__ inline unsigned short f2bf(float v) {
    unsigned u = __float_as_uint(v);
    return (unsigned short)((u + 0x7FFFu + ((u >> 16) & 1u)) >> 16);
}
__device__ inline float lo_bf(unsigned u) { return __uint_as_float(u << 16); }
__device__ inline float hi_bf(unsigned u) { return __uint_as_float(u & 0xFFFF0000u); }

// 4-value fp8 dot of two packed dwords
__device__ inline float dot4f8(unsigned a, unsigned b) {
    float s = __builtin_amdgcn_cvt_f32_fp8(a, 0) * __builtin_amdgcn_cvt_f32_fp8(b, 0);
    s = fmaf(__builtin_amdgcn_cvt_f32_fp8(a, 1), __builtin_amdgcn_cvt_f32_fp8(b, 1), s);
    s = fmaf(__builtin_amdgcn_cvt_f32_fp8(a, 2), __builtin_amdgcn_cvt_f32_fp8(b, 2), s);
    s = fmaf(__builtin_amdgcn_cvt_f32_fp8(a, 3), __builtin_amdgcn_cvt_f32_fp8(b, 3), s);
    return s;
}

// fused: X->bf16 (+sentinel) | weight transpose->bf16 | degree count | eidx pack
__global__ void prep_kernel(const float* __restrict__ X, unsigned short* __restrict__ xb,
                            const float* __restrict__ W0p, const float* __restrict__ W0n,
                            const float* __restrict__ W1p, const float* __restrict__ W1n,
                            unsigned short* __restrict__ wt,
                            const int* __restrict__ pe, const int* __restrict__ ne,
                            const int* __restrict__ ps, const int* __restrict__ ns,
                            const int* __restrict__ tgt,
                            int* cp, int* cn, int4* __restrict__ eidx) {
    int b = blockIdx.x;
    if (b < XB_BLKS) {
        int i = b * 256 + threadIdx.x;
        if (i < (N_NODES + 1) * 16) {
            ushort4 o = {0, 0, 0, 0};
            if (i < N_NODES * 16) {
                float4 v = ((const float4*)X)[i];
                o.x = f2bf(v.x); o.y = f2bf(v.y); o.z = f2bf(v.z); o.w = f2bf(v.w);
            }
            ((ushort4*)xb)[i] = o;
        }
    } else if (b < XB_BLKS + WP_BLKS) {
        int i = (b - XB_BLKS) * 256 + threadIdx.x;
        if (i < 8192) {
            int n = i >> 7, k = i & 127;
            wt[i] = f2bf(W0p[k * 64 + n]);
        } else if (i < 16384) {
            int j = i - 8192; int n = j >> 7, k = j & 127;
            wt[i] = f2bf(W0n[k * 64 + n]);
        } else if (i < 22528) {
            int j = i - 16384; int n = j / 192, k = j - n * 192;
            wt[i] = f2bf(W1p[k * 32 + n]);
        } else if (i < 28672) {
            int j = i - 22528; int n = j / 192, k = j - n * 192;
            wt[i] = f2bf(W1n[k * 32 + n]);
        }
    } else if (b < XB_BLKS + WP_BLKS + CNT_BLKS) {
        int i = (b - XB_BLKS - WP_BLKS) * 256 + threadIdx.x;
        if (i < EP_N) {
            atomicAdd(&cp[pe[i]], 1);
        } else if (i < EP_N + EN_N) {
            atomicAdd(&cn[ne[i - EP_N]], 1);
        }
    } else {
        int e = (b - XB_BLKS - WP_BLKS - CNT_BLKS) * 256 + threadIdx.x;
        if (e < EP_N) {
            int4 q = {pe[e], pe[EP_N + e], ps[e], tgt[e]};
            eidx[e] = q;
        } else if (e < EP_N + EN_N) {
            int e2 = e - EP_N;
            int4 q = {ne[e2], ne[EN_N + e2], ns[e2], tgt[e]};
            eidx[e] = q;
        }
    }
}

__global__ __launch_bounds__(512) void scan_p1(const int* __restrict__ cntP,
                                               const int* __restrict__ cntN,
                                               int* part) {
    int l = blockIdx.x < SBLK ? 0 : 1;
    int blk = blockIdx.x - l * SBLK;
    const int* cnt = l == 0 ? cntP : cntN;
    int idx = blk * SCHUNK + threadIdx.x;
    int v = idx < N_NODES ? (cnt[idx] + 3) & ~3 : 0;   // padded counts
    __shared__ int tmp[512];
    tmp[threadIdx.x] = v;
    __syncthreads();
    for (int d = 256; d > 0; d >>= 1) {
        if (threadIdx.x < d) tmp[threadIdx.x] += tmp[threadIdx.x + d];
        __syncthreads();
    }
    if (threadIdx.x == 0) part[l * SBLK + blk] = tmp[0];
}

__global__ __launch_bounds__(512) void scan_p2(int* part) {
    int t = threadIdx.x;
    int l = t >> 8, idx = t & 255;
    int v = idx < SBLK ? part[l * SBLK + idx] : 0;
    __shared__ int tmp[512];
    int sb = l << 8;
    tmp[sb + idx] = v;
    __syncthreads();
    for (int d = 1; d < 256; d <<= 1) {
        int x = (idx >= d) ? tmp[sb + idx - d] : 0;
        __syncthreads();
        tmp[sb + idx] += x;
        __syncthreads();
    }
    if (idx < SBLK) part[l * SBLK + idx] = tmp[sb + idx] - v;
}

// padded offsets + sentinel pad fill
__global__ __launch_bounds__(512) void scan_p3(const int* __restrict__ cntP,
                                               const int* __restrict__ cntN,
                                               const int* __restrict__ part,
                                               int* offP, int* offN,
                                               int* csrP, int* csrN) {
    int l = blockIdx.x < SBLK ? 0 : 1;
    int blk = blockIdx.x - l * SBLK;
    const int* cnt = l == 0 ? cntP : cntN;
    int* off = l == 0 ? offP : offN;
    int* csr = l == 0 ? csrP : csrN;
    int base = part[l * SBLK + blk];
    int t = threadIdx.x;
    int gidx = blk * SCHUNK + t;
    int c = gidx < N_NODES ? cnt[gidx] : 0;
    int cpad = (c + 3) & ~3;
    __shared__ int tmp[512];
    tmp[t] = cpad;
    __syncthreads();
    for (int d = 1; d < 512; d <<= 1) {
        int x = (t >= d) ? tmp[t - d] : 0;
        __syncthreads();
        tmp[t] += x;
        __syncthreads();
    }
    int incl = tmp[t];
    if (gidx < N_NODES) {
        int o = base + incl - cpad;
        off[gidx] = o;
        for (int p = c; p < cpad; ++p) csr[o + p] = N_NODES;  // sentinel pads
    }
    if (gidx == N_NODES - 1) off[N_NODES] = base + incl;
}

__global__ void fill_kernel(const int* __restrict__ pe, const int* __restrict__ ne,
                            const int* __restrict__ offP, const int* __restrict__ offN,
                            int* curP, int* curN, int* csrP, int* csrN) {
    int e = blockIdx.x * 256 + threadIdx.x;
    if (e < EP_N) {
        int row = pe[e], col = pe[EP_N + e];
        int slot = atomicAdd(&curP[row], 1);
        csrP[offP[row] + slot] = col;
    } else if (e < EP_N + EN_N) {
        int e2 = e - EP_N;
        int row = ne[e2], col = ne[EN_N + e2];
        int slot = atomicAdd(&curN[row], 1);
        csrN[offN[row] + slot] = col;
    }
}

// split-row joint P/N gather-mean over bf16 rows (4B/lane, 2 rows/load-inst)
// hf = lane>>5 (row parity), l5 = lane&31 (dim pair index)
__device__ inline void gmb2w(const unsigned* __restrict__ xb32,
                             const int* __restrict__ csrP, int pP, int enP, int cP,
                             const int* __restrict__ csrN, int pN, int enN, int cN,
                             int hf, int l5,
                             float& gP0, float& gP1, float& gN0, float& gN1) {
    float a0 = 0.f, a1 = 0.f, b0 = 0.f, b1 = 0.f;
    while (pP < enP && pN < enN) {
        int4 ca = *(const int4*)(csrP + pP);
        int4 cb = *(const int4*)(csrN + pN);
        int cA0 = hf ? ca.y : ca.x;
        int cA1 = hf ? ca.w : ca.z;
        int cB0 = hf ? cb.y : cb.x;
        int cB1 = hf ? cb.w : cb.z;
        unsigned va0 = xb32[cA0 * 32 + l5];
        unsigned va1 = xb32[cA1 * 32 + l5];
        unsigned vb0 = xb32[cB0 * 32 + l5];
        unsigned vb1 = xb32[cB1 * 32 + l5];
        a0 += lo_bf(va0) + lo_bf(va1);
        a1 += hi_bf(va0) + hi_bf(va1);
        b0 += lo_bf(vb0) + lo_bf(vb1);
        b1 += hi_bf(vb0) + hi_bf(vb1);
        pP += 4; pN += 4;
    }
    for (; pP < enP; pP += 4) {
        int4 ca = *(const int4*)(csrP + pP);
        int cA0 = hf ? ca.y : ca.x;
        int cA1 = hf ? ca.w : ca.z;
        unsigned va0 = xb32[cA0 * 32 + l5];
        unsigned va1 = xb32[cA1 * 32 + l5];
        a0 += lo_bf(va0) + lo_bf(va1);
        a1 += hi_bf(va0) + hi_bf(va1);
    }
    for (; pN < enN; pN += 4) {
        int4 cb = *(const int4*)(csrN + pN);
        int cB0 = hf ? cb.y : cb.x;
        int cB1 = hf ? cb.w : cb.z;
        unsigned vb0 = xb32[cB0 * 32 + l5];
        unsigned vb1 = xb32[cB1 * 32 + l5];
        b0 += lo_bf(vb0) + lo_bf(vb1);
        b1 += hi_bf(vb0) + hi_bf(vb1);
    }
    a0 += __shfl_xor(a0, 32); a1 += __shfl_xor(a1, 32);
    b0 += __shfl_xor(b0, 32); b1 += __shfl_xor(b1, 32);
    float rP = 1.f / fmaxf((float)cP, 1.f), rN = 1.f / fmaxf((float)cN, 1.f);
    gP0 = a0 * rP; gP1 = a1 * rP;
    gN0 = b0 * rN; gN1 = b1 * rN;
}

// split-row joint P/N gather-mean of interleaved (hp,hn) rows (8B/lane, 2 rows/load)
__device__ inline void gd2w(const unsigned* __restrict__ hb32,
                            const int* __restrict__ csrP, int pP, int enP, int cP,
                            const int* __restrict__ csrN, int pN, int enN, int cN,
                            int hf, int l5,
                            float& gPp0, float& gPp1, float& gPn0, float& gPn1,
                            float& gNp0, float& gNp1, float& gNn0, float& gNn1) {
    float ap0 = 0.f, ap1 = 0.f, an0 = 0.f, an1 = 0.f;
    float bp0 = 0.f, bp1 = 0.f, bn0 = 0.f, bn1 = 0.f;
    while (pP < enP && pN < enN) {
        int4 ca = *(const int4*)(csrP + pP);
        int4 cb = *(const int4*)(csrN + pN);
        int cA0 = hf ? ca.y : ca.x;
        int cA1 = hf ? ca.w : ca.z;
        int cB0 = hf ? cb.y : cb.x;
        int cB1 = hf ? cb.w : cb.z;
        uint2 va0 = *(const uint2*)(hb32 + cA0 * 64 + l5 * 2);
        uint2 va1 = *(const uint2*)(hb32 + cA1 * 64 + l5 * 2);
        uint2 vb0 = *(const uint2*)(hb32 + cB0 * 64 + l5 * 2);
        uint2 vb1 = *(const uint2*)(hb32 + cB1 * 64 + l5 * 2);
        ap0 += lo_bf(va0.x) + lo_bf(va1.x);
        an0 += hi_bf(va0.x) + hi_bf(va1.x);
        ap1 += lo_bf(va0.y) + lo_bf(va1.y);
        an1 += hi_bf(va0.y) + hi_bf(va1.y);
        bp0 += lo_bf(vb0.x) + lo_bf(vb1.x);
        bn0 += hi_bf(vb0.x) + hi_bf(vb1.x);
        bp1 += lo_bf(vb0.y) + lo_bf(vb1.y);
        bn1 += hi_bf(vb0.y) + hi_bf(vb1.y);
        pP += 4; pN += 4;
    }
    for (; pP < enP; pP += 4) {
        int4 ca = *(const int4*)(csrP + pP);
        int cA0 = hf ? ca.y : ca.x;
        int cA1 = hf ? ca.w : ca.z;
        uint2 va0 = *(const uint2*)(hb32 + cA0 * 64 + l5 * 2);
        uint2 va1 = *(const uint2*)(hb32 + cA1 * 64 + l5 * 2);
        ap0 += lo_bf(va0.x) + lo_bf(va1.x);
        an0 += hi_bf(va0.x) + hi_bf(va1.x);
        ap1 += lo_bf(va0.y) + lo_bf(va1.y);
        an1 += hi_bf(va0.y) + hi_bf(va1.y);
    }
    for (; pN < enN; pN += 4) {
        int4 cb = *(const int4*)(csrN + pN);
        int cB0 = hf ? cb.y : cb.x;
        int cB1 = hf ? cb.w : cb.z;
        uint2 vb0 = *(const uint2*)(hb32 + cB0 * 64 + l5 * 2);
        uint2 vb1 = *(const uint2*)(hb32 + cB1 * 64 + l5 * 2);
        bp0 += lo_bf(vb0.x) + lo_bf(vb1.x);
        bn0 += hi_bf(vb0.x) + hi_bf(vb1.x);
        bp1 += lo_bf(vb0.y) + lo_bf(vb1.y);
        bn1 += hi_bf(vb0.y) + hi_bf(vb1.y);
    }
    ap0 += __shfl_xor(ap0, 32); ap1 += __shfl_xor(ap1, 32);
    an0 += __shfl_xor(an0, 32); an1 += __shfl_xor(an1, 32);
    bp0 += __shfl_xor(bp0, 32); bp1 += __shfl_xor(bp1, 32);
    bn0 += __shfl_xor(bn0, 32); bn1 += __shfl_xor(bn1, 32);
    float rP = 1.f / fmaxf((float)cP, 1.f), rN = 1.f / fmaxf((float)cN, 1.f);
    gPp0 = ap0 * rP; gPp1 = ap1 * rP; gPn0 = an0 * rP; gPn1 = an1 * rP;
    gNp0 = bp0 * rN; gNp1 = bp1 * rN; gNn0 = bn0 * rN; gNn1 = bn1 * rN;
}

// both base layers: split-row gather -> MFMA GEMM -> tanh -> interleaved bf16 h
__global__ __launch_bounds__(512) void base_both(
    const unsigned short* __restrict__ xb,
    const int* __restrict__ offP, const int* __restrict__ csrP,
    const int* __restrict__ offN, const int* __restrict__ csrN,
    const int* __restrict__ cntP, const int* __restrict__ cntN,
    const unsigned short* __restrict__ wt0,
    const float* __restrict__ bp0, const float* __restrict__ bn0,
    unsigned short* __restrict__ hboth) {
    __shared__ unsigned short lds[64 * BSTR];
    int tid = threadIdx.x, lane = tid & 63, w = tid >> 6;
    int hf = lane >> 5, l5 = lane & 31;
    int base = blockIdx.x * 64;
    const unsigned* xb32 = (const unsigned*)xb;
    // zero sentinel row of hboth (once, before deep_both runs)
    if (blockIdx.x == 0 && tid < 64) ((unsigned*)hboth)[N_NODES * 64 + tid] = 0u;
    for (int r = w * 8; r < w * 8 + 8; ++r) {
        int node = base + r;
        float gP0 = 0.f, gP1 = 0.f, gN0 = 0.f, gN1 = 0.f;
        unsigned sxv = 0;
        if (node < N_NODES) {
            gmb2w(xb32, csrP, offP[node], offP[node + 1], cntP[node],
                  csrN, offN[node], offN[node + 1], cntN[node], hf, l5,
                  gP0, gP1, gN0, gN1);
            sxv = xb32[node * 32 + l5];
        }
        unsigned* rp32 = (unsigned*)&lds[r * BSTR];
        if (hf == 0) {
            rp32[l5] = (unsigned)f2bf(gP0) | ((unsigned)f2bf(gP1) << 16);
            rp32[32 + l5] = sxv;
        } else {
            rp32[64 + l5] = (unsigned)f2bf(gN0) | ((unsigned)f2bf(gN1) << 16);
            rp32[96 + l5] = sxv;
        }
    }
    __syncthreads();
    int wu = __builtin_amdgcn_readfirstlane(w);
    int mt = wu >> 1, half = wu & 1;
    int l15 = lane & 15, kq = lane >> 4;
    const unsigned short* wbase = wt0 + half * 8192;
    f32x4 acc[4];
#pragma unroll
    for (int nt = 0; nt < 4; ++nt) acc[nt] = (f32x4){0.f, 0.f, 0.f, 0.f};
    const unsigned short* arow = &lds[(mt * 16 + l15) * BSTR + half * 128 + kq * 8];
#pragma unroll
    for (int ks = 0; ks < 4; ++ks) {
        sh8 a = *(const sh8*)(arow + ks * 32);
#pragma unroll
        for (int nt = 0; nt < 4; ++nt) {
            sh8 bf = *(const sh8*)(wbase + (nt * 16 + l15) * 128 + ks * 32 + kq * 8);
            acc[nt] = __builtin_amdgcn_mfma_f32_16x16x32_bf16(a, bf, acc[nt], 0, 0, 0);
        }
    }
    __syncthreads();
    float* ht = (float*)lds;  // [64][130]
    const float* bias = half ? bn0 : bp0;
#pragma unroll
    for (int nt = 0; nt < 4; ++nt) {
        int col = nt * 16 + l15;
        float bb = bias[col];
#pragma unroll
        for (int r = 0; r < 4; ++r) {
            int row = mt * 16 + kq * 4 + r;
            ht[row * 130 + half * 64 + col] = tanhf(acc[nt][r] + bb);
        }
    }
    __syncthreads();
    unsigned* hb32 = (unsigned*)hboth;
    for (int i = tid; i < 64 * 64; i += 512) {
        int rr = i >> 6, c = i & 63;
        int node = base + rr;
        if (node < N_NODES) {
            unsigned lo = f2bf(ht[rr * 130 + c]);
            unsigned hi = f2bf(ht[rr * 130 + 64 + c]);
            hb32[node * 64 + c] = lo | (hi << 16);
        }
    }
}

// both deep layers: 32-node blocks, split-row gather -> MFMA -> tanh -> epilogue
__global__ __launch_bounds__(512) void deep_both(
    const unsigned short* __restrict__ hb,
    const int* __restrict__ offP, const int* __restrict__ csrP,
    const int* __restrict__ offN, const int* __restrict__ csrN,
    const int* __restrict__ cntP, const int* __restrict__ cntN,
    const unsigned short* __restrict__ wt1,
    const float* __restrict__ bp1, const float* __restrict__ bn1,
    const float* __restrict__ Wreg, float* __restrict__ z,
    unsigned char* __restrict__ zq, float4* __restrict__ pnu,
    float4* __restrict__ pnv) {
    __shared__ unsigned short lds[32 * DSTR];   // 25088 B
    int tid = threadIdx.x, lane = tid & 63, w = tid >> 6;
    int hf = lane >> 5, l5 = lane & 31;
    int base = blockIdx.x * 32;                 // grid exact: 3125*32 = 100000
    const unsigned* hb32 = (const unsigned*)hb;
    for (int r = w * 4; r < w * 4 + 4; ++r) {
        int node = base + r;
        float gPp0, gPp1, gPn0, gPn1, gNp0, gNp1, gNn0, gNn1;
        gd2w(hb32, csrP, offP[node], offP[node + 1], cntP[node],
             csrN, offN[node], offN[node + 1], cntN[node], hf, l5,
             gPp0, gPp1, gPn0, gPn1, gNp0, gNp1, gNn0, gNn1);
        uint2 sv = *(const uint2*)(hb32 + node * 64 + l5 * 2);
        unsigned* rp32 = (unsigned*)&lds[r * DSTR];
        if (hf == 0) {
            rp32[l5] = (unsigned)f2bf(gPp0) | ((unsigned)f2bf(gPp1) << 16);
            rp32[32 + l5] = (unsigned)f2bf(gNn0) | ((unsigned)f2bf(gNn1) << 16);
            rp32[64 + l5] = (sv.x & 0xFFFFu) | ((sv.y & 0xFFFFu) << 16);  // hp pair
        } else {
            rp32[96 + l5] = (unsigned)f2bf(gPn0) | ((unsigned)f2bf(gPn1) << 16);
            rp32[128 + l5] = (unsigned)f2bf(gNp0) | ((unsigned)f2bf(gNp1) << 16);
            rp32[160 + l5] = (sv.x >> 16) | (sv.y & 0xFFFF0000u);         // hn pair
        }
    }
    __syncthreads();
    int wu = __builtin_amdgcn_readfirstlane(w);
    int mt = wu >> 2, half = (wu >> 1) & 1, nt = wu & 1;
    int l15 = lane & 15, kq = lane >> 4;
    const unsigned short* wbase = wt1 + half * 6144;
    f32x4 acc = (f32x4){0.f, 0.f, 0.f, 0.f};
    const unsigned short* arow = &lds[(mt * 16 + l15) * DSTR + half * 192 + kq * 8];
#pragma unroll
    for (int ks = 0; ks < 6; ++ks) {
        sh8 a = *(const sh8*)(arow + ks * 32);
        sh8 bf = *(const sh8*)(wbase + (nt * 16 + l15) * 192 + ks * 32 + kq * 8);
        acc = __builtin_amdgcn_mfma_f32_16x16x32_bf16(a, bf, acc, 0, 0, 0);
    }
    __syncthreads();
    float* ot = (float*)lds;  // [32][65]
    {
        const float* bias = half ? bn1 : bp1;
        int col = nt * 16 + l15;
        float bb = bias[col];
#pragma unroll
        for (int r = 0; r < 4; ++r) {
            int row = mt * 16 + kq * 4 + r;
            ot[row * 65 + half * 32 + col] = tanhf(acc[r] + bb);
        }
    }
    __syncthreads();
    for (int r = w * 4; r < w * 4 + 4; ++r) {
        int node = base + r;
        float v = ot[r * 65 + lane];
        z[node * 64 + lane] = v;
        int pq = __builtin_amdgcn_cvt_pk_fp8_f32(v, v, 0, false);
        zq[node * 64 + lane] = (unsigned char)(pq & 0xFF);
        float vq = __builtin_amdgcn_cvt_f32_fp8(pq, 0);
        float u0 = vq * Wreg[lane * 2 + 0];
        float u1 = vq * Wreg[lane * 2 + 1];
        float v0 = vq * Wreg[128 + lane * 2 + 0];
        float v1 = vq * Wreg[128 + lane * 2 + 1];
        float s = vq * vq;
#pragma unroll
        for (int off = 32; off; off >>= 1) {
            u0 += __shfl_xor(u0, off);
            u1 += __shfl_xor(u1, off);
            v0 += __shfl_xor(v0, off);
            v1 += __shfl_xor(v1, off);
            s += __shfl_xor(s, off);
        }
        if (lane == 0) {
            float4 su = {u0, u1, s, 0.f};
            float4 sv2 = {v0, v1, s, 0.f};
            pnu[node] = su;
            pnv[node] = sv2;
        }
    }
}

// 4-lane edge groups, 16B/lane rows, two batches of 16 edges per iter
__global__ __launch_bounds__(256) void loss6_kernel(
    const unsigned char* __restrict__ zq, const float4* __restrict__ pnu,
    const float4* __restrict__ pnv, const int4* __restrict__ eidx, float* acc) {
    int tid = threadIdx.x;
    int lane = tid & 63;
    int g = lane >> 2, sub = lane & 3;   // 16 groups of 4 lanes
    int wid = (blockIdx.x * 256 + tid) >> 6;
    int nw = (gridDim.x * 256) >> 6;
    float s_p = 0.f, s_n = 0.f, s_r = 0.f;
    const float q = 0.25f;               // each edge duplicated in 4 lanes
    for (int eb = wid * 32; eb < EP_N + EN_N; eb += nw * 32) {
        int eA = eb + g, eB = eb + 16 + g;
        bool vA = eA < EP_N + EN_N, vB = eB < EP_N + EN_N;
        bool pA = eA < EP_N, pB = eB < EP_N;
        int4 qA = eidx[vA ? eA : 0];
        int4 qB = eidx[vB ? eB : 0];
        // 6 independent 16B row loads (each instruction covers 16 edges)
        uint4 ziA = *(const uint4*)(zq + ((long long)qA.x << 6) + (sub << 4));
        uint4 zjA = *(const uint4*)(zq + ((long long)qA.y << 6) + (sub << 4));
        uint4 zkA = *(const uint4*)(zq + ((long long)qA.z << 6) + (sub << 4));
        uint4 ziB = *(const uint4*)(zq + ((long long)qB.x << 6) + (sub << 4));
        uint4 zjB = *(const uint4*)(zq + ((long long)qB.y << 6) + (sub << 4));
        uint4 zkB = *(const uint4*)(zq + ((long long)qB.z << 6) + (sub << 4));
        // packed node-scalar loads (6 independent)
        float4 uA = pnu[qA.x];
        float4 wA = pnv[qA.y];
        float skA = pnu[qA.z].z;
        float4 uB = pnu[qB.x];
        float4 wB = pnv[qB.y];
        float skB = pnu[qB.z].z;
        // per-lane partial dots over 16 fp8 values
        float d1A = dot4f8(ziA.x, zjA.x) + dot4f8(ziA.y, zjA.y) +
                    dot4f8(ziA.z, zjA.z) + dot4f8(ziA.w, zjA.w);
        float d2A = dot4f8(zjA.x, zkA.x) + dot4f8(zjA.y, zkA.y) +
                    dot4f8(zjA.z, zkA.z) + dot4f8(zjA.w, zkA.w);
        float d1B = dot4f8(ziB.x, zjB.x) + dot4f8(ziB.y, zjB.y) +
                    dot4f8(ziB.z, zjB.z) + dot4f8(ziB.w, zjB.w);
        float d2B = dot4f8(zjB.x, zkB.x) + dot4f8(zjB.y, zkB.y) +
                    dot4f8(zjB.z, zkB.z) + dot4f8(zjB.w, zkB.w);
        // 2-step butterfly within 4-lane groups
#pragma unroll
        for (int off = 1; off < 4; off <<= 1) {
            d1A += __shfl_xor(d1A, off);
            d2A += __shfl_xor(d2A, off);
            d1B += __shfl_xor(d1B, off);
            d2B += __shfl_xor(d2B, off);
        }
        if (vA) {
            float nij = uA.z + wA.z - 2.f * d1A;
            float nik = wA.z + skA - 2.f * d2A;
            float tri = fmaxf(nij - nik, 0.f);
            float l0 = uA.x + wA.x, l1 = uA.y + wA.y;
            float m = fmaxf(l0, l1);
            float lse = m + logf(expf(l0 - m) + expf(l1 - m));
            s_r += (lse - (qA.w ? l1 : l0)) * q;
            if (pA) s_p += tri * q; else s_n += tri * q;
        }
        if (vB) {
            float nij = uB.z + wB.z - 2.f * d1B;
            float nik = wB.z + skB - 2.f * d2B;
            float tri = fmaxf(nij - nik, 0.f);
            float l0 = uB.x + wB.x, l1 = uB.y + wB.y;
            float m = fmaxf(l0, l1);
            float lse = m + logf(expf(l0 - m) + expf(l1 - m));
            s_r += (lse - (qB.w ? l1 : l0)) * q;
            if (pB) s_p += tri * q; else s_n += tri * q;
        }
    }
#pragma unroll
    for (int off = 32; off; off >>= 1) {
        s_p += __shfl_xor(s_p, off);
        s_n += __shfl_xor(s_n, off);
        s_r += __shfl_xor(s_r, off);
    }
    __shared__ float red[3][4];
    int w = tid >> 6;
    if (lane == 0) {
        red[0][w] = s_p; red[1][w] = s_n; red[2][w] = s_r;
    }
    __syncthreads();
    if (tid == 0) {
        atomicAdd(&acc[0], red[0][0] + red[0][1] + red[0][2] + red[0][3]);
        atomicAdd(&acc[1], red[1][0] + red[1][1] + red[1][2] + red[1][3]);
        atomicAdd(&acc[2], red[2][0] + red[2][1] + red[2][2] + red[2][3]);
    }
}

__global__ void finalize_kernel(const float* __restrict__ acc, float* out) {
    out[0] = acc[2] / (float)(EP_N + EN_N) +
             1.0f * (acc[0] / (float)EP_N + acc[1] / (float)EN_N);
}

extern "C" void kernel_launch(void* const* d_in, const int* in_sizes, int n_in,
                              void* d_out, int out_size, void* d_ws, size_t ws_size,
                              hipStream_t stream) {
    const float* X = (const float*)d_in[0];
    const float* W_pos0 = (const float*)d_in[1];
    const float* b_pos0 = (const float*)d_in[2];
    const float* W_neg0 = (const float*)d_in[3];
    const float* b_neg0 = (const float*)d_in[4];
    const float* W_pos1 = (const float*)d_in[5];
    const float* b_pos1 = (const float*)d_in[6];
    const float* W_neg1 = (const float*)d_in[7];
    const float* b_neg1 = (const float*)d_in[8];
    const float* W_reg = (const float*)d_in[9];
    const int* pe = (const int*)d_in[10];
    const int* ne = (const int*)d_in[11];
    const int* target = (const int*)d_in[12];
    const int* ps = (const int*)d_in[13];
    const int* ns = (const int*)d_in[14];
    float* out = (float*)d_out;
    float* ws = (float*)d_ws;
    int* wsi = (int*)d_ws;

    float* acc = ws + ACC_OFF;
    int* cntP = wsi + I_CNTP;
    int* cntN = wsi + I_CNTN;
    int* curP = wsi + I_CURP;
    int* curN = wsi + I_CURN;
    int* offP = wsi + I_OFFP;
    int* offN = wsi + I_OFFN;
    int* csrP = wsi + I_CSRP;
    int* csrN = wsi + I_CSRN;
    int* part = wsi + I_PART;
    int4* eidx = (int4*)(wsi + I_EIDX);
    unsigned short* xb = (unsigned short*)(ws + F_XB);
    unsigned short* hboth = (unsigned short*)(ws + F_HB);
    float4* pnu = (float4*)(ws + F_PNU);
    float4* pnv = (float4*)(ws + F_PNV);
    unsigned char* zq = (unsigned char*)(ws + F_ZQ);
    unsigned short* wt = (unsigned short*)(ws + F_WT);
    float* z = out + 1;

    hipMemsetAsync(ws, 0, (size_t)(16 + 4 * N_NODES) * sizeof(float), stream);

    prep_kernel<<<XB_BLKS + WP_BLKS + CNT_BLKS + EI_BLKS, 256, 0, stream>>>(
        X, xb, W_pos0, W_neg0, W_pos1, W_neg1, wt, pe, ne, ps, ns, target,
        cntP, cntN, eidx);
    scan_p1<<<2 * SBLK, 512, 0, stream>>>(cntP, cntN, part);
    scan_p2<<<1, 512, 0, stream>>>(part);
    scan_p3<<<2 * SBLK, 512, 0, stream>>>(cntP, cntN, part, offP, offN, csrP, csrN);
    fill_kernel<<<(EP_N + EN_N + 255) / 256, 256, 0, stream>>>(pe, ne, offP, offN,
                                                               curP, curN, csrP, csrN);

    base_both<<<NODE_BLOCKS, 512, 0, stream>>>(xb, offP, csrP, offN, csrN, cntP, cntN,
                                               wt, b_pos0, b_neg0, hboth);
    deep_both<<<DEEP_BLOCKS, 512, 0, stream>>>(hboth, offP, csrP, offN, csrN, cntP, cntN,
                                               wt + 16384, b_pos1, b_neg1,
                                               W_reg, z, zq, pnu, pnv);

    loss6_kernel<<<2048, 256, 0, stream>>>(zq, pnu, pnv, eidx, acc);
    finalize_kernel<<<1, 1, 0, stream>>>(acc, out);
}

// Round 14
// 350.378 us; speedup vs baseline: 1.4088x; 1.0076x over previous
//
#include <hip/hip_runtime.h>
#include <cstdint>

#define N_NODES 100000
#define EP_N 400000
#define EN_N 400000
#define NODE_BLOCKS ((N_NODES + 63) / 64)
#define DEEP_BLOCKS (N_NODES / 32)   // 3125, exact
#define SCHUNK 512
#define SBLK ((N_NODES + SCHUNK - 1) / SCHUNK)

#define BSTR 264   // base LDS row: [gP(64) | X(64) | gN(64) | X(64)] + 8 pad (ushorts)
#define DSTR 392   // deep LDS row: [posIn(192) | negIn(192)] + 8 pad (ushorts)

// prep_kernel block ranges
#define XB_BLKS ((((N_NODES + 1) * 16) + 255) / 256)
#define WP_BLKS 112
#define CNT_BLKS (((EP_N + EN_N) + 255) / 256)
#define EI_BLKS CNT_BLKS

// ws layout (in 4-byte units)
#define ACC_OFF 0
#define I_CNTP 16
#define I_CNTN (I_CNTP + N_NODES)
#define I_CURP (I_CNTN + N_NODES)
#define I_CURN (I_CURP + N_NODES)
#define I_OFFP (I_CURN + N_NODES)
#define I_OFFN (I_OFFP + N_NODES + 1)
#define I_CSRP (((I_OFFN + N_NODES + 1) + 3) & ~3)
#define CSR_SZ (EP_N + 4 * N_NODES)
#define I_CSRN (I_CSRP + CSR_SZ)
#define I_PART (I_CSRN + CSR_SZ)
#define I_EIDX (((I_PART + 2 * SBLK) + 3) & ~3)      // int4 per edge
#define F_XB (((I_EIDX + 4 * (EP_N + EN_N)) + 15) & ~15)
#define F_HB (F_XB + 32 * (N_NODES + 1))          // hboth: (N+1)*64 u32 (bf16 pairs)
#define F_HQ (F_HB + 64 * (N_NODES + 1))          // hq: (N+1)*32 u32 (fp8 pairs)
#define F_PNU (F_HQ + 32 * (N_NODES + 1))         // pnu: N float4
#define F_PNV (F_PNU + 4 * N_NODES)               // pnv: N float4
#define F_ZQ (F_PNV + 4 * N_NODES)                // zq: N*64 bytes
#define F_WT (((F_ZQ + 16 * N_NODES) + 15) & ~15) // wt: 28672 ushorts

typedef __attribute__((ext_vector_type(8))) short sh8;
typedef __attribute__((ext_vector_type(4))) float f32x4;

__device__ inline float bf2f(unsigned short u) {
    return __uint_as_float((unsigned)u << 16);
}
__device__ inline unsigned short f2bf(float v) {
    unsigned u = __float_as_uint(v);
    return (unsigned short)((u + 0x7FFFu + ((u >> 16) & 1u)) >> 16);
}
__device__ inline float lo_bf(unsigned u) { return __uint_as_float(u << 16); }
__device__ inline float hi_bf(unsigned u) { return __uint_as_float(u & 0xFFFF0000u); }

// 4-value fp8 dot of two packed dwords
__device__ inline float dot4f8(unsigned a, unsigned b) {
    float s = __builtin_amdgcn_cvt_f32_fp8(a, 0) * __builtin_amdgcn_cvt_f32_fp8(b, 0);
    s = fmaf(__builtin_amdgcn_cvt_f32_fp8(a, 1), __builtin_amdgcn_cvt_f32_fp8(b, 1), s);
    s = fmaf(__builtin_amdgcn_cvt_f32_fp8(a, 2), __builtin_amdgcn_cvt_f32_fp8(b, 2), s);
    s = fmaf(__builtin_amdgcn_cvt_f32_fp8(a, 3), __builtin_amdgcn_cvt_f32_fp8(b, 3), s);
    return s;
}

// fused: X->bf16 (+sentinel) | weight transpose->bf16 | degree count | eidx pack
__global__ void prep_kernel(const float* __restrict__ X, unsigned short* __restrict__ xb,
                            const float* __restrict__ W0p, const float* __restrict__ W0n,
                            const float* __restrict__ W1p, const float* __restrict__ W1n,
                            unsigned short* __restrict__ wt,
                            const int* __restrict__ pe, const int* __restrict__ ne,
                            const int* __restrict__ ps, const int* __restrict__ ns,
                            const int* __restrict__ tgt,
                            int* cp, int* cn, int4* __restrict__ eidx) {
    int b = blockIdx.x;
    if (b < XB_BLKS) {
        int i = b * 256 + threadIdx.x;
        if (i < (N_NODES + 1) * 16) {
            ushort4 o = {0, 0, 0, 0};
            if (i < N_NODES * 16) {
                float4 v = ((const float4*)X)[i];
                o.x = f2bf(v.x); o.y = f2bf(v.y); o.z = f2bf(v.z); o.w = f2bf(v.w);
            }
            ((ushort4*)xb)[i] = o;
        }
    } else if (b < XB_BLKS + WP_BLKS) {
        int i = (b - XB_BLKS) * 256 + threadIdx.x;
        if (i < 8192) {
            int n = i >> 7, k = i & 127;
            wt[i] = f2bf(W0p[k * 64 + n]);
        } else if (i < 16384) {
            int j = i - 8192; int n = j >> 7, k = j & 127;
            wt[i] = f2bf(W0n[k * 64 + n]);
        } else if (i < 22528) {
            int j = i - 16384; int n = j / 192, k = j - n * 192;
            wt[i] = f2bf(W1p[k * 32 + n]);
        } else if (i < 28672) {
            int j = i - 22528; int n = j / 192, k = j - n * 192;
            wt[i] = f2bf(W1n[k * 32 + n]);
        }
    } else if (b < XB_BLKS + WP_BLKS + CNT_BLKS) {
        int i = (b - XB_BLKS - WP_BLKS) * 256 + threadIdx.x;
        if (i < EP_N) {
            atomicAdd(&cp[pe[i]], 1);
        } else if (i < EP_N + EN_N) {
            atomicAdd(&cn[ne[i - EP_N]], 1);
        }
    } else {
        int e = (b - XB_BLKS - WP_BLKS - CNT_BLKS) * 256 + threadIdx.x;
        if (e < EP_N) {
            int4 q = {pe[e], pe[EP_N + e], ps[e], tgt[e]};
            eidx[e] = q;
        } else if (e < EP_N + EN_N) {
            int e2 = e - EP_N;
            int4 q = {ne[e2], ne[EN_N + e2], ns[e2], tgt[e]};
            eidx[e] = q;
        }
    }
}

__global__ __launch_bounds__(512) void scan_p1(const int* __restrict__ cntP,
                                               const int* __restrict__ cntN,
                                               int* part) {
    int l = blockIdx.x < SBLK ? 0 : 1;
    int blk = blockIdx.x - l * SBLK;
    const int* cnt = l == 0 ? cntP : cntN;
    int idx = blk * SCHUNK + threadIdx.x;
    int v = idx < N_NODES ? (cnt[idx] + 3) & ~3 : 0;   // padded counts
    __shared__ int tmp[512];
    tmp[threadIdx.x] = v;
    __syncthreads();
    for (int d = 256; d > 0; d >>= 1) {
        if (threadIdx.x < d) tmp[threadIdx.x] += tmp[threadIdx.x + d];
        __syncthreads();
    }
    if (threadIdx.x == 0) part[l * SBLK + blk] = tmp[0];
}

__global__ __launch_bounds__(512) void scan_p2(int* part) {
    int t = threadIdx.x;
    int l = t >> 8, idx = t & 255;
    int v = idx < SBLK ? part[l * SBLK + idx] : 0;
    __shared__ int tmp[512];
    int sb = l << 8;
    tmp[sb + idx] = v;
    __syncthreads();
    for (int d = 1; d < 256; d <<= 1) {
        int x = (idx >= d) ? tmp[sb + idx - d] : 0;
        __syncthreads();
        tmp[sb + idx] += x;
        __syncthreads();
    }
    if (idx < SBLK) part[l * SBLK + idx] = tmp[sb + idx] - v;
}

// padded offsets + sentinel pad fill
__global__ __launch_bounds__(512) void scan_p3(const int* __restrict__ cntP,
                                               const int* __restrict__ cntN,
                                               const int* __restrict__ part,
                                               int* offP, int* offN,
                                               int* csrP, int* csrN) {
    int l = blockIdx.x < SBLK ? 0 : 1;
    int blk = blockIdx.x - l * SBLK;
    const int* cnt = l == 0 ? cntP : cntN;
    int* off = l == 0 ? offP : offN;
    int* csr = l == 0 ? csrP : csrN;
    int base = part[l * SBLK + blk];
    int t = threadIdx.x;
    int gidx = blk * SCHUNK + t;
    int c = gidx < N_NODES ? cnt[gidx] : 0;
    int cpad = (c + 3) & ~3;
    __shared__ int tmp[512];
    tmp[t] = cpad;
    __syncthreads();
    for (int d = 1; d < 512; d <<= 1) {
        int x = (t >= d) ? tmp[t - d] : 0;
        __syncthreads();
        tmp[t] += x;
        __syncthreads();
    }
    int incl = tmp[t];
    if (gidx < N_NODES) {
        int o = base + incl - cpad;
        off[gidx] = o;
        for (int p = c; p < cpad; ++p) csr[o + p] = N_NODES;  // sentinel pads
    }
    if (gidx == N_NODES - 1) off[N_NODES] = base + incl;
}

__global__ void fill_kernel(const int* __restrict__ pe, const int* __restrict__ ne,
                            const int* __restrict__ offP, const int* __restrict__ offN,
                            int* curP, int* curN, int* csrP, int* csrN) {
    int e = blockIdx.x * 256 + threadIdx.x;
    if (e < EP_N) {
        int row = pe[e], col = pe[EP_N + e];
        int slot = atomicAdd(&curP[row], 1);
        csrP[offP[row] + slot] = col;
    } else if (e < EP_N + EN_N) {
        int e2 = e - EP_N;
        int row = ne[e2], col = ne[EN_N + e2];
        int slot = atomicAdd(&curN[row], 1);
        csrN[offN[row] + slot] = col;
    }
}

// split-row joint P/N gather-mean over bf16 rows (4B/lane, 2 rows/load-inst)
// hf = lane>>5 (row parity), l5 = lane&31 (dim pair index)
__device__ inline void gmb2w(const unsigned* __restrict__ xb32,
                             const int* __restrict__ csrP, int pP, int enP, int cP,
                             const int* __restrict__ csrN, int pN, int enN, int cN,
                             int hf, int l5,
                             float& gP0, float& gP1, float& gN0, float& gN1) {
    float a0 = 0.f, a1 = 0.f, b0 = 0.f, b1 = 0.f;
    while (pP < enP && pN < enN) {
        int4 ca = *(const int4*)(csrP + pP);
        int4 cb = *(const int4*)(csrN + pN);
        int cA0 = hf ? ca.y : ca.x;
        int cA1 = hf ? ca.w : ca.z;
        int cB0 = hf ? cb.y : cb.x;
        int cB1 = hf ? cb.w : cb.z;
        unsigned va0 = xb32[cA0 * 32 + l5];
        unsigned va1 = xb32[cA1 * 32 + l5];
        unsigned vb0 = xb32[cB0 * 32 + l5];
        unsigned vb1 = xb32[cB1 * 32 + l5];
        a0 += lo_bf(va0) + lo_bf(va1);
        a1 += hi_bf(va0) + hi_bf(va1);
        b0 += lo_bf(vb0) + lo_bf(vb1);
        b1 += hi_bf(vb0) + hi_bf(vb1);
        pP += 4; pN += 4;
    }
    for (; pP < enP; pP += 4) {
        int4 ca = *(const int4*)(csrP + pP);
        int cA0 = hf ? ca.y : ca.x;
        int cA1 = hf ? ca.w : ca.z;
        unsigned va0 = xb32[cA0 * 32 + l5];
        unsigned va1 = xb32[cA1 * 32 + l5];
        a0 += lo_bf(va0) + lo_bf(va1);
        a1 += hi_bf(va0) + hi_bf(va1);
    }
    for (; pN < enN; pN += 4) {
        int4 cb = *(const int4*)(csrN + pN);
        int cB0 = hf ? cb.y : cb.x;
        int cB1 = hf ? cb.w : cb.z;
        unsigned vb0 = xb32[cB0 * 32 + l5];
        unsigned vb1 = xb32[cB1 * 32 + l5];
        b0 += lo_bf(vb0) + lo_bf(vb1);
        b1 += hi_bf(vb0) + hi_bf(vb1);
    }
    a0 += __shfl_xor(a0, 32); a1 += __shfl_xor(a1, 32);
    b0 += __shfl_xor(b0, 32); b1 += __shfl_xor(b1, 32);
    float rP = 1.f / fmaxf((float)cP, 1.f), rN = 1.f / fmaxf((float)cN, 1.f);
    gP0 = a0 * rP; gP1 = a1 * rP;
    gN0 = b0 * rN; gN1 = b1 * rN;
}

// split-row joint P/N gather-mean of fp8 {hp,hn} pair rows (4B/lane, 2 rows/load)
// u32 = bytes {fp8 hp_{2l5}, fp8 hn_{2l5}, fp8 hp_{2l5+1}, fp8 hn_{2l5+1}}
__device__ inline void gd2q(const unsigned* __restrict__ hq32,
                            const int* __restrict__ csrP, int pP, int enP, int cP,
                            const int* __restrict__ csrN, int pN, int enN, int cN,
                            int hf, int l5,
                            float& gPp0, float& gPp1, float& gPn0, float& gPn1,
                            float& gNp0, float& gNp1, float& gNn0, float& gNn1) {
    float ap0 = 0.f, ap1 = 0.f, an0 = 0.f, an1 = 0.f;
    float bp0 = 0.f, bp1 = 0.f, bn0 = 0.f, bn1 = 0.f;
    while (pP < enP && pN < enN) {
        int4 ca = *(const int4*)(csrP + pP);
        int4 cb = *(const int4*)(csrN + pN);
        int cA0 = hf ? ca.y : ca.x;
        int cA1 = hf ? ca.w : ca.z;
        int cB0 = hf ? cb.y : cb.x;
        int cB1 = hf ? cb.w : cb.z;
        unsigned va0 = hq32[cA0 * 32 + l5];
        unsigned va1 = hq32[cA1 * 32 + l5];
        unsigned vb0 = hq32[cB0 * 32 + l5];
        unsigned vb1 = hq32[cB1 * 32 + l5];
        ap0 += __builtin_amdgcn_cvt_f32_fp8(va0, 0) + __builtin_amdgcn_cvt_f32_fp8(va1, 0);
        an0 += __builtin_amdgcn_cvt_f32_fp8(va0, 1) + __builtin_amdgcn_cvt_f32_fp8(va1, 1);
        ap1 += __builtin_amdgcn_cvt_f32_fp8(va0, 2) + __builtin_amdgcn_cvt_f32_fp8(va1, 2);
        an1 += __builtin_amdgcn_cvt_f32_fp8(va0, 3) + __builtin_amdgcn_cvt_f32_fp8(va1, 3);
        bp0 += __builtin_amdgcn_cvt_f32_fp8(vb0, 0) + __builtin_amdgcn_cvt_f32_fp8(vb1, 0);
        bn0 += __builtin_amdgcn_cvt_f32_fp8(vb0, 1) + __builtin_amdgcn_cvt_f32_fp8(vb1, 1);
        bp1 += __builtin_amdgcn_cvt_f32_fp8(vb0, 2) + __builtin_amdgcn_cvt_f32_fp8(vb1, 2);
        bn1 += __builtin_amdgcn_cvt_f32_fp8(vb0, 3) + __builtin_amdgcn_cvt_f32_fp8(vb1, 3);
        pP += 4; pN += 4;
    }
    for (; pP < enP; pP += 4) {
        int4 ca = *(const int4*)(csrP + pP);
        int cA0 = hf ? ca.y : ca.x;
        int cA1 = hf ? ca.w : ca.z;
        unsigned va0 = hq32[cA0 * 32 + l5];
        unsigned va1 = hq32[cA1 * 32 + l5];
        ap0 += __builtin_amdgcn_cvt_f32_fp8(va0, 0) + __builtin_amdgcn_cvt_f32_fp8(va1, 0);
        an0 += __builtin_amdgcn_cvt_f32_fp8(va0, 1) + __builtin_amdgcn_cvt_f32_fp8(va1, 1);
        ap1 += __builtin_amdgcn_cvt_f32_fp8(va0, 2) + __builtin_amdgcn_cvt_f32_fp8(va1, 2);
        an1 += __builtin_amdgcn_cvt_f32_fp8(va0, 3) + __builtin_amdgcn_cvt_f32_fp8(va1, 3);
    }
    for (; pN < enN; pN += 4) {
        int4 cb = *(const int4*)(csrN + pN);
        int cB0 = hf ? cb.y : cb.x;
        int cB1 = hf ? cb.w : cb.z;
        unsigned vb0 = hq32[cB0 * 32 + l5];
        unsigned vb1 = hq32[cB1 * 32 + l5];
        bp0 += __builtin_amdgcn_cvt_f32_fp8(vb0, 0) + __builtin_amdgcn_cvt_f32_fp8(vb1, 0);
        bn0 += __builtin_amdgcn_cvt_f32_fp8(vb0, 1) + __builtin_amdgcn_cvt_f32_fp8(vb1, 1);
        bp1 += __builtin_amdgcn_cvt_f32_fp8(vb0, 2) + __builtin_amdgcn_cvt_f32_fp8(vb1, 2);
        bn1 += __builtin_amdgcn_cvt_f32_fp8(vb0, 3) + __builtin_amdgcn_cvt_f32_fp8(vb1, 3);
    }
    ap0 += __shfl_xor(ap0, 32); ap1 += __shfl_xor(ap1, 32);
    an0 += __shfl_xor(an0, 32); an1 += __shfl_xor(an1, 32);
    bp0 += __shfl_xor(bp0, 32); bp1 += __shfl_xor(bp1, 32);
    bn0 += __shfl_xor(bn0, 32); bn1 += __shfl_xor(bn1, 32);
    float rP = 1.f / fmaxf((float)cP, 1.f), rN = 1.f / fmaxf((float)cN, 1.f);
    gPp0 = ap0 * rP; gPp1 = ap1 * rP; gPn0 = an0 * rP; gPn1 = an1 * rP;
    gNp0 = bp0 * rN; gNp1 = bp1 * rN; gNn0 = bn0 * rN; gNn1 = bn1 * rN;
}

// both base layers: split-row gather -> MFMA GEMM -> tanh -> bf16 h + fp8 hq
__global__ __launch_bounds__(512) void base_both(
    const unsigned short* __restrict__ xb,
    const int* __restrict__ offP, const int* __restrict__ csrP,
    const int* __restrict__ offN, const int* __restrict__ csrN,
    const int* __restrict__ cntP, const int* __restrict__ cntN,
    const unsigned short* __restrict__ wt0,
    const float* __restrict__ bp0, const float* __restrict__ bn0,
    unsigned short* __restrict__ hboth, unsigned* __restrict__ hq32) {
    __shared__ unsigned short lds[64 * BSTR];
    int tid = threadIdx.x, lane = tid & 63, w = tid >> 6;
    int hf = lane >> 5, l5 = lane & 31;
    int base = blockIdx.x * 64;
    const unsigned* xb32 = (const unsigned*)xb;
    // zero sentinel rows (once, before deep_both runs)
    if (blockIdx.x == 0 && tid < 64) ((unsigned*)hboth)[N_NODES * 64 + tid] = 0u;
    if (blockIdx.x == 0 && tid < 32) hq32[N_NODES * 32 + tid] = 0u;
    for (int r = w * 8; r < w * 8 + 8; ++r) {
        int node = base + r;
        float gP0 = 0.f, gP1 = 0.f, gN0 = 0.f, gN1 = 0.f;
        unsigned sxv = 0;
        if (node < N_NODES) {
            gmb2w(xb32, csrP, offP[node], offP[node + 1], cntP[node],
                  csrN, offN[node], offN[node + 1], cntN[node], hf, l5,
                  gP0, gP1, gN0, gN1);
            sxv = xb32[node * 32 + l5];
        }
        unsigned* rp32 = (unsigned*)&lds[r * BSTR];
        if (hf == 0) {
            rp32[l5] = (unsigned)f2bf(gP0) | ((unsigned)f2bf(gP1) << 16);
            rp32[32 + l5] = sxv;
        } else {
            rp32[64 + l5] = (unsigned)f2bf(gN0) | ((unsigned)f2bf(gN1) << 16);
            rp32[96 + l5] = sxv;
        }
    }
    __syncthreads();
    int wu = __builtin_amdgcn_readfirstlane(w);
    int mt = wu >> 1, half = wu & 1;
    int l15 = lane & 15, kq = lane >> 4;
    const unsigned short* wbase = wt0 + half * 8192;
    f32x4 acc[4];
#pragma unroll
    for (int nt = 0; nt < 4; ++nt) acc[nt] = (f32x4){0.f, 0.f, 0.f, 0.f};
    const unsigned short* arow = &lds[(mt * 16 + l15) * BSTR + half * 128 + kq * 8];
#pragma unroll
    for (int ks = 0; ks < 4; ++ks) {
        sh8 a = *(const sh8*)(arow + ks * 32);
#pragma unroll
        for (int nt = 0; nt < 4; ++nt) {
            sh8 bf = *(const sh8*)(wbase + (nt * 16 + l15) * 128 + ks * 32 + kq * 8);
            acc[nt] = __builtin_amdgcn_mfma_f32_16x16x32_bf16(a, bf, acc[nt], 0, 0, 0);
        }
    }
    __syncthreads();
    float* ht = (float*)lds;  // [64][130]
    const float* bias = half ? bn0 : bp0;
#pragma unroll
    for (int nt = 0; nt < 4; ++nt) {
        int col = nt * 16 + l15;
        float bb = bias[col];
#pragma unroll
        for (int r = 0; r < 4; ++r) {
            int row = mt * 16 + kq * 4 + r;
            ht[row * 130 + half * 64 + col] = tanhf(acc[nt][r] + bb);
        }
    }
    __syncthreads();
    unsigned* hb32 = (unsigned*)hboth;
    for (int i = tid; i < 64 * 64; i += 512) {
        int rr = i >> 6, c = i & 63;
        int node = base + rr;
        if (node < N_NODES) {
            unsigned lo = f2bf(ht[rr * 130 + c]);
            unsigned hi = f2bf(ht[rr * 130 + 64 + c]);
            hb32[node * 64 + c] = lo | (hi << 16);
        }
    }
    for (int i = tid; i < 64 * 32; i += 512) {
        int rr = i >> 5, c2 = i & 31;
        int node = base + rr;
        if (node < N_NODES) {
            float hp0 = ht[rr * 130 + 2 * c2];
            float hn0 = ht[rr * 130 + 64 + 2 * c2];
            float hp1 = ht[rr * 130 + 2 * c2 + 1];
            float hn1 = ht[rr * 130 + 64 + 2 * c2 + 1];
            int lo = __builtin_amdgcn_cvt_pk_fp8_f32(hp0, hn0, 0, false);
            int q = __builtin_amdgcn_cvt_pk_fp8_f32(hp1, hn1, lo, true);
            hq32[node * 32 + c2] = (unsigned)q;
        }
    }
}

// both deep layers: 32-node blocks, fp8 split-row gather -> MFMA -> tanh -> epilogue
__global__ __launch_bounds__(512) void deep_both(
    const unsigned short* __restrict__ hb, const unsigned* __restrict__ hq32,
    const int* __restrict__ offP, const int* __restrict__ csrP,
    const int* __restrict__ offN, const int* __restrict__ csrN,
    const int* __restrict__ cntP, const int* __restrict__ cntN,
    const unsigned short* __restrict__ wt1,
    const float* __restrict__ bp1, const float* __restrict__ bn1,
    const float* __restrict__ Wreg, float* __restrict__ z,
    unsigned char* __restrict__ zq, float4* __restrict__ pnu,
    float4* __restrict__ pnv) {
    __shared__ unsigned short lds[32 * DSTR];   // 25088 B
    int tid = threadIdx.x, lane = tid & 63, w = tid >> 6;
    int hf = lane >> 5, l5 = lane & 31;
    int base = blockIdx.x * 32;                 // grid exact: 3125*32 = 100000
    const unsigned* hb32 = (const unsigned*)hb;
    for (int r = w * 4; r < w * 4 + 4; ++r) {
        int node = base + r;
        float gPp0, gPp1, gPn0, gPn1, gNp0, gNp1, gNn0, gNn1;
        gd2q(hq32, csrP, offP[node], offP[node + 1], cntP[node],
             csrN, offN[node], offN[node + 1], cntN[node], hf, l5,
             gPp0, gPp1, gPn0, gPn1, gNp0, gNp1, gNn0, gNn1);
        uint2 sv = *(const uint2*)(hb32 + node * 64 + l5 * 2);
        unsigned* rp32 = (unsigned*)&lds[r * DSTR];
        if (hf == 0) {
            rp32[l5] = (unsigned)f2bf(gPp0) | ((unsigned)f2bf(gPp1) << 16);
            rp32[32 + l5] = (unsigned)f2bf(gNn0) | ((unsigned)f2bf(gNn1) << 16);
            rp32[64 + l5] = (sv.x & 0xFFFFu) | ((sv.y & 0xFFFFu) << 16);  // hp pair
        } else {
            rp32[96 + l5] = (unsigned)f2bf(gPn0) | ((unsigned)f2bf(gPn1) << 16);
            rp32[128 + l5] = (unsigned)f2bf(gNp0) | ((unsigned)f2bf(gNp1) << 16);
            rp32[160 + l5] = (sv.x >> 16) | (sv.y & 0xFFFF0000u);         // hn pair
        }
    }
    __syncthreads();
    int wu = __builtin_amdgcn_readfirstlane(w);
    int mt = wu >> 2, half = (wu >> 1) & 1, nt = wu & 1;
    int l15 = lane & 15, kq = lane >> 4;
    const unsigned short* wbase = wt1 + half * 6144;
    f32x4 acc = (f32x4){0.f, 0.f, 0.f, 0.f};
    const unsigned short* arow = &lds[(mt * 16 + l15) * DSTR + half * 192 + kq * 8];
#pragma unroll
    for (int ks = 0; ks < 6; ++ks) {
        sh8 a = *(const sh8*)(arow + ks * 32);
        sh8 bf = *(const sh8*)(wbase + (nt * 16 + l15) * 192 + ks * 32 + kq * 8);
        acc = __builtin_amdgcn_mfma_f32_16x16x32_bf16(a, bf, acc, 0, 0, 0);
    }
    __syncthreads();
    float* ot = (float*)lds;  // [32][65]
    {
        const float* bias = half ? bn1 : bp1;
        int col = nt * 16 + l15;
        float bb = bias[col];
#pragma unroll
        for (int r = 0; r < 4; ++r) {
            int row = mt * 16 + kq * 4 + r;
            ot[row * 65 + half * 32 + col] = tanhf(acc[r] + bb);
        }
    }
    __syncthreads();
    for (int r = w * 4; r < w * 4 + 4; ++r) {
        int node = base + r;
        float v = ot[r * 65 + lane];
        z[node * 64 + lane] = v;
        int pq = __builtin_amdgcn_cvt_pk_fp8_f32(v, v, 0, false);
        zq[node * 64 + lane] = (unsigned char)(pq & 0xFF);
        float vq = __builtin_amdgcn_cvt_f32_fp8(pq, 0);
        float u0 = vq * Wreg[lane * 2 + 0];
        float u1 = vq * Wreg[lane * 2 + 1];
        float v0 = vq * Wreg[128 + lane * 2 + 0];
        float v1 = vq * Wreg[128 + lane * 2 + 1];
        float s = vq * vq;
#pragma unroll
        for (int off = 32; off; off >>= 1) {
            u0 += __shfl_xor(u0, off);
            u1 += __shfl_xor(u1, off);
            v0 += __shfl_xor(v0, off);
            v1 += __shfl_xor(v1, off);
            s += __shfl_xor(s, off);
        }
        if (lane == 0) {
            float4 su = {u0, u1, s, 0.f};
            float4 sv2 = {v0, v1, s, 0.f};
            pnu[node] = su;
            pnv[node] = sv2;
        }
    }
}

// 4-lane edge groups, 16B/lane rows, two batches of 16 edges per iter
__global__ __launch_bounds__(256) void loss6_kernel(
    const unsigned char* __restrict__ zq, const float4* __restrict__ pnu,
    const float4* __restrict__ pnv, const int4* __restrict__ eidx, float* acc) {
    int tid = threadIdx.x;
    int lane = tid & 63;
    int g = lane >> 2, sub = lane & 3;   // 16 groups of 4 lanes
    int wid = (blockIdx.x * 256 + tid) >> 6;
    int nw = (gridDim.x * 256) >> 6;
    float s_p = 0.f, s_n = 0.f, s_r = 0.f;
    const float q = 0.25f;               // each edge duplicated in 4 lanes
    for (int eb = wid * 32; eb < EP_N + EN_N; eb += nw * 32) {
        int eA = eb + g, eB = eb + 16 + g;
        bool vA = eA < EP_N + EN_N, vB = eB < EP_N + EN_N;
        bool pA = eA < EP_N, pB = eB < EP_N;
        int4 qA = eidx[vA ? eA : 0];
        int4 qB = eidx[vB ? eB : 0];
        uint4 ziA = *(const uint4*)(zq + ((long long)qA.x << 6) + (sub << 4));
        uint4 zjA = *(const uint4*)(zq + ((long long)qA.y << 6) + (sub << 4));
        uint4 zkA = *(const uint4*)(zq + ((long long)qA.z << 6) + (sub << 4));
        uint4 ziB = *(const uint4*)(zq + ((long long)qB.x << 6) + (sub << 4));
        uint4 zjB = *(const uint4*)(zq + ((long long)qB.y << 6) + (sub << 4));
        uint4 zkB = *(const uint4*)(zq + ((long long)qB.z << 6) + (sub << 4));
        float4 uA = pnu[qA.x];
        float4 wA = pnv[qA.y];
        float skA = pnu[qA.z].z;
        float4 uB = pnu[qB.x];
        float4 wB = pnv[qB.y];
        float skB = pnu[qB.z].z;
        float d1A = dot4f8(ziA.x, zjA.x) + dot4f8(ziA.y, zjA.y) +
                    dot4f8(ziA.z, zjA.z) + dot4f8(ziA.w, zjA.w);
        float d2A = dot4f8(zjA.x, zkA.x) + dot4f8(zjA.y, zkA.y) +
                    dot4f8(zjA.z, zkA.z) + dot4f8(zjA.w, zkA.w);
        float d1B = dot4f8(ziB.x, zjB.x) + dot4f8(ziB.y, zjB.y) +
                    dot4f8(ziB.z, zjB.z) + dot4f8(ziB.w, zjB.w);
        float d2B = dot4f8(zjB.x, zkB.x) + dot4f8(zjB.y, zkB.y) +
                    dot4f8(zjB.z, zkB.z) + dot4f8(zjB.w, zkB.w);
#pragma unroll
        for (int off = 1; off < 4; off <<= 1) {
            d1A += __shfl_xor(d1A, off);
            d2A += __shfl_xor(d2A, off);
            d1B += __shfl_xor(d1B, off);
            d2B += __shfl_xor(d2B, off);
        }
        if (vA) {
            float nij = uA.z + wA.z - 2.f * d1A;
            float nik = wA.z + skA - 2.f * d2A;
            float tri = fmaxf(nij - nik, 0.f);
            float l0 = uA.x + wA.x, l1 = uA.y + wA.y;
            float m = fmaxf(l0, l1);
            float lse = m + logf(expf(l0 - m) + expf(l1 - m));
            s_r += (lse - (qA.w ? l1 : l0)) * q;
            if (pA) s_p += tri * q; else s_n += tri * q;
        }
        if (vB) {
            float nij = uB.z + wB.z - 2.f * d1B;
            float nik = wB.z + skB - 2.f * d2B;
            float tri = fmaxf(nij - nik, 0.f);
            float l0 = uB.x + wB.x, l1 = uB.y + wB.y;
            float m = fmaxf(l0, l1);
            float lse = m + logf(expf(l0 - m) + expf(l1 - m));
            s_r += (lse - (qB.w ? l1 : l0)) * q;
            if (pB) s_p += tri * q; else s_n += tri * q;
        }
    }
#pragma unroll
    for (int off = 32; off; off >>= 1) {
        s_p += __shfl_xor(s_p, off);
        s_n += __shfl_xor(s_n, off);
        s_r += __shfl_xor(s_r, off);
    }
    __shared__ float red[3][4];
    int w = tid >> 6;
    if (lane == 0) {
        red[0][w] = s_p; red[1][w] = s_n; red[2][w] = s_r;
    }
    __syncthreads();
    if (tid == 0) {
        atomicAdd(&acc[0], red[0][0] + red[0][1] + red[0][2] + red[0][3]);
        atomicAdd(&acc[1], red[1][0] + red[1][1] + red[1][2] + red[1][3]);
        atomicAdd(&acc[2], red[2][0] + red[2][1] + red[2][2] + red[2][3]);
    }
}

__global__ void finalize_kernel(const float* __restrict__ acc, float* out) {
    out[0] = acc[2] / (float)(EP_N + EN_N) +
             1.0f * (acc[0] / (float)EP_N + acc[1] / (float)EN_N);
}

extern "C" void kernel_launch(void* const* d_in, const int* in_sizes, int n_in,
                              void* d_out, int out_size, void* d_ws, size_t ws_size,
                              hipStream_t stream) {
    const float* X = (const float*)d_in[0];
    const float* W_pos0 = (const float*)d_in[1];
    const float* b_pos0 = (const float*)d_in[2];
    const float* W_neg0 = (const float*)d_in[3];
    const float* b_neg0 = (const float*)d_in[4];
    const float* W_pos1 = (const float*)d_in[5];
    const float* b_pos1 = (const float*)d_in[6];
    const float* W_neg1 = (const float*)d_in[7];
    const float* b_neg1 = (const float*)d_in[8];
    const float* W_reg = (const float*)d_in[9];
    const int* pe = (const int*)d_in[10];
    const int* ne = (const int*)d_in[11];
    const int* target = (const int*)d_in[12];
    const int* ps = (const int*)d_in[13];
    const int* ns = (const int*)d_in[14];
    float* out = (float*)d_out;
    float* ws = (float*)d_ws;
    int* wsi = (int*)d_ws;

    float* acc = ws + ACC_OFF;
    int* cntP = wsi + I_CNTP;
    int* cntN = wsi + I_CNTN;
    int* curP = wsi + I_CURP;
    int* curN = wsi + I_CURN;
    int* offP = wsi + I_OFFP;
    int* offN = wsi + I_OFFN;
    int* csrP = wsi + I_CSRP;
    int* csrN = wsi + I_CSRN;
    int* part = wsi + I_PART;
    int4* eidx = (int4*)(wsi + I_EIDX);
    unsigned short* xb = (unsigned short*)(ws + F_XB);
    unsigned short* hboth = (unsigned short*)(ws + F_HB);
    unsigned* hq32 = (unsigned*)(ws + F_HQ);
    float4* pnu = (float4*)(ws + F_PNU);
    float4* pnv = (float4*)(ws + F_PNV);
    unsigned char* zq = (unsigned char*)(ws + F_ZQ);
    unsigned short* wt = (unsigned short*)(ws + F_WT);
    float* z = out + 1;

    hipMemsetAsync(ws, 0, (size_t)(16 + 4 * N_NODES) * sizeof(float), stream);

    prep_kernel<<<XB_BLKS + WP_BLKS + CNT_BLKS + EI_BLKS, 256, 0, stream>>>(
        X, xb, W_pos0, W_neg0, W_pos1, W_neg1, wt, pe, ne, ps, ns, target,
        cntP, cntN, eidx);
    scan_p1<<<2 * SBLK, 512, 0, stream>>>(cntP, cntN, part);
    scan_p2<<<1, 512, 0, stream>>>(part);
    scan_p3<<<2 * SBLK, 512, 0, stream>>>(cntP, cntN, part, offP, offN, csrP, csrN);
    fill_kernel<<<(EP_N + EN_N + 255) / 256, 256, 0, stream>>>(pe, ne, offP, offN,
                                                               curP, curN, csrP, csrN);

    base_both<<<NODE_BLOCKS, 512, 0, stream>>>(xb, offP, csrP, offN, csrN, cntP, cntN,
                                               wt, b_pos0, b_neg0, hboth, hq32);
    deep_both<<<DEEP_BLOCKS, 512, 0, stream>>>(hboth, hq32, offP, csrP, offN, csrN,
                                               cntP, cntN, wt + 16384, b_pos1, b_neg1,
                                               W_reg, z, zq, pnu, pnv);

    loss6_kernel<<<2048, 256, 0, stream>>>(zq, pnu, pnv, eidx, acc);
    finalize_kernel<<<1, 1, 0, stream>>>(acc, out);
}

// Round 15
// 347.874 us; speedup vs baseline: 1.4190x; 1.0072x over previous
//
#include <hip/hip_runtime.h>
#include <cstdint>

#define N_NODES 100000
#define EP_N 400000
#define EN_N 400000
#define NODE_BLOCKS ((N_NODES + 63) / 64)
#define DEEP_BLOCKS (N_NODES / 32)   // 3125, exact
#define SCHUNK 512
#define SBLK ((N_NODES + SCHUNK - 1) / SCHUNK)

#define BSTR 264   // base LDS row (ushorts)
#define DSTR 392   // deep LDS row (ushorts)

// prep_kernel block ranges
#define XB_BLKS ((((N_NODES + 1) * 16) + 255) / 256)
#define WP_BLKS 112
#define CNT_BLKS (((EP_N + EN_N) + 255) / 256)

// ws layout (in 4-byte units)
#define ACC_OFF 0
#define I_CNTP 16
#define I_CNTN (I_CNTP + N_NODES)
#define I_CURP (I_CNTN + N_NODES)
#define I_CURN (I_CURP + N_NODES)
#define I_OFFP (I_CURN + N_NODES)
#define I_OFFN (I_OFFP + N_NODES + 1)
#define I_OFFPC (I_OFFN + N_NODES + 1)
#define I_OFFNC (I_OFFPC + N_NODES + 1)
#define I_CSRP (((I_OFFNC + N_NODES + 1) + 3) & ~3)
#define CSR_SZ (EP_N + 4 * N_NODES)
#define I_CSRN (I_CSRP + CSR_SZ)
#define I_PART (I_CSRN + CSR_SZ)            // 4*SBLK ints
#define I_EIDX (((I_PART + 4 * SBLK) + 3) & ~3)      // int4 per edge
#define F_XB (((I_EIDX + 4 * (EP_N + EN_N)) + 15) & ~15)
#define F_HB (F_XB + 32 * (N_NODES + 1))          // hboth: (N+1)*64 u32 (bf16 pairs)
#define F_HQ (F_HB + 64 * (N_NODES + 1))          // hq: (N+1)*32 u32 (fp8 pairs)
#define F_PNU (F_HQ + 32 * (N_NODES + 1))         // pnu: N float4
#define F_PNV (F_PNU + 4 * N_NODES)               // pnv: N float4
#define F_ZQ (F_PNV + 4 * N_NODES)                // zq: N*64 bytes
#define F_WT (((F_ZQ + 16 * N_NODES) + 15) & ~15) // wt: 28672 ushorts

typedef __attribute__((ext_vector_type(8))) short sh8;
typedef __attribute__((ext_vector_type(4))) float f32x4;

__device__ inline float bf2f(unsigned short u) {
    return __uint_as_float((unsigned)u << 16);
}
__device__ inline unsigned short f2bf(float v) {
    unsigned u = __float_as_uint(v);
    return (unsigned short)((u + 0x7FFFu + ((u >> 16) & 1u)) >> 16);
}
__device__ inline float lo_bf(unsigned u) { return __uint_as_float(u << 16); }
__device__ inline float hi_bf(unsigned u) { return __uint_as_float(u & 0xFFFF0000u); }

// 4-value fp8 dot of two packed dwords
__device__ inline float dot4f8(unsigned a, unsigned b) {
    float s = __builtin_amdgcn_cvt_f32_fp8(a, 0) * __builtin_amdgcn_cvt_f32_fp8(b, 0);
    s = fmaf(__builtin_amdgcn_cvt_f32_fp8(a, 1), __builtin_amdgcn_cvt_f32_fp8(b, 1), s);
    s = fmaf(__builtin_amdgcn_cvt_f32_fp8(a, 2), __builtin_amdgcn_cvt_f32_fp8(b, 2), s);
    s = fmaf(__builtin_amdgcn_cvt_f32_fp8(a, 3), __builtin_amdgcn_cvt_f32_fp8(b, 3), s);
    return s;
}

// fused: X->bf16 (+sentinel) | weight transpose->bf16 | degree count
__global__ void prep_kernel(const float* __restrict__ X, unsigned short* __restrict__ xb,
                            const float* __restrict__ W0p, const float* __restrict__ W0n,
                            const float* __restrict__ W1p, const float* __restrict__ W1n,
                            unsigned short* __restrict__ wt,
                            const int* __restrict__ pe, const int* __restrict__ ne,
                            int* cp, int* cn) {
    int b = blockIdx.x;
    if (b < XB_BLKS) {
        int i = b * 256 + threadIdx.x;
        if (i < (N_NODES + 1) * 16) {
            ushort4 o = {0, 0, 0, 0};
            if (i < N_NODES * 16) {
                float4 v = ((const float4*)X)[i];
                o.x = f2bf(v.x); o.y = f2bf(v.y); o.z = f2bf(v.z); o.w = f2bf(v.w);
            }
            ((ushort4*)xb)[i] = o;
        }
    } else if (b < XB_BLKS + WP_BLKS) {
        int i = (b - XB_BLKS) * 256 + threadIdx.x;
        if (i < 8192) {
            int n = i >> 7, k = i & 127;
            wt[i] = f2bf(W0p[k * 64 + n]);
        } else if (i < 16384) {
            int j = i - 8192; int n = j >> 7, k = j & 127;
            wt[i] = f2bf(W0n[k * 64 + n]);
        } else if (i < 22528) {
            int j = i - 16384; int n = j / 192, k = j - n * 192;
            wt[i] = f2bf(W1p[k * 32 + n]);
        } else if (i < 28672) {
            int j = i - 22528; int n = j / 192, k = j - n * 192;
            wt[i] = f2bf(W1n[k * 32 + n]);
        }
    } else {
        int i = (b - XB_BLKS - WP_BLKS) * 256 + threadIdx.x;
        if (i < EP_N) {
            atomicAdd(&cp[pe[i]], 1);
        } else if (i < EP_N + EN_N) {
            atomicAdd(&cn[ne[i - EP_N]], 1);
        }
    }
}

// per-block sums of padded AND raw counts
__global__ __launch_bounds__(512) void scan_p1(const int* __restrict__ cntP,
                                               const int* __restrict__ cntN,
                                               int* part) {
    int l = blockIdx.x < SBLK ? 0 : 1;
    int blk = blockIdx.x - l * SBLK;
    const int* cnt = l == 0 ? cntP : cntN;
    int idx = blk * SCHUNK + threadIdx.x;
    int c = idx < N_NODES ? cnt[idx] : 0;
    int vp = (c + 3) & ~3;
    __shared__ int tmp[512];
    __shared__ int tmp2[512];
    tmp[threadIdx.x] = vp;
    tmp2[threadIdx.x] = c;
    __syncthreads();
    for (int d = 256; d > 0; d >>= 1) {
        if (threadIdx.x < d) {
            tmp[threadIdx.x] += tmp[threadIdx.x + d];
            tmp2[threadIdx.x] += tmp2[threadIdx.x + d];
        }
        __syncthreads();
    }
    if (threadIdx.x == 0) {
        part[l * SBLK + blk] = tmp[0];
        part[(2 + l) * SBLK + blk] = tmp2[0];
    }
}

// one block scans 4 partial arrays (exclusive), 256-wide segments
__global__ __launch_bounds__(1024) void scan_p2(int* part) {
    int t = threadIdx.x;
    int l = t >> 8, idx = t & 255;
    int v = idx < SBLK ? part[l * SBLK + idx] : 0;
    __shared__ int tmp[1024];
    int sb = l << 8;
    tmp[sb + idx] = v;
    __syncthreads();
    for (int d = 1; d < 256; d <<= 1) {
        int x = (idx >= d) ? tmp[sb + idx - d] : 0;
        __syncthreads();
        tmp[sb + idx] += x;
        __syncthreads();
    }
    if (idx < SBLK) part[l * SBLK + idx] = tmp[sb + idx] - v;
}

// padded offsets + sentinel pad fill + compact offsets
__global__ __launch_bounds__(512) void scan_p3(const int* __restrict__ cntP,
                                               const int* __restrict__ cntN,
                                               const int* __restrict__ part,
                                               int* offP, int* offN,
                                               int* offPc, int* offNc,
                                               int* csrP, int* csrN) {
    int l = blockIdx.x < SBLK ? 0 : 1;
    int blk = blockIdx.x - l * SBLK;
    const int* cnt = l == 0 ? cntP : cntN;
    int* off = l == 0 ? offP : offN;
    int* offc = l == 0 ? offPc : offNc;
    int* csr = l == 0 ? csrP : csrN;
    int base = part[l * SBLK + blk];
    int basec = part[(2 + l) * SBLK + blk];
    int t = threadIdx.x;
    int gidx = blk * SCHUNK + t;
    int c = gidx < N_NODES ? cnt[gidx] : 0;
    int cpad = (c + 3) & ~3;
    __shared__ int tmp[512];
    __shared__ int tmp2[512];
    tmp[t] = cpad;
    tmp2[t] = c;
    __syncthreads();
    for (int d = 1; d < 512; d <<= 1) {
        int x = (t >= d) ? tmp[t - d] : 0;
        int x2 = (t >= d) ? tmp2[t - d] : 0;
        __syncthreads();
        tmp[t] += x;
        tmp2[t] += x2;
        __syncthreads();
    }
    int incl = tmp[t], inclc = tmp2[t];
    if (gidx < N_NODES) {
        int o = base + incl - cpad;
        off[gidx] = o;
        offc[gidx] = basec + inclc - c;
        for (int p = c; p < cpad; ++p) csr[o + p] = N_NODES;  // sentinel pads
    }
    if (gidx == N_NODES - 1) {
        off[N_NODES] = base + incl;
        offc[N_NODES] = basec + inclc;
    }
}

// CSR fill + row-sorted eidx pack (sorted by source node within each half)
__global__ void fill_kernel(const int* __restrict__ pe, const int* __restrict__ ne,
                            const int* __restrict__ offP, const int* __restrict__ offN,
                            const int* __restrict__ offPc, const int* __restrict__ offNc,
                            const int* __restrict__ ps, const int* __restrict__ ns,
                            const int* __restrict__ tgt,
                            int* curP, int* curN, int* csrP, int* csrN,
                            int4* __restrict__ eidx) {
    int e = blockIdx.x * 256 + threadIdx.x;
    if (e < EP_N) {
        int row = pe[e], col = pe[EP_N + e];
        int slot = atomicAdd(&curP[row], 1);
        csrP[offP[row] + slot] = col;
        int4 q = {row, col, ps[e], tgt[e]};
        eidx[offPc[row] + slot] = q;
    } else if (e < EP_N + EN_N) {
        int e2 = e - EP_N;
        int row = ne[e2], col = ne[EN_N + e2];
        int slot = atomicAdd(&curN[row], 1);
        csrN[offN[row] + slot] = col;
        int4 q = {row, col, ns[e2], tgt[e]};
        eidx[EP_N + offNc[row] + slot] = q;
    }
}

// split-row joint P/N gather-mean over bf16 rows (4B/lane, 2 rows/load-inst)
__device__ inline void gmb2w(const unsigned* __restrict__ xb32,
                             const int* __restrict__ csrP, int pP, int enP, int cP,
                             const int* __restrict__ csrN, int pN, int enN, int cN,
                             int hf, int l5,
                             float& gP0, float& gP1, float& gN0, float& gN1) {
    float a0 = 0.f, a1 = 0.f, b0 = 0.f, b1 = 0.f;
    while (pP < enP && pN < enN) {
        int4 ca = *(const int4*)(csrP + pP);
        int4 cb = *(const int4*)(csrN + pN);
        int cA0 = hf ? ca.y : ca.x;
        int cA1 = hf ? ca.w : ca.z;
        int cB0 = hf ? cb.y : cb.x;
        int cB1 = hf ? cb.w : cb.z;
        unsigned va0 = xb32[cA0 * 32 + l5];
        unsigned va1 = xb32[cA1 * 32 + l5];
        unsigned vb0 = xb32[cB0 * 32 + l5];
        unsigned vb1 = xb32[cB1 * 32 + l5];
        a0 += lo_bf(va0) + lo_bf(va1);
        a1 += hi_bf(va0) + hi_bf(va1);
        b0 += lo_bf(vb0) + lo_bf(vb1);
        b1 += hi_bf(vb0) + hi_bf(vb1);
        pP += 4; pN += 4;
    }
    for (; pP < enP; pP += 4) {
        int4 ca = *(const int4*)(csrP + pP);
        int cA0 = hf ? ca.y : ca.x;
        int cA1 = hf ? ca.w : ca.z;
        unsigned va0 = xb32[cA0 * 32 + l5];
        unsigned va1 = xb32[cA1 * 32 + l5];
        a0 += lo_bf(va0) + lo_bf(va1);
        a1 += hi_bf(va0) + hi_bf(va1);
    }
    for (; pN < enN; pN += 4) {
        int4 cb = *(const int4*)(csrN + pN);
        int cB0 = hf ? cb.y : cb.x;
        int cB1 = hf ? cb.w : cb.z;
        unsigned vb0 = xb32[cB0 * 32 + l5];
        unsigned vb1 = xb32[cB1 * 32 + l5];
        b0 += lo_bf(vb0) + lo_bf(vb1);
        b1 += hi_bf(vb0) + hi_bf(vb1);
    }
    a0 += __shfl_xor(a0, 32); a1 += __shfl_xor(a1, 32);
    b0 += __shfl_xor(b0, 32); b1 += __shfl_xor(b1, 32);
    float rP = 1.f / fmaxf((float)cP, 1.f), rN = 1.f / fmaxf((float)cN, 1.f);
    gP0 = a0 * rP; gP1 = a1 * rP;
    gN0 = b0 * rN; gN1 = b1 * rN;
}

// split-row joint P/N gather-mean of fp8 {hp,hn} pair rows (4B/lane, 2 rows/load)
__device__ inline void gd2q(const unsigned* __restrict__ hq32,
                            const int* __restrict__ csrP, int pP, int enP, int cP,
                            const int* __restrict__ csrN, int pN, int enN, int cN,
                            int hf, int l5,
                            float& gPp0, float& gPp1, float& gPn0, float& gPn1,
                            float& gNp0, float& gNp1, float& gNn0, float& gNn1) {
    float ap0 = 0.f, ap1 = 0.f, an0 = 0.f, an1 = 0.f;
    float bp0 = 0.f, bp1 = 0.f, bn0 = 0.f, bn1 = 0.f;
    while (pP < enP && pN < enN) {
        int4 ca = *(const int4*)(csrP + pP);
        int4 cb = *(const int4*)(csrN + pN);
        int cA0 = hf ? ca.y : ca.x;
        int cA1 = hf ? ca.w : ca.z;
        int cB0 = hf ? cb.y : cb.x;
        int cB1 = hf ? cb.w : cb.z;
        unsigned va0 = hq32[cA0 * 32 + l5];
        unsigned va1 = hq32[cA1 * 32 + l5];
        unsigned vb0 = hq32[cB0 * 32 + l5];
        unsigned vb1 = hq32[cB1 * 32 + l5];
        ap0 += __builtin_amdgcn_cvt_f32_fp8(va0, 0) + __builtin_amdgcn_cvt_f32_fp8(va1, 0);
        an0 += __builtin_amdgcn_cvt_f32_fp8(va0, 1) + __builtin_amdgcn_cvt_f32_fp8(va1, 1);
        ap1 += __builtin_amdgcn_cvt_f32_fp8(va0, 2) + __builtin_amdgcn_cvt_f32_fp8(va1, 2);
        an1 += __builtin_amdgcn_cvt_f32_fp8(va0, 3) + __builtin_amdgcn_cvt_f32_fp8(va1, 3);
        bp0 += __builtin_amdgcn_cvt_f32_fp8(vb0, 0) + __builtin_amdgcn_cvt_f32_fp8(vb1, 0);
        bn0 += __builtin_amdgcn_cvt_f32_fp8(vb0, 1) + __builtin_amdgcn_cvt_f32_fp8(vb1, 1);
        bp1 += __builtin_amdgcn_cvt_f32_fp8(vb0, 2) + __builtin_amdgcn_cvt_f32_fp8(vb1, 2);
        bn1 += __builtin_amdgcn_cvt_f32_fp8(vb0, 3) + __builtin_amdgcn_cvt_f32_fp8(vb1, 3);
        pP += 4; pN += 4;
    }
    for (; pP < enP; pP += 4) {
        int4 ca = *(const int4*)(csrP + pP);
        int cA0 = hf ? ca.y : ca.x;
        int cA1 = hf ? ca.w : ca.z;
        unsigned va0 = hq32[cA0 * 32 + l5];
        unsigned va1 = hq32[cA1 * 32 + l5];
        ap0 += __builtin_amdgcn_cvt_f32_fp8(va0, 0) + __builtin_amdgcn_cvt_f32_fp8(va1, 0);
        an0 += __builtin_amdgcn_cvt_f32_fp8(va0, 1) + __builtin_amdgcn_cvt_f32_fp8(va1, 1);
        ap1 += __builtin_amdgcn_cvt_f32_fp8(va0, 2) + __builtin_amdgcn_cvt_f32_fp8(va1, 2);
        an1 += __builtin_amdgcn_cvt_f32_fp8(va0, 3) + __builtin_amdgcn_cvt_f32_fp8(va1, 3);
    }
    for (; pN < enN; pN += 4) {
        int4 cb = *(const int4*)(csrN + pN);
        int cB0 = hf ? cb.y : cb.x;
        int cB1 = hf ? cb.w : cb.z;
        unsigned vb0 = hq32[cB0 * 32 + l5];
        unsigned vb1 = hq32[cB1 * 32 + l5];
        bp0 += __builtin_amdgcn_cvt_f32_fp8(vb0, 0) + __builtin_amdgcn_cvt_f32_fp8(vb1, 0);
        bn0 += __builtin_amdgcn_cvt_f32_fp8(vb0, 1) + __builtin_amdgcn_cvt_f32_fp8(vb1, 1);
        bp1 += __builtin_amdgcn_cvt_f32_fp8(vb0, 2) + __builtin_amdgcn_cvt_f32_fp8(vb1, 2);
        bn1 += __builtin_amdgcn_cvt_f32_fp8(vb0, 3) + __builtin_amdgcn_cvt_f32_fp8(vb1, 3);
    }
    ap0 += __shfl_xor(ap0, 32); ap1 += __shfl_xor(ap1, 32);
    an0 += __shfl_xor(an0, 32); an1 += __shfl_xor(an1, 32);
    bp0 += __shfl_xor(bp0, 32); bp1 += __shfl_xor(bp1, 32);
    bn0 += __shfl_xor(bn0, 32); bn1 += __shfl_xor(bn1, 32);
    float rP = 1.f / fmaxf((float)cP, 1.f), rN = 1.f / fmaxf((float)cN, 1.f);
    gPp0 = ap0 * rP; gPp1 = ap1 * rP; gPn0 = an0 * rP; gPn1 = an1 * rP;
    gNp0 = bp0 * rN; gNp1 = bp1 * rN; gNn0 = bn0 * rN; gNn1 = bn1 * rN;
}

// both base layers: split-row gather -> MFMA GEMM -> tanh -> bf16 h + fp8 hq
__global__ __launch_bounds__(512) void base_both(
    const unsigned short* __restrict__ xb,
    const int* __restrict__ offP, const int* __restrict__ csrP,
    const int* __restrict__ offN, const int* __restrict__ csrN,
    const int* __restrict__ cntP, const int* __restrict__ cntN,
    const unsigned short* __restrict__ wt0,
    const float* __restrict__ bp0, const float* __restrict__ bn0,
    unsigned short* __restrict__ hboth, unsigned* __restrict__ hq32) {
    __shared__ unsigned short lds[64 * BSTR];
    int tid = threadIdx.x, lane = tid & 63, w = tid >> 6;
    int hf = lane >> 5, l5 = lane & 31;
    int base = blockIdx.x * 64;
    const unsigned* xb32 = (const unsigned*)xb;
    if (blockIdx.x == 0 && tid < 64) ((unsigned*)hboth)[N_NODES * 64 + tid] = 0u;
    if (blockIdx.x == 0 && tid < 32) hq32[N_NODES * 32 + tid] = 0u;
    for (int r = w * 8; r < w * 8 + 8; ++r) {
        int node = base + r;
        float gP0 = 0.f, gP1 = 0.f, gN0 = 0.f, gN1 = 0.f;
        unsigned sxv = 0;
        if (node < N_NODES) {
            gmb2w(xb32, csrP, offP[node], offP[node + 1], cntP[node],
                  csrN, offN[node], offN[node + 1], cntN[node], hf, l5,
                  gP0, gP1, gN0, gN1);
            sxv = xb32[node * 32 + l5];
        }
        unsigned* rp32 = (unsigned*)&lds[r * BSTR];
        if (hf == 0) {
            rp32[l5] = (unsigned)f2bf(gP0) | ((unsigned)f2bf(gP1) << 16);
            rp32[32 + l5] = sxv;
        } else {
            rp32[64 + l5] = (unsigned)f2bf(gN0) | ((unsigned)f2bf(gN1) << 16);
            rp32[96 + l5] = sxv;
        }
    }
    __syncthreads();
    int wu = __builtin_amdgcn_readfirstlane(w);
    int mt = wu >> 1, half = wu & 1;
    int l15 = lane & 15, kq = lane >> 4;
    const unsigned short* wbase = wt0 + half * 8192;
    f32x4 acc[4];
#pragma unroll
    for (int nt = 0; nt < 4; ++nt) acc[nt] = (f32x4){0.f, 0.f, 0.f, 0.f};
    const unsigned short* arow = &lds[(mt * 16 + l15) * BSTR + half * 128 + kq * 8];
#pragma unroll
    for (int ks = 0; ks < 4; ++ks) {
        sh8 a = *(const sh8*)(arow + ks * 32);
#pragma unroll
        for (int nt = 0; nt < 4; ++nt) {
            sh8 bf = *(const sh8*)(wbase + (nt * 16 + l15) * 128 + ks * 32 + kq * 8);
            acc[nt] = __builtin_amdgcn_mfma_f32_16x16x32_bf16(a, bf, acc[nt], 0, 0, 0);
        }
    }
    __syncthreads();
    float* ht = (float*)lds;  // [64][130]
    const float* bias = half ? bn0 : bp0;
#pragma unroll
    for (int nt = 0; nt < 4; ++nt) {
        int col = nt * 16 + l15;
        float bb = bias[col];
#pragma unroll
        for (int r = 0; r < 4; ++r) {
            int row = mt * 16 + kq * 4 + r;
            ht[row * 130 + half * 64 + col] = tanhf(acc[nt][r] + bb);
        }
    }
    __syncthreads();
    unsigned* hb32 = (unsigned*)hboth;
    for (int i = tid; i < 64 * 64; i += 512) {
        int rr = i >> 6, c = i & 63;
        int node = base + rr;
        if (node < N_NODES) {
            unsigned lo = f2bf(ht[rr * 130 + c]);
            unsigned hi = f2bf(ht[rr * 130 + 64 + c]);
            hb32[node * 64 + c] = lo | (hi << 16);
        }
    }
    for (int i = tid; i < 64 * 32; i += 512) {
        int rr = i >> 5, c2 = i & 31;
        int node = base + rr;
        if (node < N_NODES) {
            float hp0 = ht[rr * 130 + 2 * c2];
            float hn0 = ht[rr * 130 + 64 + 2 * c2];
            float hp1 = ht[rr * 130 + 2 * c2 + 1];
            float hn1 = ht[rr * 130 + 64 + 2 * c2 + 1];
            int lo = __builtin_amdgcn_cvt_pk_fp8_f32(hp0, hn0, 0, false);
            int q = __builtin_amdgcn_cvt_pk_fp8_f32(hp1, hn1, lo, true);
            hq32[node * 32 + c2] = (unsigned)q;
        }
    }
}

// both deep layers: 32-node blocks, fp8 split-row gather -> MFMA -> tanh -> epilogue
__global__ __launch_bounds__(512) void deep_both(
    const unsigned short* __restrict__ hb, const unsigned* __restrict__ hq32,
    const int* __restrict__ offP, const int* __restrict__ csrP,
    const int* __restrict__ offN, const int* __restrict__ csrN,
    const int* __restrict__ cntP, const int* __restrict__ cntN,
    const unsigned short* __restrict__ wt1,
    const float* __restrict__ bp1, const float* __restrict__ bn1,
    const float* __restrict__ Wreg, float* __restrict__ z,
    unsigned char* __restrict__ zq, float4* __restrict__ pnu,
    float4* __restrict__ pnv) {
    __shared__ unsigned short lds[32 * DSTR];   // 25088 B
    int tid = threadIdx.x, lane = tid & 63, w = tid >> 6;
    int hf = lane >> 5, l5 = lane & 31;
    int base = blockIdx.x * 32;
    const unsigned* hb32 = (const unsigned*)hb;
    for (int r = w * 4; r < w * 4 + 4; ++r) {
        int node = base + r;
        float gPp0, gPp1, gPn0, gPn1, gNp0, gNp1, gNn0, gNn1;
        gd2q(hq32, csrP, offP[node], offP[node + 1], cntP[node],
             csrN, offN[node], offN[node + 1], cntN[node], hf, l5,
             gPp0, gPp1, gPn0, gPn1, gNp0, gNp1, gNn0, gNn1);
        uint2 sv = *(const uint2*)(hb32 + node * 64 + l5 * 2);
        unsigned* rp32 = (unsigned*)&lds[r * DSTR];
        if (hf == 0) {
            rp32[l5] = (unsigned)f2bf(gPp0) | ((unsigned)f2bf(gPp1) << 16);
            rp32[32 + l5] = (unsigned)f2bf(gNn0) | ((unsigned)f2bf(gNn1) << 16);
            rp32[64 + l5] = (sv.x & 0xFFFFu) | ((sv.y & 0xFFFFu) << 16);  // hp pair
        } else {
            rp32[96 + l5] = (unsigned)f2bf(gPn0) | ((unsigned)f2bf(gPn1) << 16);
            rp32[128 + l5] = (unsigned)f2bf(gNp0) | ((unsigned)f2bf(gNp1) << 16);
            rp32[160 + l5] = (sv.x >> 16) | (sv.y & 0xFFFF0000u);         // hn pair
        }
    }
    __syncthreads();
    int wu = __builtin_amdgcn_readfirstlane(w);
    int mt = wu >> 2, half = (wu >> 1) & 1, nt = wu & 1;
    int l15 = lane & 15, kq = lane >> 4;
    const unsigned short* wbase = wt1 + half * 6144;
    f32x4 acc = (f32x4){0.f, 0.f, 0.f, 0.f};
    const unsigned short* arow = &lds[(mt * 16 + l15) * DSTR + half * 192 + kq * 8];
#pragma unroll
    for (int ks = 0; ks < 6; ++ks) {
        sh8 a = *(const sh8*)(arow + ks * 32);
        sh8 bf = *(const sh8*)(wbase + (nt * 16 + l15) * 192 + ks * 32 + kq * 8);
        acc = __builtin_amdgcn_mfma_f32_16x16x32_bf16(a, bf, acc, 0, 0, 0);
    }
    __syncthreads();
    float* ot = (float*)lds;  // [32][65]
    {
        const float* bias = half ? bn1 : bp1;
        int col = nt * 16 + l15;
        float bb = bias[col];
#pragma unroll
        for (int r = 0; r < 4; ++r) {
            int row = mt * 16 + kq * 4 + r;
            ot[row * 65 + half * 32 + col] = tanhf(acc[r] + bb);
        }
    }
    __syncthreads();
    for (int r = w * 4; r < w * 4 + 4; ++r) {
        int node = base + r;
        float v = ot[r * 65 + lane];
        z[node * 64 + lane] = v;
        int pq = __builtin_amdgcn_cvt_pk_fp8_f32(v, v, 0, false);
        zq[node * 64 + lane] = (unsigned char)(pq & 0xFF);
        float vq = __builtin_amdgcn_cvt_f32_fp8(pq, 0);
        float u0 = vq * Wreg[lane * 2 + 0];
        float u1 = vq * Wreg[lane * 2 + 1];
        float v0 = vq * Wreg[128 + lane * 2 + 0];
        float v1 = vq * Wreg[128 + lane * 2 + 1];
        float s = vq * vq;
#pragma unroll
        for (int off = 32; off; off >>= 1) {
            u0 += __shfl_xor(u0, off);
            u1 += __shfl_xor(u1, off);
            v0 += __shfl_xor(v0, off);
            v1 += __shfl_xor(v1, off);
            s += __shfl_xor(s, off);
        }
        if (lane == 0) {
            float4 su = {u0, u1, s, 0.f};
            float4 sv2 = {v0, v1, s, 0.f};
            pnu[node] = su;
            pnv[node] = sv2;
        }
    }
}

// 4-lane edge groups, 16B/lane rows, two batches of 16 edges per iter
__global__ __launch_bounds__(256) void loss6_kernel(
    const unsigned char* __restrict__ zq, const float4* __restrict__ pnu,
    const float4* __restrict__ pnv, const int4* __restrict__ eidx, float* acc) {
    int tid = threadIdx.x;
    int lane = tid & 63;
    int g = lane >> 2, sub = lane & 3;   // 16 groups of 4 lanes
    int wid = (blockIdx.x * 256 + tid) >> 6;
    int nw = (gridDim.x * 256) >> 6;
    float s_p = 0.f, s_n = 0.f, s_r = 0.f;
    const float q = 0.25f;               // each edge duplicated in 4 lanes
    for (int eb = wid * 32; eb < EP_N + EN_N; eb += nw * 32) {
        int eA = eb + g, eB = eb + 16 + g;
        bool vA = eA < EP_N + EN_N, vB = eB < EP_N + EN_N;
        bool pA = eA < EP_N, pB = eB < EP_N;
        int4 qA = eidx[vA ? eA : 0];
        int4 qB = eidx[vB ? eB : 0];
        uint4 ziA = *(const uint4*)(zq + ((long long)qA.x << 6) + (sub << 4));
        uint4 zjA = *(const uint4*)(zq + ((long long)qA.y << 6) + (sub << 4));
        uint4 zkA = *(const uint4*)(zq + ((long long)qA.z << 6) + (sub << 4));
        uint4 ziB = *(const uint4*)(zq + ((long long)qB.x << 6) + (sub << 4));
        uint4 zjB = *(const uint4*)(zq + ((long long)qB.y << 6) + (sub << 4));
        uint4 zkB = *(const uint4*)(zq + ((long long)qB.z << 6) + (sub << 4));
        float4 uA = pnu[qA.x];
        float4 wA = pnv[qA.y];
        float skA = pnu[qA.z].z;
        float4 uB = pnu[qB.x];
        float4 wB = pnv[qB.y];
        float skB = pnu[qB.z].z;
        float d1A = dot4f8(ziA.x, zjA.x) + dot4f8(ziA.y, zjA.y) +
                    dot4f8(ziA.z, zjA.z) + dot4f8(ziA.w, zjA.w);
        float d2A = dot4f8(zjA.x, zkA.x) + dot4f8(zjA.y, zkA.y) +
                    dot4f8(zjA.z, zkA.z) + dot4f8(zjA.w, zkA.w);
        float d1B = dot4f8(ziB.x, zjB.x) + dot4f8(ziB.y, zjB.y) +
                    dot4f8(ziB.z, zjB.z) + dot4f8(ziB.w, zjB.w);
        float d2B = dot4f8(zjB.x, zkB.x) + dot4f8(zjB.y, zkB.y) +
                    dot4f8(zjB.z, zkB.z) + dot4f8(zjB.w, zkB.w);
#pragma unroll
        for (int off = 1; off < 4; off <<= 1) {
            d1A += __shfl_xor(d1A, off);
            d2A += __shfl_xor(d2A, off);
            d1B += __shfl_xor(d1B, off);
            d2B += __shfl_xor(d2B, off);
        }
        if (vA) {
            float nij = uA.z + wA.z - 2.f * d1A;
            float nik = wA.z + skA - 2.f * d2A;
            float tri = fmaxf(nij - nik, 0.f);
            float l0 = uA.x + wA.x, l1 = uA.y + wA.y;
            float m = fmaxf(l0, l1);
            float lse = m + logf(expf(l0 - m) + expf(l1 - m));
            s_r += (lse - (qA.w ? l1 : l0)) * q;
            if (pA) s_p += tri * q; else s_n += tri * q;
        }
        if (vB) {
            float nij = uB.z + wB.z - 2.f * d1B;
            float nik = wB.z + skB - 2.f * d2B;
            float tri = fmaxf(nij - nik, 0.f);
            float l0 = uB.x + wB.x, l1 = uB.y + wB.y;
            float m = fmaxf(l0, l1);
            float lse = m + logf(expf(l0 - m) + expf(l1 - m));
            s_r += (lse - (qB.w ? l1 : l0)) * q;
            if (pB) s_p += tri * q; else s_n += tri * q;
        }
    }
#pragma unroll
    for (int off = 32; off; off >>= 1) {
        s_p += __shfl_xor(s_p, off);
        s_n += __shfl_xor(s_n, off);
        s_r += __shfl_xor(s_r, off);
    }
    __shared__ float red[3][4];
    int w = tid >> 6;
    if (lane == 0) {
        red[0][w] = s_p; red[1][w] = s_n; red[2][w] = s_r;
    }
    __syncthreads();
    if (tid == 0) {
        atomicAdd(&acc[0], red[0][0] + red[0][1] + red[0][2] + red[0][3]);
        atomicAdd(&acc[1], red[1][0] + red[1][1] + red[1][2] + red[1][3]);
        atomicAdd(&acc[2], red[2][0] + red[2][1] + red[2][2] + red[2][3]);
    }
}

__global__ void finalize_kernel(const float* __restrict__ acc, float* out) {
    out[0] = acc[2] / (float)(EP_N + EN_N) +
             1.0f * (acc[0] / (float)EP_N + acc[1] / (float)EN_N);
}

extern "C" void kernel_launch(void* const* d_in, const int* in_sizes, int n_in,
                              void* d_out, int out_size, void* d_ws, size_t ws_size,
                              hipStream_t stream) {
    const float* X = (const float*)d_in[0];
    const float* W_pos0 = (const float*)d_in[1];
    const float* b_pos0 = (const float*)d_in[2];
    const float* W_neg0 = (const float*)d_in[3];
    const float* b_neg0 = (const float*)d_in[4];
    const float* W_pos1 = (const float*)d_in[5];
    const float* b_pos1 = (const float*)d_in[6];
    const float* W_neg1 = (const float*)d_in[7];
    const float* b_neg1 = (const float*)d_in[8];
    const float* W_reg = (const float*)d_in[9];
    const int* pe = (const int*)d_in[10];
    const int* ne = (const int*)d_in[11];
    const int* target = (const int*)d_in[12];
    const int* ps = (const int*)d_in[13];
    const int* ns = (const int*)d_in[14];
    float* out = (float*)d_out;
    float* ws = (float*)d_ws;
    int* wsi = (int*)d_ws;

    float* acc = ws + ACC_OFF;
    int* cntP = wsi + I_CNTP;
    int* cntN = wsi + I_CNTN;
    int* curP = wsi + I_CURP;
    int* curN = wsi + I_CURN;
    int* offP = wsi + I_OFFP;
    int* offN = wsi + I_OFFN;
    int* offPc = wsi + I_OFFPC;
    int* offNc = wsi + I_OFFNC;
    int* csrP = wsi + I_CSRP;
    int* csrN = wsi + I_CSRN;
    int* part = wsi + I_PART;
    int4* eidx = (int4*)(wsi + I_EIDX);
    unsigned short* xb = (unsigned short*)(ws + F_XB);
    unsigned short* hboth = (unsigned short*)(ws + F_HB);
    unsigned* hq32 = (unsigned*)(ws + F_HQ);
    float4* pnu = (float4*)(ws + F_PNU);
    float4* pnv = (float4*)(ws + F_PNV);
    unsigned char* zq = (unsigned char*)(ws + F_ZQ);
    unsigned short* wt = (unsigned short*)(ws + F_WT);
    float* z = out + 1;

    hipMemsetAsync(ws, 0, (size_t)(16 + 4 * N_NODES) * sizeof(float), stream);

    prep_kernel<<<XB_BLKS + WP_BLKS + CNT_BLKS, 256, 0, stream>>>(
        X, xb, W_pos0, W_neg0, W_pos1, W_neg1, wt, pe, ne, cntP, cntN);
    scan_p1<<<2 * SBLK, 512, 0, stream>>>(cntP, cntN, part);
    scan_p2<<<1, 1024, 0, stream>>>(part);
    scan_p3<<<2 * SBLK, 512, 0, stream>>>(cntP, cntN, part, offP, offN,
                                          offPc, offNc, csrP, csrN);
    fill_kernel<<<(EP_N + EN_N + 255) / 256, 256, 0, stream>>>(
        pe, ne, offP, offN, offPc, offNc, ps, ns, target,
        curP, curN, csrP, csrN, eidx);

    base_both<<<NODE_BLOCKS, 512, 0, stream>>>(xb, offP, csrP, offN, csrN, cntP, cntN,
                                               wt, b_pos0, b_neg0, hboth, hq32);
    deep_both<<<DEEP_BLOCKS, 512, 0, stream>>>(hboth, hq32, offP, csrP, offN, csrN,
                                               cntP, cntN, wt + 16384, b_pos1, b_neg1,
                                               W_reg, z, zq, pnu, pnv);

    loss6_kernel<<<2048, 256, 0, stream>>>(zq, pnu, pnv, eidx, acc);
    finalize_kernel<<<1, 1, 0, stream>>>(acc, out);
}

// Round 16
// 332.157 us; speedup vs baseline: 1.4861x; 1.0473x over previous
//
#include <hip/hip_runtime.h>
#include <cstdint>

#define N_NODES 100000
#define EP_N 400000
#define EN_N 400000
#define NODE_BLOCKS ((N_NODES + 63) / 64)
#define DEEP_BLOCKS (N_NODES / 32)
#define SCHUNK 512
#define SBLK ((N_NODES + SCHUNK - 1) / SCHUNK)

#define BSTR 264
#define DSTR 392

#define XB_BLKS ((((N_NODES + 1) * 16) + 255) / 256)
#define WP_BLKS 113
#define CNT_BLKS (((EP_N + EN_N) + 255) / 256)

// ws layout (in 4-byte units)
#define ACC_OFF 0
#define I_CNTP 16
#define I_CNTN (I_CNTP + N_NODES)
#define I_CURP (I_CNTN + N_NODES)
#define I_CURN (I_CURP + N_NODES)
#define I_OFFP (I_CURN + N_NODES)
#define I_OFFN (I_OFFP + N_NODES + 1)
#define I_OFFPC (I_OFFN + N_NODES + 1)
#define I_OFFNC (I_OFFPC + N_NODES + 1)
#define I_CSRP (((I_OFFNC + N_NODES + 1) + 3) & ~3)
#define CSR_SZ (EP_N + 4 * N_NODES)
#define I_CSRN (I_CSRP + CSR_SZ)
#define I_PART (I_CSRN + CSR_SZ)
#define I_EIDX (((I_PART + 4 * SBLK) + 3) & ~3)
#define F_XB (((I_EIDX + 4 * (EP_N + EN_N)) + 15) & ~15)
#define F_HB (F_XB + 32 * (N_NODES + 1))
#define F_HQ (F_HB + 64 * (N_NODES + 1))
#define F_PNU (F_HQ + 32 * (N_NODES + 1))          // pnu: N float4 {u0,u1,s,0}
#define F_ZQ (F_PNU + 4 * N_NODES)                 // zq: N*64 bytes
#define F_WT (((F_ZQ + 16 * N_NODES) + 15) & ~15)  // wt: 28672 ushorts + 64 u32 wvb

typedef __attribute__((ext_vector_type(8))) short sh8;
typedef __attribute__((ext_vector_type(4))) float f32x4;

__device__ inline float bf2f(unsigned short u) {
    return __uint_as_float((unsigned)u << 16);
}
__device__ inline unsigned short f2bf(float v) {
    unsigned u = __float_as_uint(v);
    return (unsigned short)((u + 0x7FFFu + ((u >> 16) & 1u)) >> 16);
}
__device__ inline float lo_bf(unsigned u) { return __uint_as_float(u << 16); }
__device__ inline float hi_bf(unsigned u) { return __uint_as_float(u & 0xFFFF0000u); }

__device__ inline void cvt16(uint4 r, float* f) {
#pragma unroll
    for (int c = 0; c < 4; ++c) {
        unsigned u = (&r.x)[c];
        f[c * 4 + 0] = __builtin_amdgcn_cvt_f32_fp8(u, 0);
        f[c * 4 + 1] = __builtin_amdgcn_cvt_f32_fp8(u, 1);
        f[c * 4 + 2] = __builtin_amdgcn_cvt_f32_fp8(u, 2);
        f[c * 4 + 3] = __builtin_amdgcn_cvt_f32_fp8(u, 3);
    }
}

// fused: X->bf16 (+sentinel) | weight transpose->bf16 (+Wreg v-cols) | degree count
__global__ void prep_kernel(const float* __restrict__ X, unsigned short* __restrict__ xb,
                            const float* __restrict__ W0p, const float* __restrict__ W0n,
                            const float* __restrict__ W1p, const float* __restrict__ W1n,
                            const float* __restrict__ Wreg,
                            unsigned short* __restrict__ wt,
                            const int* __restrict__ pe, const int* __restrict__ ne,
                            int* cp, int* cn) {
    int b = blockIdx.x;
    if (b < XB_BLKS) {
        int i = b * 256 + threadIdx.x;
        if (i < (N_NODES + 1) * 16) {
            ushort4 o = {0, 0, 0, 0};
            if (i < N_NODES * 16) {
                float4 v = ((const float4*)X)[i];
                o.x = f2bf(v.x); o.y = f2bf(v.y); o.z = f2bf(v.z); o.w = f2bf(v.w);
            }
            ((ushort4*)xb)[i] = o;
        }
    } else if (b < XB_BLKS + WP_BLKS) {
        int i = (b - XB_BLKS) * 256 + threadIdx.x;
        if (i < 8192) {
            int n = i >> 7, k = i & 127;
            wt[i] = f2bf(W0p[k * 64 + n]);
        } else if (i < 16384) {
            int j = i - 8192; int n = j >> 7, k = j & 127;
            wt[i] = f2bf(W0n[k * 64 + n]);
        } else if (i < 22528) {
            int j = i - 16384; int n = j / 192, k = j - n * 192;
            wt[i] = f2bf(W1p[k * 32 + n]);
        } else if (i < 28672) {
            int j = i - 22528; int n = j / 192, k = j - n * 192;
            wt[i] = f2bf(W1n[k * 32 + n]);
        } else if (i < 28736) {
            int j = i - 28672;   // Wreg v-cols packed bf16: {v0,v1} per dim
            unsigned* wvb = (unsigned*)(wt + 28672);
            wvb[j] = (unsigned)f2bf(Wreg[128 + j * 2]) |
                     ((unsigned)f2bf(Wreg[128 + j * 2 + 1]) << 16);
        }
    } else {
        int i = (b - XB_BLKS - WP_BLKS) * 256 + threadIdx.x;
        if (i < EP_N) {
            atomicAdd(&cp[pe[i]], 1);
        } else if (i < EP_N + EN_N) {
            atomicAdd(&cn[ne[i - EP_N]], 1);
        }
    }
}

__global__ __launch_bounds__(512) void scan_p1(const int* __restrict__ cntP,
                                               const int* __restrict__ cntN,
                                               int* part) {
    int l = blockIdx.x < SBLK ? 0 : 1;
    int blk = blockIdx.x - l * SBLK;
    const int* cnt = l == 0 ? cntP : cntN;
    int idx = blk * SCHUNK + threadIdx.x;
    int c = idx < N_NODES ? cnt[idx] : 0;
    int vp = (c + 3) & ~3;
    __shared__ int tmp[512];
    __shared__ int tmp2[512];
    tmp[threadIdx.x] = vp;
    tmp2[threadIdx.x] = c;
    __syncthreads();
    for (int d = 256; d > 0; d >>= 1) {
        if (threadIdx.x < d) {
            tmp[threadIdx.x] += tmp[threadIdx.x + d];
            tmp2[threadIdx.x] += tmp2[threadIdx.x + d];
        }
        __syncthreads();
    }
    if (threadIdx.x == 0) {
        part[l * SBLK + blk] = tmp[0];
        part[(2 + l) * SBLK + blk] = tmp2[0];
    }
}

__global__ __launch_bounds__(1024) void scan_p2(int* part) {
    int t = threadIdx.x;
    int l = t >> 8, idx = t & 255;
    int v = idx < SBLK ? part[l * SBLK + idx] : 0;
    __shared__ int tmp[1024];
    int sb = l << 8;
    tmp[sb + idx] = v;
    __syncthreads();
    for (int d = 1; d < 256; d <<= 1) {
        int x = (idx >= d) ? tmp[sb + idx - d] : 0;
        __syncthreads();
        tmp[sb + idx] += x;
        __syncthreads();
    }
    if (idx < SBLK) part[l * SBLK + idx] = tmp[sb + idx] - v;
}

__global__ __launch_bounds__(512) void scan_p3(const int* __restrict__ cntP,
                                               const int* __restrict__ cntN,
                                               const int* __restrict__ part,
                                               int* offP, int* offN,
                                               int* offPc, int* offNc,
                                               int* csrP, int* csrN) {
    int l = blockIdx.x < SBLK ? 0 : 1;
    int blk = blockIdx.x - l * SBLK;
    const int* cnt = l == 0 ? cntP : cntN;
    int* off = l == 0 ? offP : offN;
    int* offc = l == 0 ? offPc : offNc;
    int* csr = l == 0 ? csrP : csrN;
    int base = part[l * SBLK + blk];
    int basec = part[(2 + l) * SBLK + blk];
    int t = threadIdx.x;
    int gidx = blk * SCHUNK + t;
    int c = gidx < N_NODES ? cnt[gidx] : 0;
    int cpad = (c + 3) & ~3;
    __shared__ int tmp[512];
    __shared__ int tmp2[512];
    tmp[t] = cpad;
    tmp2[t] = c;
    __syncthreads();
    for (int d = 1; d < 512; d <<= 1) {
        int x = (t >= d) ? tmp[t - d] : 0;
        int x2 = (t >= d) ? tmp2[t - d] : 0;
        __syncthreads();
        tmp[t] += x;
        tmp2[t] += x2;
        __syncthreads();
    }
    int incl = tmp[t], inclc = tmp2[t];
    if (gidx < N_NODES) {
        int o = base + incl - cpad;
        off[gidx] = o;
        offc[gidx] = basec + inclc - c;
        for (int p = c; p < cpad; ++p) csr[o + p] = N_NODES;
    }
    if (gidx == N_NODES - 1) {
        off[N_NODES] = base + incl;
        offc[N_NODES] = basec + inclc;
    }
}

__global__ void fill_kernel(const int* __restrict__ pe, const int* __restrict__ ne,
                            const int* __restrict__ offP, const int* __restrict__ offN,
                            const int* __restrict__ offPc, const int* __restrict__ offNc,
                            const int* __restrict__ ps, const int* __restrict__ ns,
                            const int* __restrict__ tgt,
                            int* curP, int* curN, int* csrP, int* csrN,
                            int4* __restrict__ eidx) {
    int e = blockIdx.x * 256 + threadIdx.x;
    if (e < EP_N) {
        int row = pe[e], col = pe[EP_N + e];
        int slot = atomicAdd(&curP[row], 1);
        csrP[offP[row] + slot] = col;
        int4 q = {row, col, ps[e], tgt[e]};
        eidx[offPc[row] + slot] = q;
    } else if (e < EP_N + EN_N) {
        int e2 = e - EP_N;
        int row = ne[e2], col = ne[EN_N + e2];
        int slot = atomicAdd(&curN[row], 1);
        csrN[offN[row] + slot] = col;
        int4 q = {row, col, ns[e2], tgt[e]};
        eidx[EP_N + offNc[row] + slot] = q;
    }
}

__device__ inline void gmb2w(const unsigned* __restrict__ xb32,
                             const int* __restrict__ csrP, int pP, int enP, int cP,
                             const int* __restrict__ csrN, int pN, int enN, int cN,
                             int hf, int l5,
                             float& gP0, float& gP1, float& gN0, float& gN1) {
    float a0 = 0.f, a1 = 0.f, b0 = 0.f, b1 = 0.f;
    while (pP < enP && pN < enN) {
        int4 ca = *(const int4*)(csrP + pP);
        int4 cb = *(const int4*)(csrN + pN);
        int cA0 = hf ? ca.y : ca.x;
        int cA1 = hf ? ca.w : ca.z;
        int cB0 = hf ? cb.y : cb.x;
        int cB1 = hf ? cb.w : cb.z;
        unsigned va0 = xb32[cA0 * 32 + l5];
        unsigned va1 = xb32[cA1 * 32 + l5];
        unsigned vb0 = xb32[cB0 * 32 + l5];
        unsigned vb1 = xb32[cB1 * 32 + l5];
        a0 += lo_bf(va0) + lo_bf(va1);
        a1 += hi_bf(va0) + hi_bf(va1);
        b0 += lo_bf(vb0) + lo_bf(vb1);
        b1 += hi_bf(vb0) + hi_bf(vb1);
        pP += 4; pN += 4;
    }
    for (; pP < enP; pP += 4) {
        int4 ca = *(const int4*)(csrP + pP);
        int cA0 = hf ? ca.y : ca.x;
        int cA1 = hf ? ca.w : ca.z;
        unsigned va0 = xb32[cA0 * 32 + l5];
        unsigned va1 = xb32[cA1 * 32 + l5];
        a0 += lo_bf(va0) + lo_bf(va1);
        a1 += hi_bf(va0) + hi_bf(va1);
    }
    for (; pN < enN; pN += 4) {
        int4 cb = *(const int4*)(csrN + pN);
        int cB0 = hf ? cb.y : cb.x;
        int cB1 = hf ? cb.w : cb.z;
        unsigned vb0 = xb32[cB0 * 32 + l5];
        unsigned vb1 = xb32[cB1 * 32 + l5];
        b0 += lo_bf(vb0) + lo_bf(vb1);
        b1 += hi_bf(vb0) + hi_bf(vb1);
    }
    a0 += __shfl_xor(a0, 32); a1 += __shfl_xor(a1, 32);
    b0 += __shfl_xor(b0, 32); b1 += __shfl_xor(b1, 32);
    float rP = 1.f / fmaxf((float)cP, 1.f), rN = 1.f / fmaxf((float)cN, 1.f);
    gP0 = a0 * rP; gP1 = a1 * rP;
    gN0 = b0 * rN; gN1 = b1 * rN;
}

__device__ inline void gd2q(const unsigned* __restrict__ hq32,
                            const int* __restrict__ csrP, int pP, int enP, int cP,
                            const int* __restrict__ csrN, int pN, int enN, int cN,
                            int hf, int l5,
                            float& gPp0, float& gPp1, float& gPn0, float& gPn1,
                            float& gNp0, float& gNp1, float& gNn0, float& gNn1) {
    float ap0 = 0.f, ap1 = 0.f, an0 = 0.f, an1 = 0.f;
    float bp0 = 0.f, bp1 = 0.f, bn0 = 0.f, bn1 = 0.f;
    while (pP < enP && pN < enN) {
        int4 ca = *(const int4*)(csrP + pP);
        int4 cb = *(const int4*)(csrN + pN);
        int cA0 = hf ? ca.y : ca.x;
        int cA1 = hf ? ca.w : ca.z;
        int cB0 = hf ? cb.y : cb.x;
        int cB1 = hf ? cb.w : cb.z;
        unsigned va0 = hq32[cA0 * 32 + l5];
        unsigned va1 = hq32[cA1 * 32 + l5];
        unsigned vb0 = hq32[cB0 * 32 + l5];
        unsigned vb1 = hq32[cB1 * 32 + l5];
        ap0 += __builtin_amdgcn_cvt_f32_fp8(va0, 0) + __builtin_amdgcn_cvt_f32_fp8(va1, 0);
        an0 += __builtin_amdgcn_cvt_f32_fp8(va0, 1) + __builtin_amdgcn_cvt_f32_fp8(va1, 1);
        ap1 += __builtin_amdgcn_cvt_f32_fp8(va0, 2) + __builtin_amdgcn_cvt_f32_fp8(va1, 2);
        an1 += __builtin_amdgcn_cvt_f32_fp8(va0, 3) + __builtin_amdgcn_cvt_f32_fp8(va1, 3);
        bp0 += __builtin_amdgcn_cvt_f32_fp8(vb0, 0) + __builtin_amdgcn_cvt_f32_fp8(vb1, 0);
        bn0 += __builtin_amdgcn_cvt_f32_fp8(vb0, 1) + __builtin_amdgcn_cvt_f32_fp8(vb1, 1);
        bp1 += __builtin_amdgcn_cvt_f32_fp8(vb0, 2) + __builtin_amdgcn_cvt_f32_fp8(vb1, 2);
        bn1 += __builtin_amdgcn_cvt_f32_fp8(vb0, 3) + __builtin_amdgcn_cvt_f32_fp8(vb1, 3);
        pP += 4; pN += 4;
    }
    for (; pP < enP; pP += 4) {
        int4 ca = *(const int4*)(csrP + pP);
        int cA0 = hf ? ca.y : ca.x;
        int cA1 = hf ? ca.w : ca.z;
        unsigned va0 = hq32[cA0 * 32 + l5];
        unsigned va1 = hq32[cA1 * 32 + l5];
        ap0 += __builtin_amdgcn_cvt_f32_fp8(va0, 0) + __builtin_amdgcn_cvt_f32_fp8(va1, 0);
        an0 += __builtin_amdgcn_cvt_f32_fp8(va0, 1) + __builtin_amdgcn_cvt_f32_fp8(va1, 1);
        ap1 += __builtin_amdgcn_cvt_f32_fp8(va0, 2) + __builtin_amdgcn_cvt_f32_fp8(va1, 2);
        an1 += __builtin_amdgcn_cvt_f32_fp8(va0, 3) + __builtin_amdgcn_cvt_f32_fp8(va1, 3);
    }
    for (; pN < enN; pN += 4) {
        int4 cb = *(const int4*)(csrN + pN);
        int cB0 = hf ? cb.y : cb.x;
        int cB1 = hf ? cb.w : cb.z;
        unsigned vb0 = hq32[cB0 * 32 + l5];
        unsigned vb1 = hq32[cB1 * 32 + l5];
        bp0 += __builtin_amdgcn_cvt_f32_fp8(vb0, 0) + __builtin_amdgcn_cvt_f32_fp8(vb1, 0);
        bn0 += __builtin_amdgcn_cvt_f32_fp8(vb0, 1) + __builtin_amdgcn_cvt_f32_fp8(vb1, 1);
        bp1 += __builtin_amdgcn_cvt_f32_fp8(vb0, 2) + __builtin_amdgcn_cvt_f32_fp8(vb1, 2);
        bn1 += __builtin_amdgcn_cvt_f32_fp8(vb0, 3) + __builtin_amdgcn_cvt_f32_fp8(vb1, 3);
    }
    ap0 += __shfl_xor(ap0, 32); ap1 += __shfl_xor(ap1, 32);
    an0 += __shfl_xor(an0, 32); an1 += __shfl_xor(an1, 32);
    bp0 += __shfl_xor(bp0, 32); bp1 += __shfl_xor(bp1, 32);
    bn0 += __shfl_xor(bn0, 32); bn1 += __shfl_xor(bn1, 32);
    float rP = 1.f / fmaxf((float)cP, 1.f), rN = 1.f / fmaxf((float)cN, 1.f);
    gPp0 = ap0 * rP; gPp1 = ap1 * rP; gPn0 = an0 * rP; gPn1 = an1 * rP;
    gNp0 = bp0 * rN; gNp1 = bp1 * rN; gNn0 = bn0 * rN; gNn1 = bn1 * rN;
}

__global__ __launch_bounds__(512) void base_both(
    const unsigned short* __restrict__ xb,
    const int* __restrict__ offP, const int* __restrict__ csrP,
    const int* __restrict__ offN, const int* __restrict__ csrN,
    const int* __restrict__ cntP, const int* __restrict__ cntN,
    const unsigned short* __restrict__ wt0,
    const float* __restrict__ bp0, const float* __restrict__ bn0,
    unsigned short* __restrict__ hboth, unsigned* __restrict__ hq32) {
    __shared__ unsigned short lds[64 * BSTR];
    int tid = threadIdx.x, lane = tid & 63, w = tid >> 6;
    int hf = lane >> 5, l5 = lane & 31;
    int base = blockIdx.x * 64;
    const unsigned* xb32 = (const unsigned*)xb;
    if (blockIdx.x == 0 && tid < 64) ((unsigned*)hboth)[N_NODES * 64 + tid] = 0u;
    if (blockIdx.x == 0 && tid < 32) hq32[N_NODES * 32 + tid] = 0u;
    for (int r = w * 8; r < w * 8 + 8; ++r) {
        int node = base + r;
        float gP0 = 0.f, gP1 = 0.f, gN0 = 0.f, gN1 = 0.f;
        unsigned sxv = 0;
        if (node < N_NODES) {
            gmb2w(xb32, csrP, offP[node], offP[node + 1], cntP[node],
                  csrN, offN[node], offN[node + 1], cntN[node], hf, l5,
                  gP0, gP1, gN0, gN1);
            sxv = xb32[node * 32 + l5];
        }
        unsigned* rp32 = (unsigned*)&lds[r * BSTR];
        if (hf == 0) {
            rp32[l5] = (unsigned)f2bf(gP0) | ((unsigned)f2bf(gP1) << 16);
            rp32[32 + l5] = sxv;
        } else {
            rp32[64 + l5] = (unsigned)f2bf(gN0) | ((unsigned)f2bf(gN1) << 16);
            rp32[96 + l5] = sxv;
        }
    }
    __syncthreads();
    int wu = __builtin_amdgcn_readfirstlane(w);
    int mt = wu >> 1, half = wu & 1;
    int l15 = lane & 15, kq = lane >> 4;
    const unsigned short* wbase = wt0 + half * 8192;
    f32x4 acc[4];
#pragma unroll
    for (int nt = 0; nt < 4; ++nt) acc[nt] = (f32x4){0.f, 0.f, 0.f, 0.f};
    const unsigned short* arow = &lds[(mt * 16 + l15) * BSTR + half * 128 + kq * 8];
#pragma unroll
    for (int ks = 0; ks < 4; ++ks) {
        sh8 a = *(const sh8*)(arow + ks * 32);
#pragma unroll
        for (int nt = 0; nt < 4; ++nt) {
            sh8 bf = *(const sh8*)(wbase + (nt * 16 + l15) * 128 + ks * 32 + kq * 8);
            acc[nt] = __builtin_amdgcn_mfma_f32_16x16x32_bf16(a, bf, acc[nt], 0, 0, 0);
        }
    }
    __syncthreads();
    float* ht = (float*)lds;  // [64][130]
    const float* bias = half ? bn0 : bp0;
#pragma unroll
    for (int nt = 0; nt < 4; ++nt) {
        int col = nt * 16 + l15;
        float bb = bias[col];
#pragma unroll
        for (int r = 0; r < 4; ++r) {
            int row = mt * 16 + kq * 4 + r;
            ht[row * 130 + half * 64 + col] = tanhf(acc[nt][r] + bb);
        }
    }
    __syncthreads();
    unsigned* hb32 = (unsigned*)hboth;
    for (int i = tid; i < 64 * 64; i += 512) {
        int rr = i >> 6, c = i & 63;
        int node = base + rr;
        if (node < N_NODES) {
            unsigned lo = f2bf(ht[rr * 130 + c]);
            unsigned hi = f2bf(ht[rr * 130 + 64 + c]);
            hb32[node * 64 + c] = lo | (hi << 16);
        }
    }
    for (int i = tid; i < 64 * 32; i += 512) {
        int rr = i >> 5, c2 = i & 31;
        int node = base + rr;
        if (node < N_NODES) {
            float hp0 = ht[rr * 130 + 2 * c2];
            float hn0 = ht[rr * 130 + 64 + 2 * c2];
            float hp1 = ht[rr * 130 + 2 * c2 + 1];
            float hn1 = ht[rr * 130 + 64 + 2 * c2 + 1];
            int lo = __builtin_amdgcn_cvt_pk_fp8_f32(hp0, hn0, 0, false);
            int q = __builtin_amdgcn_cvt_pk_fp8_f32(hp1, hn1, lo, true);
            hq32[node * 32 + c2] = (unsigned)q;
        }
    }
}

__global__ __launch_bounds__(512) void deep_both(
    const unsigned short* __restrict__ hb, const unsigned* __restrict__ hq32,
    const int* __restrict__ offP, const int* __restrict__ csrP,
    const int* __restrict__ offN, const int* __restrict__ csrN,
    const int* __restrict__ cntP, const int* __restrict__ cntN,
    const unsigned short* __restrict__ wt1,
    const float* __restrict__ bp1, const float* __restrict__ bn1,
    const float* __restrict__ Wreg, float* __restrict__ z,
    unsigned char* __restrict__ zq, float4* __restrict__ pnu) {
    __shared__ unsigned short lds[32 * DSTR];
    int tid = threadIdx.x, lane = tid & 63, w = tid >> 6;
    int hf = lane >> 5, l5 = lane & 31;
    int base = blockIdx.x * 32;
    const unsigned* hb32 = (const unsigned*)hb;
    for (int r = w * 4; r < w * 4 + 4; ++r) {
        int node = base + r;
        float gPp0, gPp1, gPn0, gPn1, gNp0, gNp1, gNn0, gNn1;
        gd2q(hq32, csrP, offP[node], offP[node + 1], cntP[node],
             csrN, offN[node], offN[node + 1], cntN[node], hf, l5,
             gPp0, gPp1, gPn0, gPn1, gNp0, gNp1, gNn0, gNn1);
        uint2 sv = *(const uint2*)(hb32 + node * 64 + l5 * 2);
        unsigned* rp32 = (unsigned*)&lds[r * DSTR];
        if (hf == 0) {
            rp32[l5] = (unsigned)f2bf(gPp0) | ((unsigned)f2bf(gPp1) << 16);
            rp32[32 + l5] = (unsigned)f2bf(gNn0) | ((unsigned)f2bf(gNn1) << 16);
            rp32[64 + l5] = (sv.x & 0xFFFFu) | ((sv.y & 0xFFFFu) << 16);
        } else {
            rp32[96 + l5] = (unsigned)f2bf(gPn0) | ((unsigned)f2bf(gPn1) << 16);
            rp32[128 + l5] = (unsigned)f2bf(gNp0) | ((unsigned)f2bf(gNp1) << 16);
            rp32[160 + l5] = (sv.x >> 16) | (sv.y & 0xFFFF0000u);
        }
    }
    __syncthreads();
    int wu = __builtin_amdgcn_readfirstlane(w);
    int mt = wu >> 2, half = (wu >> 1) & 1, nt = wu & 1;
    int l15 = lane & 15, kq = lane >> 4;
    const unsigned short* wbase = wt1 + half * 6144;
    f32x4 acc = (f32x4){0.f, 0.f, 0.f, 0.f};
    const unsigned short* arow = &lds[(mt * 16 + l15) * DSTR + half * 192 + kq * 8];
#pragma unroll
    for (int ks = 0; ks < 6; ++ks) {
        sh8 a = *(const sh8*)(arow + ks * 32);
        sh8 bf = *(const sh8*)(wbase + (nt * 16 + l15) * 192 + ks * 32 + kq * 8);
        acc = __builtin_amdgcn_mfma_f32_16x16x32_bf16(a, bf, acc, 0, 0, 0);
    }
    __syncthreads();
    float* ot = (float*)lds;  // [32][65]
    {
        const float* bias = half ? bn1 : bp1;
        int col = nt * 16 + l15;
        float bb = bias[col];
#pragma unroll
        for (int r = 0; r < 4; ++r) {
            int row = mt * 16 + kq * 4 + r;
            ot[row * 65 + half * 32 + col] = tanhf(acc[r] + bb);
        }
    }
    __syncthreads();
    for (int r = w * 4; r < w * 4 + 4; ++r) {
        int node = base + r;
        float v = ot[r * 65 + lane];
        z[node * 64 + lane] = v;
        int pq = __builtin_amdgcn_cvt_pk_fp8_f32(v, v, 0, false);
        zq[node * 64 + lane] = (unsigned char)(pq & 0xFF);
        float vq = __builtin_amdgcn_cvt_f32_fp8(pq, 0);
        float u0 = vq * Wreg[lane * 2 + 0];
        float u1 = vq * Wreg[lane * 2 + 1];
        float s = vq * vq;
#pragma unroll
        for (int off = 32; off; off >>= 1) {
            u0 += __shfl_xor(u0, off);
            u1 += __shfl_xor(u1, off);
            s += __shfl_xor(s, off);
        }
        if (lane == 0) {
            float4 su = {u0, u1, s, 0.f};
            pnu[node] = su;
        }
    }
}

// 4-lane edge groups: sj/sk/v computed from rows; only pnu[i] (L2-local) loaded
__global__ __launch_bounds__(256) void loss7_kernel(
    const unsigned char* __restrict__ zq, const float4* __restrict__ pnu,
    const unsigned* __restrict__ wvb, const int4* __restrict__ eidx, float* acc) {
    int tid = threadIdx.x;
    int lane = tid & 63;
    int g = lane >> 2, sub = lane & 3;
    int wid = (blockIdx.x * 256 + tid) >> 6;
    int nw = (gridDim.x * 256) >> 6;
    // per-lane Wreg v-cols for dims [sub*16, sub*16+16), packed {v0,v1} bf16
    uint4 wv4[4];
#pragma unroll
    for (int t = 0; t < 4; ++t) wv4[t] = ((const uint4*)wvb)[sub * 4 + t];
    float s_p = 0.f, s_n = 0.f, s_r = 0.f;
    const float q = 0.25f;
    for (int eb = wid * 32; eb < EP_N + EN_N; eb += nw * 32) {
        int eA = eb + g, eB = eb + 16 + g;
        bool vA = eA < EP_N + EN_N, vB = eB < EP_N + EN_N;
        bool pA = eA < EP_N, pB = eB < EP_N;
        int4 qA = eidx[vA ? eA : 0];
        int4 qB = eidx[vB ? eB : 0];
        uint4 ziA = *(const uint4*)(zq + ((long long)qA.x << 6) + (sub << 4));
        uint4 zjA = *(const uint4*)(zq + ((long long)qA.y << 6) + (sub << 4));
        uint4 zkA = *(const uint4*)(zq + ((long long)qA.z << 6) + (sub << 4));
        uint4 ziB = *(const uint4*)(zq + ((long long)qB.x << 6) + (sub << 4));
        uint4 zjB = *(const uint4*)(zq + ((long long)qB.y << 6) + (sub << 4));
        uint4 zkB = *(const uint4*)(zq + ((long long)qB.z << 6) + (sub << 4));
        float4 uA = pnu[qA.x];
        float4 uB = pnu[qB.x];
        float d1A = 0.f, d2A = 0.f, sjA = 0.f, skA = 0.f, v0A = 0.f, v1A = 0.f;
        {
            float fi[16], fj[16], fk[16];
            cvt16(ziA, fi); cvt16(zjA, fj); cvt16(zkA, fk);
#pragma unroll
            for (int t = 0; t < 16; ++t) {
                d1A = fmaf(fi[t], fj[t], d1A);
                d2A = fmaf(fj[t], fk[t], d2A);
                sjA = fmaf(fj[t], fj[t], sjA);
                skA = fmaf(fk[t], fk[t], skA);
                unsigned wp = (&wv4[t >> 2].x)[t & 3];
                v0A = fmaf(fj[t], lo_bf(wp), v0A);
                v1A = fmaf(fj[t], hi_bf(wp), v1A);
            }
        }
        float d1B = 0.f, d2B = 0.f, sjB = 0.f, skB = 0.f, v0B = 0.f, v1B = 0.f;
        {
            float fi[16], fj[16], fk[16];
            cvt16(ziB, fi); cvt16(zjB, fj); cvt16(zkB, fk);
#pragma unroll
            for (int t = 0; t < 16; ++t) {
                d1B = fmaf(fi[t], fj[t], d1B);
                d2B = fmaf(fj[t], fk[t], d2B);
                sjB = fmaf(fj[t], fj[t], sjB);
                skB = fmaf(fk[t], fk[t], skB);
                unsigned wp = (&wv4[t >> 2].x)[t & 3];
                v0B = fmaf(fj[t], lo_bf(wp), v0B);
                v1B = fmaf(fj[t], hi_bf(wp), v1B);
            }
        }
#pragma unroll
        for (int off = 1; off < 4; off <<= 1) {
            d1A += __shfl_xor(d1A, off);
            d2A += __shfl_xor(d2A, off);
            sjA += __shfl_xor(sjA, off);
            skA += __shfl_xor(skA, off);
            v0A += __shfl_xor(v0A, off);
            v1A += __shfl_xor(v1A, off);
            d1B += __shfl_xor(d1B, off);
            d2B += __shfl_xor(d2B, off);
            sjB += __shfl_xor(sjB, off);
            skB += __shfl_xor(skB, off);
            v0B += __shfl_xor(v0B, off);
            v1B += __shfl_xor(v1B, off);
        }
        if (vA) {
            float nij = uA.z + sjA - 2.f * d1A;
            float nik = sjA + skA - 2.f * d2A;
            float tri = fmaxf(nij - nik, 0.f);
            float l0 = uA.x + v0A, l1 = uA.y + v1A;
            float m = fmaxf(l0, l1);
            float lse = m + logf(expf(l0 - m) + expf(l1 - m));
            s_r += (lse - (qA.w ? l1 : l0)) * q;
            if (pA) s_p += tri * q; else s_n += tri * q;
        }
        if (vB) {
            float nij = uB.z + sjB - 2.f * d1B;
            float nik = sjB + skB - 2.f * d2B;
            float tri = fmaxf(nij - nik, 0.f);
            float l0 = uB.x + v0B, l1 = uB.y + v1B;
            float m = fmaxf(l0, l1);
            float lse = m + logf(expf(l0 - m) + expf(l1 - m));
            s_r += (lse - (qB.w ? l1 : l0)) * q;
            if (pB) s_p += tri * q; else s_n += tri * q;
        }
    }
#pragma unroll
    for (int off = 32; off; off >>= 1) {
        s_p += __shfl_xor(s_p, off);
        s_n += __shfl_xor(s_n, off);
        s_r += __shfl_xor(s_r, off);
    }
    __shared__ float red[3][4];
    int w = tid >> 6;
    if (lane == 0) {
        red[0][w] = s_p; red[1][w] = s_n; red[2][w] = s_r;
    }
    __syncthreads();
    if (tid == 0) {
        atomicAdd(&acc[0], red[0][0] + red[0][1] + red[0][2] + red[0][3]);
        atomicAdd(&acc[1], red[1][0] + red[1][1] + red[1][2] + red[1][3]);
        atomicAdd(&acc[2], red[2][0] + red[2][1] + red[2][2] + red[2][3]);
    }
}

__global__ void finalize_kernel(const float* __restrict__ acc, float* out) {
    out[0] = acc[2] / (float)(EP_N + EN_N) +
             1.0f * (acc[0] / (float)EP_N + acc[1] / (float)EN_N);
}

extern "C" void kernel_launch(void* const* d_in, const int* in_sizes, int n_in,
                              void* d_out, int out_size, void* d_ws, size_t ws_size,
                              hipStream_t stream) {
    const float* X = (const float*)d_in[0];
    const float* W_pos0 = (const float*)d_in[1];
    const float* b_pos0 = (const float*)d_in[2];
    const float* W_neg0 = (const float*)d_in[3];
    const float* b_neg0 = (const float*)d_in[4];
    const float* W_pos1 = (const float*)d_in[5];
    const float* b_pos1 = (const float*)d_in[6];
    const float* W_neg1 = (const float*)d_in[7];
    const float* b_neg1 = (const float*)d_in[8];
    const float* W_reg = (const float*)d_in[9];
    const int* pe = (const int*)d_in[10];
    const int* ne = (const int*)d_in[11];
    const int* target = (const int*)d_in[12];
    const int* ps = (const int*)d_in[13];
    const int* ns = (const int*)d_in[14];
    float* out = (float*)d_out;
    float* ws = (float*)d_ws;
    int* wsi = (int*)d_ws;

    float* acc = ws + ACC_OFF;
    int* cntP = wsi + I_CNTP;
    int* cntN = wsi + I_CNTN;
    int* curP = wsi + I_CURP;
    int* curN = wsi + I_CURN;
    int* offP = wsi + I_OFFP;
    int* offN = wsi + I_OFFN;
    int* offPc = wsi + I_OFFPC;
    int* offNc = wsi + I_OFFNC;
    int* csrP = wsi + I_CSRP;
    int* csrN = wsi + I_CSRN;
    int* part = wsi + I_PART;
    int4* eidx = (int4*)(wsi + I_EIDX);
    unsigned short* xb = (unsigned short*)(ws + F_XB);
    unsigned short* hboth = (unsigned short*)(ws + F_HB);
    unsigned* hq32 = (unsigned*)(ws + F_HQ);
    float4* pnu = (float4*)(ws + F_PNU);
    unsigned char* zq = (unsigned char*)(ws + F_ZQ);
    unsigned short* wt = (unsigned short*)(ws + F_WT);
    const unsigned* wvb = (const unsigned*)(wt + 28672);
    float* z = out + 1;

    hipMemsetAsync(ws, 0, (size_t)(16 + 4 * N_NODES) * sizeof(float), stream);

    prep_kernel<<<XB_BLKS + WP_BLKS + CNT_BLKS, 256, 0, stream>>>(
        X, xb, W_pos0, W_neg0, W_pos1, W_neg1, W_reg, wt, pe, ne, cntP, cntN);
    scan_p1<<<2 * SBLK, 512, 0, stream>>>(cntP, cntN, part);
    scan_p2<<<1, 1024, 0, stream>>>(part);
    scan_p3<<<2 * SBLK, 512, 0, stream>>>(cntP, cntN, part, offP, offN,
                                          offPc, offNc, csrP, csrN);
    fill_kernel<<<(EP_N + EN_N + 255) / 256, 256, 0, stream>>>(
        pe, ne, offP, offN, offPc, offNc, ps, ns, target,
        curP, curN, csrP, csrN, eidx);

    base_both<<<NODE_BLOCKS, 512, 0, stream>>>(xb, offP, csrP, offN, csrN, cntP, cntN,
                                               wt, b_pos0, b_neg0, hboth, hq32);
    deep_both<<<DEEP_BLOCKS, 512, 0, stream>>>(hboth, hq32, offP, csrP, offN, csrN,
                                               cntP, cntN, wt + 16384, b_pos1, b_neg1,
                                               W_reg, z, zq, pnu);

    loss7_kernel<<<2048, 256, 0, stream>>>(zq, pnu, wvb, eidx, acc);
    finalize_kernel<<<1, 1, 0, stream>>>(acc, out);
}